// Round 4
// baseline (23984.566 us; speedup 1.0000x reference)
//
#include <hip/hip_runtime.h>

typedef short s16x8 __attribute__((ext_vector_type(8)));
typedef float f32x4 __attribute__((ext_vector_type(4)));

#define T_NEW 1560
#define MPAD  1664
#define DIMM  1536
#define NQKV  4608
#define LKV   9360
#define LPAD  9376
#define NEWB  7800
#define HD    128
#define ATT_SCALE 0.08838834764831845f

static __device__ __forceinline__ short f2bf(float f) {
  unsigned u = __builtin_bit_cast(unsigned, f);
  u = (u + 0x7fffu + ((u >> 16) & 1u)) >> 16;
  return (short)u;
}

static __device__ __forceinline__ float bf2f(short s) {
  unsigned u = ((unsigned)(unsigned short)s) << 16;
  return __builtin_bit_cast(float, u);
}

static __device__ __forceinline__ void mfma16(f32x4& d, s16x8 a, s16x8 b) {
  asm("v_mfma_f32_16x16x32_bf16 %0, %1, %2, %0" : "+v"(d) : "v"(a), "v"(b));
}

#define GLD16(gp, lp) __builtin_amdgcn_global_load_lds(                  \
    (const __attribute__((address_space(1))) void*)(gp),                 \
    (__attribute__((address_space(3))) void*)(lp), 16, 0, 0)

// ---------------- conversion kernels ----------------

__global__ __launch_bounds__(256) void k_cvt(const float* __restrict__ s,
                                             short* __restrict__ d, int n8) {
  int i = blockIdx.x * 256 + threadIdx.x;
  if (i >= n8) return;
  const f32x4* p = (const f32x4*)s + (size_t)i * 2;
  f32x4 a = p[0], b = p[1];
  s16x8 o;
  o[0]=f2bf(a[0]); o[1]=f2bf(a[1]); o[2]=f2bf(a[2]); o[3]=f2bf(a[3]);
  o[4]=f2bf(b[0]); o[5]=f2bf(b[1]); o[6]=f2bf(b[2]); o[7]=f2bf(b[3]);
  *((s16x8*)d + i) = o;
}

// x (1560x1536) -> bf16 padded to 1664 rows (pad rows = 0)
__global__ __launch_bounds__(256) void k_cvt_x(const float* __restrict__ s,
                                               short* __restrict__ d) {
  int i = blockIdx.x * 256 + threadIdx.x;   // over MPAD*192
  s16x8 o;
  if (i < T_NEW * (DIMM / 8)) {
    const f32x4* p = (const f32x4*)s + (size_t)i * 2;
    f32x4 a = p[0], b = p[1];
    o[0]=f2bf(a[0]); o[1]=f2bf(a[1]); o[2]=f2bf(a[2]); o[3]=f2bf(a[3]);
    o[4]=f2bf(b[0]); o[5]=f2bf(b[1]); o[6]=f2bf(b[2]); o[7]=f2bf(b[3]);
  } else {
    o = 0;
  }
  *((s16x8*)d + i) = o;
}

// cache (9360x1536 f32) -> dst rows [0,7800) with roll, rows [9360,9376) zero
__global__ __launch_bounds__(256) void k_gather(const float* __restrict__ src,
                                                short* __restrict__ dst) {
  int i = blockIdx.x * 256 + threadIdx.x;   // over 7816*192
  int vrow = i / 192;
  int c8 = i - vrow * 192;
  s16x8 o;
  int drow;
  if (vrow < NEWB) {
    drow = vrow;
    int srow = (vrow < 1560) ? vrow : vrow + 1560;
    const f32x4* p = (const f32x4*)(src + (size_t)srow * DIMM + c8 * 8);
    f32x4 a = p[0], b = p[1];
    o[0]=f2bf(a[0]); o[1]=f2bf(a[1]); o[2]=f2bf(a[2]); o[3]=f2bf(a[3]);
    o[4]=f2bf(b[0]); o[5]=f2bf(b[1]); o[6]=f2bf(b[2]); o[7]=f2bf(b[3]);
  } else {
    drow = LKV + (vrow - NEWB);
    o = 0;
  }
  *(s16x8*)(dst + (size_t)drow * DIMM + c8 * 8) = o;
}

// ---------------- GEMM: C[M,N] = A[M,K] * Bt[N,K]^T + bias ----------------

__global__ __launch_bounds__(256) void k_gemm(const short* __restrict__ A,
                                              const short* __restrict__ Bt,
                                              const float* __restrict__ bias,
                                              float* __restrict__ C,
                                              int N, int K, int Mvalid) {
  __shared__ short lA[4096];
  __shared__ short lB[4096];
  const int tid = threadIdx.x;
  const int w = tid >> 6, l = tid & 63;
  const int lo = l & 15, hi = l >> 4;
  const int wr = w >> 1, wc = w & 1;
  const int brow = blockIdx.y * 128, bcol = blockIdx.x * 128;
  f32x4 acc[4][4] = {};
  const short* gA = A + (size_t)(brow + w * 32 + (l >> 2)) * K + ((l & 3) * 8);
  const short* gB = Bt + (size_t)(bcol + w * 32 + (l >> 2)) * K + ((l & 3) * 8);
  short* lAw = &lA[w * 1024];
  short* lBw = &lB[w * 1024];
  for (int k0 = 0; k0 < K; k0 += 32) {
    GLD16(gA + k0, lAw);
    GLD16(gA + (size_t)16 * K + k0, lAw + 512);
    GLD16(gB + k0, lBw);
    GLD16(gB + (size_t)16 * K + k0, lBw + 512);
    __syncthreads();
    s16x8 af[4], bf[4];
#pragma unroll
    for (int m = 0; m < 4; ++m)
      af[m] = *(const s16x8*)&lA[(wr * 64 + m * 16 + lo) * 32 + hi * 8];
#pragma unroll
    for (int n = 0; n < 4; ++n)
      bf[n] = *(const s16x8*)&lB[(wc * 64 + n * 16 + lo) * 32 + hi * 8];
#pragma unroll
    for (int m = 0; m < 4; ++m)
#pragma unroll
      for (int n = 0; n < 4; ++n)
        mfma16(acc[m][n], af[m], bf[n]);
    __syncthreads();
  }
#pragma unroll
  for (int n = 0; n < 4; ++n) {
    int c = bcol + wc * 64 + n * 16 + lo;
    float bs = bias[c];
#pragma unroll
    for (int m = 0; m < 4; ++m) {
      int r0 = brow + wr * 64 + m * 16 + 4 * hi;
#pragma unroll
      for (int r = 0; r < 4; ++r) {
        int rr = r0 + r;
        if (rr < Mvalid) C[(size_t)rr * N + c] = acc[m][n][r] + bs;
      }
    }
  }
}

// ---------------- bias'd QKV row post: rmsnorm+rope for q,k; v passthrough --

__global__ __launch_bounds__(256) void k_post(const float* __restrict__ qkv,
                                              const float* __restrict__ fc,
                                              const float* __restrict__ fs,
                                              const float* __restrict__ gq,
                                              const float* __restrict__ gk,
                                              short* __restrict__ Qb,
                                              short* __restrict__ Kb,
                                              short* __restrict__ Vr) {
  const int t = blockIdx.x, tid = threadIdx.x;
  __shared__ float buf[DIMM];
  __shared__ float red[4];
  const float* row = qkv + (size_t)t * NQKV;
  for (int sec = 0; sec < 2; ++sec) {
    const float* src = row + sec * DIMM;
    const float* g = sec ? gk : gq;
    float ssq = 0.f;
#pragma unroll
    for (int i = 0; i < 6; ++i) {
      float v = src[tid + i * 256];
      buf[tid + i * 256] = v;
      ssq += v * v;
    }
#pragma unroll
    for (int off = 32; off > 0; off >>= 1) ssq += __shfl_xor(ssq, off);
    if ((tid & 63) == 0) red[tid >> 6] = ssq;
    __syncthreads();
    float rms = rsqrtf((red[0] + red[1] + red[2] + red[3]) * (1.f / 1536.f) + 1e-6f);
    short* dst = sec ? (Kb + (size_t)(NEWB + t) * DIMM) : (Qb + (size_t)t * DIMM);
#pragma unroll
    for (int i = 0; i < 6; ++i) {
      int e = tid + i * 256;
      int d = e & 127;
      float vn = buf[e] * rms * g[e];
      float o;
      if (d < 64) {
        float v2 = buf[e + 64] * rms * g[e + 64];
        o = vn * fc[t * 64 + d] - v2 * fs[t * 64 + d];
      } else {
        float v1 = buf[e - 64] * rms * g[e - 64];
        o = v1 * fs[t * 64 + d - 64] + vn * fc[t * 64 + d - 64];
      }
      dst[e] = f2bf(o);
    }
    __syncthreads();
  }
#pragma unroll
  for (int i = 0; i < 6; ++i) {
    int e = tid + i * 256;
    Vr[(size_t)(NEWB + t) * DIMM + e] = f2bf(row[3072 + e]);
  }
}

// ---------------- scalar fp32 reference attention (bisection probe) --------
// block = 256 threads, one (t, h) pair per block; reads row-major Kb and Vr
// (bypasses both MFMA attention and k_transv).

__global__ __launch_bounds__(256) void k_attn_ref(const short* __restrict__ Qb,
                                                  const short* __restrict__ Kb,
                                                  const short* __restrict__ Vr,
                                                  short* __restrict__ Ob) {
  const int t = blockIdx.x, h = blockIdx.y, tid = threadIdx.x;
  __shared__ float q[HD];
  __shared__ float p[LKV];
  __shared__ float red[4];
  __shared__ float acc2[256];
  if (tid < HD) q[tid] = bf2f(Qb[(size_t)t * DIMM + h * HD + tid]);
  __syncthreads();

  float lmax = -1e30f;
  for (int k = tid; k < LKV; k += 256) {
    const short* kr = Kb + (size_t)k * DIMM + h * HD;
    float s = 0.f;
    for (int d = 0; d < HD; ++d) s += q[d] * bf2f(kr[d]);
    s *= ATT_SCALE;
    p[k] = s;
    lmax = fmaxf(lmax, s);
  }
#pragma unroll
  for (int off = 32; off > 0; off >>= 1) lmax = fmaxf(lmax, __shfl_xor(lmax, off));
  if ((tid & 63) == 0) red[tid >> 6] = lmax;
  __syncthreads();
  float bmax = fmaxf(fmaxf(red[0], red[1]), fmaxf(red[2], red[3]));
  __syncthreads();

  float lsum = 0.f;
  for (int k = tid; k < LKV; k += 256) {
    float e = __expf(p[k] - bmax);
    p[k] = e;
    lsum += e;
  }
#pragma unroll
  for (int off = 32; off > 0; off >>= 1) lsum += __shfl_xor(lsum, off);
  if ((tid & 63) == 0) red[tid >> 6] = lsum;
  __syncthreads();
  float bsum = red[0] + red[1] + red[2] + red[3];

  const int d = tid & 127, half = tid >> 7;
  float acc = 0.f;
  for (int k = half; k < LKV; k += 2)
    acc += p[k] * bf2f(Vr[(size_t)k * DIMM + h * HD + d]);
  acc2[tid] = acc;
  __syncthreads();
  if (tid < 128) {
    float o = (acc2[tid] + acc2[tid + 128]) / bsum;
    Ob[(size_t)t * DIMM + h * HD + d] = f2bf(o);
  }
}

// ---------------- launch ----------------

extern "C" void kernel_launch(void* const* d_in, const int* in_sizes, int n_in,
                              void* d_out, int out_size, void* d_ws, size_t ws_size,
                              hipStream_t stream) {
  (void)in_sizes; (void)n_in; (void)out_size;
  const float* x  = (const float*)d_in[0];
  const float* fc = (const float*)d_in[1];
  const float* fs = (const float*)d_in[2];
  const float* ck = (const float*)d_in[3];
  const float* cv = (const float*)d_in[4];
  const float* wq = (const float*)d_in[5];
  const float* p_bq = (const float*)d_in[6];
  const float* wk = (const float*)d_in[7];
  const float* p_bk = (const float*)d_in[8];
  const float* wv = (const float*)d_in[9];
  const float* p_bv = (const float*)d_in[10];
  const float* wo = (const float*)d_in[11];
  const float* p_bo = (const float*)d_in[12];
  const float* gq = (const float*)d_in[13];
  const float* gk = (const float*)d_in[14];
  float* out = (float*)d_out;

  char* ws = (char*)d_ws;
  if (ws_size < 117393408ull) return;
  short* xb   = (short*)(ws + 0);                 // 1664x1536 bf16 (alias Ob)
  short* ob   = xb;
  short* wqkv = (short*)(ws + 5111808);           // 4608x1536 bf16
  short* wob  = (short*)(ws + 19267584);          // 1536x1536 bf16
  float* bqkv = (float*)(ws + 23986176);          // 4608 f32
  float* qkvf = (float*)(ws + 24004608);          // 1664x4608 f32
  short* qb   = (short*)(ws + 54675456);          // 1664x1536 bf16
  short* kb   = (short*)(ws + 59787264);          // 9376x1536 bf16
  short* vr   = (short*)(ws + 88590336);          // 9376x1536 bf16

  k_cvt_x<<<1248, 256, 0, stream>>>(x, xb);
  k_cvt<<<1152, 256, 0, stream>>>(wq, wqkv, 294912);
  k_cvt<<<1152, 256, 0, stream>>>(wk, wqkv + 1536 * 1536, 294912);
  k_cvt<<<1152, 256, 0, stream>>>(wv, wqkv + 2 * 1536 * 1536, 294912);
  k_cvt<<<1152, 256, 0, stream>>>(wo, wob, 294912);
  hipMemcpyAsync(bqkv, p_bq, 1536 * 4, hipMemcpyDeviceToDevice, stream);
  hipMemcpyAsync(bqkv + 1536, p_bk, 1536 * 4, hipMemcpyDeviceToDevice, stream);
  hipMemcpyAsync(bqkv + 3072, p_bv, 1536 * 4, hipMemcpyDeviceToDevice, stream);
  k_gather<<<5862, 256, 0, stream>>>(ck, kb);
  k_gather<<<5862, 256, 0, stream>>>(cv, vr);
  hipMemsetAsync(qb + (size_t)1560 * 1536, 0, 104 * 1536 * 2, stream);

  k_gemm<<<dim3(36, 13), 256, 0, stream>>>(xb, wqkv, bqkv, qkvf, 4608, 1536, 1664);
  // zero ob pad rows (probe writes only rows < 1560; final GEMM reads 1664)
  hipMemsetAsync(ob + (size_t)1560 * 1536, 0, 104 * 1536 * 2, stream);
  k_post<<<1560, 256, 0, stream>>>(qkvf, fc, fs, gq, gk, qb, kb, vr);
  k_attn_ref<<<dim3(1560, 12), 256, 0, stream>>>(qb, kb, vr, ob);
  k_gemm<<<dim3(12, 13), 256, 0, stream>>>(ob, wob, p_bo, out, 1536, 1536, 1560);
}

// Round 6
// 934.614 us; speedup vs baseline: 25.6625x; 25.6625x over previous
//
#include <hip/hip_runtime.h>

typedef short s16x8 __attribute__((ext_vector_type(8)));
typedef __bf16 bf16x8 __attribute__((ext_vector_type(8)));
typedef float f32x4 __attribute__((ext_vector_type(4)));

#define T_NEW 1560
#define MPAD  1664
#define DIMM  1536
#define NQKV  4608
#define LKV   9360
#define LPAD  9376
#define NEWB  7800
#define HD    128
#define ATT_SCALE 0.08838834764831845f

static __device__ __forceinline__ short f2bf(float f) {
  unsigned u = __builtin_bit_cast(unsigned, f);
  u = (u + 0x7fffu + ((u >> 16) & 1u)) >> 16;
  return (short)u;
}

static __device__ __forceinline__ float bf2f(short s) {
  unsigned u = ((unsigned)(unsigned short)s) << 16;
  return __builtin_bit_cast(float, u);
}

// builtin MFMA: compiler models latency and inserts required wait-states
// (raw inline-asm MFMA lacks hazard handling -> stale VALU reads; r2/3/5 bug)
static __device__ __forceinline__ void mfma16(f32x4& d, s16x8 a, s16x8 b) {
  d = __builtin_amdgcn_mfma_f32_16x16x32_bf16(
      __builtin_bit_cast(bf16x8, a), __builtin_bit_cast(bf16x8, b), d, 0, 0, 0);
}

#define GLD16(gp, lp) __builtin_amdgcn_global_load_lds(                  \
    (const __attribute__((address_space(1))) void*)(gp),                 \
    (__attribute__((address_space(3))) void*)(lp), 16, 0, 0)

// ---------------- conversion kernels ----------------

__global__ __launch_bounds__(256) void k_cvt(const float* __restrict__ s,
                                             short* __restrict__ d, int n8) {
  int i = blockIdx.x * 256 + threadIdx.x;
  if (i >= n8) return;
  const f32x4* p = (const f32x4*)s + (size_t)i * 2;
  f32x4 a = p[0], b = p[1];
  s16x8 o;
  o[0]=f2bf(a[0]); o[1]=f2bf(a[1]); o[2]=f2bf(a[2]); o[3]=f2bf(a[3]);
  o[4]=f2bf(b[0]); o[5]=f2bf(b[1]); o[6]=f2bf(b[2]); o[7]=f2bf(b[3]);
  *((s16x8*)d + i) = o;
}

// x (1560x1536) -> bf16 padded to 1664 rows (pad rows = 0)
__global__ __launch_bounds__(256) void k_cvt_x(const float* __restrict__ s,
                                               short* __restrict__ d) {
  int i = blockIdx.x * 256 + threadIdx.x;   // over MPAD*192
  s16x8 o;
  if (i < T_NEW * (DIMM / 8)) {
    const f32x4* p = (const f32x4*)s + (size_t)i * 2;
    f32x4 a = p[0], b = p[1];
    o[0]=f2bf(a[0]); o[1]=f2bf(a[1]); o[2]=f2bf(a[2]); o[3]=f2bf(a[3]);
    o[4]=f2bf(b[0]); o[5]=f2bf(b[1]); o[6]=f2bf(b[2]); o[7]=f2bf(b[3]);
  } else {
    o = 0;
  }
  *((s16x8*)d + i) = o;
}

// cache (9360x1536 f32) -> dst rows [0,7800) with roll, rows [9360,9376) zero
__global__ __launch_bounds__(256) void k_gather(const float* __restrict__ src,
                                                short* __restrict__ dst) {
  int i = blockIdx.x * 256 + threadIdx.x;   // over 7816*192
  int vrow = i / 192;
  int c8 = i - vrow * 192;
  s16x8 o;
  int drow;
  if (vrow < NEWB) {
    drow = vrow;
    int srow = (vrow < 1560) ? vrow : vrow + 1560;
    const f32x4* p = (const f32x4*)(src + (size_t)srow * DIMM + c8 * 8);
    f32x4 a = p[0], b = p[1];
    o[0]=f2bf(a[0]); o[1]=f2bf(a[1]); o[2]=f2bf(a[2]); o[3]=f2bf(a[3]);
    o[4]=f2bf(b[0]); o[5]=f2bf(b[1]); o[6]=f2bf(b[2]); o[7]=f2bf(b[3]);
  } else {
    drow = LKV + (vrow - NEWB);
    o = 0;
  }
  *(s16x8*)(dst + (size_t)drow * DIMM + c8 * 8) = o;
}

// ---------------- GEMM: C[M,N] = A[M,K] * Bt[N,K]^T + bias ----------------

__global__ __launch_bounds__(256) void k_gemm(const short* __restrict__ A,
                                              const short* __restrict__ Bt,
                                              const float* __restrict__ bias,
                                              float* __restrict__ C,
                                              int N, int K, int Mvalid) {
  __shared__ short lA[4096];
  __shared__ short lB[4096];
  const int tid = threadIdx.x;
  const int w = tid >> 6, l = tid & 63;
  const int lo = l & 15, hi = l >> 4;
  const int wr = w >> 1, wc = w & 1;
  const int brow = blockIdx.y * 128, bcol = blockIdx.x * 128;
  f32x4 acc[4][4] = {};
  const short* gA = A + (size_t)(brow + w * 32 + (l >> 2)) * K + ((l & 3) * 8);
  const short* gB = Bt + (size_t)(bcol + w * 32 + (l >> 2)) * K + ((l & 3) * 8);
  short* lAw = &lA[w * 1024];
  short* lBw = &lB[w * 1024];
  for (int k0 = 0; k0 < K; k0 += 32) {
    GLD16(gA + k0, lAw);
    GLD16(gA + (size_t)16 * K + k0, lAw + 512);
    GLD16(gB + k0, lBw);
    GLD16(gB + (size_t)16 * K + k0, lBw + 512);
    __syncthreads();
    s16x8 af[4], bf[4];
#pragma unroll
    for (int m = 0; m < 4; ++m)
      af[m] = *(const s16x8*)&lA[(wr * 64 + m * 16 + lo) * 32 + hi * 8];
#pragma unroll
    for (int n = 0; n < 4; ++n)
      bf[n] = *(const s16x8*)&lB[(wc * 64 + n * 16 + lo) * 32 + hi * 8];
#pragma unroll
    for (int m = 0; m < 4; ++m)
#pragma unroll
      for (int n = 0; n < 4; ++n)
        mfma16(acc[m][n], af[m], bf[n]);
    __syncthreads();
  }
#pragma unroll
  for (int n = 0; n < 4; ++n) {
    int c = bcol + wc * 64 + n * 16 + lo;
    float bs = bias[c];
#pragma unroll
    for (int m = 0; m < 4; ++m) {
      int r0 = brow + wr * 64 + m * 16 + 4 * hi;
#pragma unroll
      for (int r = 0; r < 4; ++r) {
        int rr = r0 + r;
        if (rr < Mvalid) C[(size_t)rr * N + c] = acc[m][n][r] + bs;
      }
    }
  }
}

// ---------------- bias'd QKV row post: rmsnorm+rope for q,k; v passthrough --

__global__ __launch_bounds__(256) void k_post(const float* __restrict__ qkv,
                                              const float* __restrict__ fc,
                                              const float* __restrict__ fs,
                                              const float* __restrict__ gq,
                                              const float* __restrict__ gk,
                                              short* __restrict__ Qb,
                                              short* __restrict__ Kb,
                                              short* __restrict__ Vr) {
  const int t = blockIdx.x, tid = threadIdx.x;
  __shared__ float buf[DIMM];
  __shared__ float red[4];
  const float* row = qkv + (size_t)t * NQKV;
  for (int sec = 0; sec < 2; ++sec) {
    const float* src = row + sec * DIMM;
    const float* g = sec ? gk : gq;
    float ssq = 0.f;
#pragma unroll
    for (int i = 0; i < 6; ++i) {
      float v = src[tid + i * 256];
      buf[tid + i * 256] = v;
      ssq += v * v;
    }
#pragma unroll
    for (int off = 32; off > 0; off >>= 1) ssq += __shfl_xor(ssq, off);
    if ((tid & 63) == 0) red[tid >> 6] = ssq;
    __syncthreads();
    float rms = rsqrtf((red[0] + red[1] + red[2] + red[3]) * (1.f / 1536.f) + 1e-6f);
    short* dst = sec ? (Kb + (size_t)(NEWB + t) * DIMM) : (Qb + (size_t)t * DIMM);
#pragma unroll
    for (int i = 0; i < 6; ++i) {
      int e = tid + i * 256;
      int d = e & 127;
      float vn = buf[e] * rms * g[e];
      float o;
      if (d < 64) {
        float v2 = buf[e + 64] * rms * g[e + 64];
        o = vn * fc[t * 64 + d] - v2 * fs[t * 64 + d];
      } else {
        float v1 = buf[e - 64] * rms * g[e - 64];
        o = v1 * fs[t * 64 + d - 64] + vn * fc[t * 64 + d - 64];
      }
      dst[e] = f2bf(o);
    }
    __syncthreads();
  }
#pragma unroll
  for (int i = 0; i < 6; ++i) {
    int e = tid + i * 256;
    Vr[(size_t)(NEWB + t) * DIMM + e] = f2bf(row[3072 + e]);
  }
}

// ---------------- V transpose: Vr[l][h*128+d] -> Vt[h][d][l] ----------------

__global__ __launch_bounds__(256) void k_transv(const short* __restrict__ Vr,
                                                short* __restrict__ Vt) {
  const int h = blockIdx.y;
  const int l0 = blockIdx.x * 32;
  const int tid = threadIdx.x;
  __shared__ short lt[128 * 34];
#pragma unroll
  for (int i = 0; i < 16; ++i) {
    int idx = i * 256 + tid;
    int li = idx >> 7;
    int d = idx & 127;
    lt[d * 34 + li] = Vr[(size_t)(l0 + li) * DIMM + h * HD + d];
  }
  __syncthreads();
#pragma unroll
  for (int i = 0; i < 16; ++i) {
    int idx = i * 256 + tid;
    int d = idx >> 5;
    int li = idx & 31;
    Vt[((size_t)h * HD + d) * LPAD + l0 + li] = lt[d * 34 + li];
  }
}

// ---------------- flash attention (MFMA, builtin; direct-global K/Vt) ------
// block: 128 thr (2 independent waves), 16 queries/wave; grid (49, 12).
// Only LDS: per-wave padded P buffer (16 rows x 40 shorts).

__global__ __launch_bounds__(128) void k_attn(const short* __restrict__ Qb,
                                              const short* __restrict__ Kb,
                                              const short* __restrict__ Vt,
                                              short* __restrict__ Ob) {
  const int h = blockIdx.y;
  const int w = threadIdx.x >> 6;
  const int l = threadIdx.x & 63;
  const int lo = l & 15, hi = l >> 4;
  const int q0 = blockIdx.x * 32 + w * 16;
  __shared__ short lP[2][640];
  short* P = lP[w];

  s16x8 aq[4];
  const short* qp = Qb + (size_t)(q0 + lo) * DIMM + h * HD + hi * 8;
#pragma unroll
  for (int kk = 0; kk < 4; ++kk) aq[kk] = *(const s16x8*)(qp + kk * 32);

  f32x4 oacc[8];
#pragma unroll
  for (int n = 0; n < 8; ++n) oacc[n] = 0;
  float m_r[4], l_r[4];
#pragma unroll
  for (int r = 0; r < 4; ++r) { m_r[r] = -1e30f; l_r[r] = 0.f; }

  const short* Kp = Kb + (size_t)lo * DIMM + h * HD + hi * 8;
  const short* Vp = Vt + (size_t)h * HD * LPAD + hi * 8;

  for (int kbv = 0; kbv < LKV; kbv += 32) {
    const short* kRow0 = Kp + (size_t)kbv * DIMM;
    const short* kRow1 = kRow0 + (size_t)16 * DIMM;
    f32x4 s0 = 0, s1 = 0;
#pragma unroll
    for (int kk = 0; kk < 4; ++kk) {
      s16x8 b0 = *(const s16x8*)(kRow0 + kk * 32);
      s16x8 b1 = *(const s16x8*)(kRow1 + kk * 32);
      mfma16(s0, aq[kk], b0);
      mfma16(s1, aq[kk], b1);
    }

    float sv0[4], sv1[4];
    const int key1 = kbv + 16 + lo;   // key0 = kbv+lo is always < LKV
#pragma unroll
    for (int r = 0; r < 4; ++r) {
      sv0[r] = s0[r] * ATT_SCALE;
      sv1[r] = (key1 < LKV) ? s1[r] * ATT_SCALE : -1e30f;
    }
    float mx[4];
#pragma unroll
    for (int r = 0; r < 4; ++r) mx[r] = fmaxf(sv0[r], sv1[r]);
#pragma unroll
    for (int off = 1; off < 16; off <<= 1) {
#pragma unroll
      for (int r = 0; r < 4; ++r) mx[r] = fmaxf(mx[r], __shfl_xor(mx[r], off));
    }
    float alpha[4], ps[4];
    short pb0[4], pb1[4];
#pragma unroll
    for (int r = 0; r < 4; ++r) {
      float mn = fmaxf(m_r[r], mx[r]);
      alpha[r] = __expf(m_r[r] - mn);
      m_r[r] = mn;
      float p0 = __expf(sv0[r] - mn);
      float p1 = __expf(sv1[r] - mn);
      ps[r] = p0 + p1;
      pb0[r] = f2bf(p0);
      pb1[r] = f2bf(p1);
    }
#pragma unroll
    for (int off = 1; off < 16; off <<= 1) {
#pragma unroll
      for (int r = 0; r < 4; ++r) ps[r] += __shfl_xor(ps[r], off);
    }
#pragma unroll
    for (int r = 0; r < 4; ++r) l_r[r] = l_r[r] * alpha[r] + ps[r];
#pragma unroll
    for (int n = 0; n < 8; ++n)
#pragma unroll
      for (int r = 0; r < 4; ++r) oacc[n][r] *= alpha[r];

    // P fragment redistribution through per-wave LDS (row stride 40 shorts)
#pragma unroll
    for (int r = 0; r < 4; ++r) {
      int row = 4 * hi + r;
      P[row * 40 + lo] = pb0[r];
      P[row * 40 + 16 + lo] = pb1[r];
    }
    s16x8 ap = *(const s16x8*)&P[lo * 40 + hi * 8];
#pragma unroll
    for (int n = 0; n < 8; ++n) {
      s16x8 bv = *(const s16x8*)(Vp + (size_t)(n * 16 + lo) * LPAD + kbv);
      mfma16(oacc[n], ap, bv);
    }
  }

  float inv[4];
#pragma unroll
  for (int r = 0; r < 4; ++r) inv[r] = 1.f / l_r[r];
#pragma unroll
  for (int n = 0; n < 8; ++n)
#pragma unroll
    for (int r = 0; r < 4; ++r) {
      int rr = q0 + 4 * hi + r;
      Ob[(size_t)rr * DIMM + h * HD + n * 16 + lo] = f2bf(oacc[n][r] * inv[r]);
    }
}

// ---------------- launch ----------------

extern "C" void kernel_launch(void* const* d_in, const int* in_sizes, int n_in,
                              void* d_out, int out_size, void* d_ws, size_t ws_size,
                              hipStream_t stream) {
  (void)in_sizes; (void)n_in; (void)out_size;
  const float* x  = (const float*)d_in[0];
  const float* fc = (const float*)d_in[1];
  const float* fs = (const float*)d_in[2];
  const float* ck = (const float*)d_in[3];
  const float* cv = (const float*)d_in[4];
  const float* wq = (const float*)d_in[5];
  const float* p_bq = (const float*)d_in[6];
  const float* wk = (const float*)d_in[7];
  const float* p_bk = (const float*)d_in[8];
  const float* wv = (const float*)d_in[9];
  const float* p_bv = (const float*)d_in[10];
  const float* wo = (const float*)d_in[11];
  const float* p_bo = (const float*)d_in[12];
  const float* gq = (const float*)d_in[13];
  const float* gk = (const float*)d_in[14];
  float* out = (float*)d_out;

  char* ws = (char*)d_ws;
  if (ws_size < 117393408ull) return;
  short* xb   = (short*)(ws + 0);                 // 1664x1536 bf16 (alias Ob)
  short* ob   = xb;
  short* wqkv = (short*)(ws + 5111808);           // 4608x1536 bf16
  short* wob  = (short*)(ws + 19267584);          // 1536x1536 bf16
  float* bqkv = (float*)(ws + 23986176);          // 4608 f32
  float* qkvf = (float*)(ws + 24004608);          // 1664x4608 f32 (alias Vt)
  short* vt   = (short*)(ws + 24004608);          // 12x128x9376 bf16
  short* qb   = (short*)(ws + 54675456);          // 1664x1536 bf16
  short* kb   = (short*)(ws + 59787264);          // 9376x1536 bf16
  short* vr   = (short*)(ws + 88590336);          // 9376x1536 bf16

  k_cvt_x<<<1248, 256, 0, stream>>>(x, xb);
  k_cvt<<<1152, 256, 0, stream>>>(wq, wqkv, 294912);
  k_cvt<<<1152, 256, 0, stream>>>(wk, wqkv + 1536 * 1536, 294912);
  k_cvt<<<1152, 256, 0, stream>>>(wv, wqkv + 2 * 1536 * 1536, 294912);
  k_cvt<<<1152, 256, 0, stream>>>(wo, wob, 294912);
  hipMemcpyAsync(bqkv, p_bq, 1536 * 4, hipMemcpyDeviceToDevice, stream);
  hipMemcpyAsync(bqkv + 1536, p_bk, 1536 * 4, hipMemcpyDeviceToDevice, stream);
  hipMemcpyAsync(bqkv + 3072, p_bv, 1536 * 4, hipMemcpyDeviceToDevice, stream);
  k_gather<<<5862, 256, 0, stream>>>(ck, kb);
  k_gather<<<5862, 256, 0, stream>>>(cv, vr);
  hipMemsetAsync(qb + (size_t)1560 * 1536, 0, 104 * 1536 * 2, stream);

  k_gemm<<<dim3(36, 13), 256, 0, stream>>>(xb, wqkv, bqkv, qkvf, 4608, 1536, 1664);
  // zero ob pad rows (attn writes rows < 1568; final GEMM stages 1664)
  hipMemsetAsync(ob + (size_t)1560 * 1536, 0, 104 * 1536 * 2, stream);
  k_post<<<1560, 256, 0, stream>>>(qkvf, fc, fs, gq, gk, qb, kb, vr);
  k_transv<<<dim3(293, 12), 256, 0, stream>>>(vr, vt);
  k_attn<<<dim3(49, 12), 128, 0, stream>>>(qb, kb, vt, ob);
  k_gemm<<<dim3(12, 13), 256, 0, stream>>>(ob, wob, p_bo, out, 1536, 1536, 1560);
}

// Round 7
// 780.579 us; speedup vs baseline: 30.7267x; 1.1973x over previous
//
#include <hip/hip_runtime.h>

typedef short s16x8 __attribute__((ext_vector_type(8)));
typedef __bf16 bf16x8 __attribute__((ext_vector_type(8)));
typedef float f32x4 __attribute__((ext_vector_type(4)));

#define T_NEW 1560
#define MPAD  1664
#define DIMM  1536
#define NQKV  4608
#define LKV   9360
#define LPAD  9376
#define NEWB  7800
#define HD    128
#define NSPLIT 4
#define NTILE  293          /* ceil(9360/32) */
#define SPLIT_STRIDE ((size_t)12 * 1560 * 128)
#define ATT_SCALE 0.08838834764831845f

static __device__ __forceinline__ short f2bf(float f) {
  unsigned u = __builtin_bit_cast(unsigned, f);
  u = (u + 0x7fffu + ((u >> 16) & 1u)) >> 16;
  return (short)u;
}

static __device__ __forceinline__ float bf2f(short s) {
  unsigned u = ((unsigned)(unsigned short)s) << 16;
  return __builtin_bit_cast(float, u);
}

// builtin MFMA: compiler models latency + inserts MFMA->VALU wait states
// (raw inline-asm MFMA lacks hazard handling -> stale VALU reads; r2-r5 bug)
static __device__ __forceinline__ void mfma16(f32x4& d, s16x8 a, s16x8 b) {
  d = __builtin_amdgcn_mfma_f32_16x16x32_bf16(
      __builtin_bit_cast(bf16x8, a), __builtin_bit_cast(bf16x8, b), d, 0, 0, 0);
}

#define GLD16(gp, lp) __builtin_amdgcn_global_load_lds(                  \
    (const __attribute__((address_space(1))) void*)(gp),                 \
    (__attribute__((address_space(3))) void*)(lp), 16, 0, 0)

// ---------------- conversion kernels ----------------

__global__ __launch_bounds__(256) void k_cvt(const float* __restrict__ s,
                                             short* __restrict__ d, int n8) {
  int i = blockIdx.x * 256 + threadIdx.x;
  if (i >= n8) return;
  const f32x4* p = (const f32x4*)s + (size_t)i * 2;
  f32x4 a = p[0], b = p[1];
  s16x8 o;
  o[0]=f2bf(a[0]); o[1]=f2bf(a[1]); o[2]=f2bf(a[2]); o[3]=f2bf(a[3]);
  o[4]=f2bf(b[0]); o[5]=f2bf(b[1]); o[6]=f2bf(b[2]); o[7]=f2bf(b[3]);
  *((s16x8*)d + i) = o;
}

// x (1560x1536) -> bf16 padded to 1664 rows (pad rows = 0)
__global__ __launch_bounds__(256) void k_cvt_x(const float* __restrict__ s,
                                               short* __restrict__ d) {
  int i = blockIdx.x * 256 + threadIdx.x;   // over MPAD*192
  s16x8 o;
  if (i < T_NEW * (DIMM / 8)) {
    const f32x4* p = (const f32x4*)s + (size_t)i * 2;
    f32x4 a = p[0], b = p[1];
    o[0]=f2bf(a[0]); o[1]=f2bf(a[1]); o[2]=f2bf(a[2]); o[3]=f2bf(a[3]);
    o[4]=f2bf(b[0]); o[5]=f2bf(b[1]); o[6]=f2bf(b[2]); o[7]=f2bf(b[3]);
  } else {
    o = 0;
  }
  *((s16x8*)d + i) = o;
}

// cache (9360x1536 f32) -> dst rows [0,7800) with roll, rows [9360,9376) zero
__global__ __launch_bounds__(256) void k_gather(const float* __restrict__ src,
                                                short* __restrict__ dst) {
  int i = blockIdx.x * 256 + threadIdx.x;   // over 7816*192
  int vrow = i / 192;
  int c8 = i - vrow * 192;
  s16x8 o;
  int drow;
  if (vrow < NEWB) {
    drow = vrow;
    int srow = (vrow < 1560) ? vrow : vrow + 1560;
    const f32x4* p = (const f32x4*)(src + (size_t)srow * DIMM + c8 * 8);
    f32x4 a = p[0], b = p[1];
    o[0]=f2bf(a[0]); o[1]=f2bf(a[1]); o[2]=f2bf(a[2]); o[3]=f2bf(a[3]);
    o[4]=f2bf(b[0]); o[5]=f2bf(b[1]); o[6]=f2bf(b[2]); o[7]=f2bf(b[3]);
  } else {
    drow = LKV + (vrow - NEWB);
    o = 0;
  }
  *(s16x8*)(dst + (size_t)drow * DIMM + c8 * 8) = o;
}

// ---------------- GEMM: C[M,N] = A[M,K] * Bt[N,K]^T + bias ----------------

__global__ __launch_bounds__(256) void k_gemm(const short* __restrict__ A,
                                              const short* __restrict__ Bt,
                                              const float* __restrict__ bias,
                                              float* __restrict__ C,
                                              int N, int K, int Mvalid) {
  __shared__ short lA[4096];
  __shared__ short lB[4096];
  const int tid = threadIdx.x;
  const int w = tid >> 6, l = tid & 63;
  const int lo = l & 15, hi = l >> 4;
  const int wr = w >> 1, wc = w & 1;
  const int brow = blockIdx.y * 128, bcol = blockIdx.x * 128;
  f32x4 acc[4][4] = {};
  const short* gA = A + (size_t)(brow + w * 32 + (l >> 2)) * K + ((l & 3) * 8);
  const short* gB = Bt + (size_t)(bcol + w * 32 + (l >> 2)) * K + ((l & 3) * 8);
  short* lAw = &lA[w * 1024];
  short* lBw = &lB[w * 1024];
  for (int k0 = 0; k0 < K; k0 += 32) {
    GLD16(gA + k0, lAw);
    GLD16(gA + (size_t)16 * K + k0, lAw + 512);
    GLD16(gB + k0, lBw);
    GLD16(gB + (size_t)16 * K + k0, lBw + 512);
    __syncthreads();
    s16x8 af[4], bf[4];
#pragma unroll
    for (int m = 0; m < 4; ++m)
      af[m] = *(const s16x8*)&lA[(wr * 64 + m * 16 + lo) * 32 + hi * 8];
#pragma unroll
    for (int n = 0; n < 4; ++n)
      bf[n] = *(const s16x8*)&lB[(wc * 64 + n * 16 + lo) * 32 + hi * 8];
#pragma unroll
    for (int m = 0; m < 4; ++m)
#pragma unroll
      for (int n = 0; n < 4; ++n)
        mfma16(acc[m][n], af[m], bf[n]);
    __syncthreads();
  }
#pragma unroll
  for (int n = 0; n < 4; ++n) {
    int c = bcol + wc * 64 + n * 16 + lo;
    float bs = bias[c];
#pragma unroll
    for (int m = 0; m < 4; ++m) {
      int r0 = brow + wr * 64 + m * 16 + 4 * hi;
#pragma unroll
      for (int r = 0; r < 4; ++r) {
        int rr = r0 + r;
        if (rr < Mvalid) C[(size_t)rr * N + c] = acc[m][n][r] + bs;
      }
    }
  }
}

// ---------------- bias'd QKV row post: rmsnorm+rope for q,k; v passthrough --

__global__ __launch_bounds__(256) void k_post(const float* __restrict__ qkv,
                                              const float* __restrict__ fc,
                                              const float* __restrict__ fs,
                                              const float* __restrict__ gq,
                                              const float* __restrict__ gk,
                                              short* __restrict__ Qb,
                                              short* __restrict__ Kb,
                                              short* __restrict__ Vr) {
  const int t = blockIdx.x, tid = threadIdx.x;
  __shared__ float buf[DIMM];
  __shared__ float red[4];
  const float* row = qkv + (size_t)t * NQKV;
  for (int sec = 0; sec < 2; ++sec) {
    const float* src = row + sec * DIMM;
    const float* g = sec ? gk : gq;
    float ssq = 0.f;
#pragma unroll
    for (int i = 0; i < 6; ++i) {
      float v = src[tid + i * 256];
      buf[tid + i * 256] = v;
      ssq += v * v;
    }
#pragma unroll
    for (int off = 32; off > 0; off >>= 1) ssq += __shfl_xor(ssq, off);
    if ((tid & 63) == 0) red[tid >> 6] = ssq;
    __syncthreads();
    float rms = rsqrtf((red[0] + red[1] + red[2] + red[3]) * (1.f / 1536.f) + 1e-6f);
    short* dst = sec ? (Kb + (size_t)(NEWB + t) * DIMM) : (Qb + (size_t)t * DIMM);
#pragma unroll
    for (int i = 0; i < 6; ++i) {
      int e = tid + i * 256;
      int d = e & 127;
      float vn = buf[e] * rms * g[e];
      float o;
      if (d < 64) {
        float v2 = buf[e + 64] * rms * g[e + 64];
        o = vn * fc[t * 64 + d] - v2 * fs[t * 64 + d];
      } else {
        float v1 = buf[e - 64] * rms * g[e - 64];
        o = v1 * fs[t * 64 + d - 64] + vn * fc[t * 64 + d - 64];
      }
      dst[e] = f2bf(o);
    }
    __syncthreads();
  }
#pragma unroll
  for (int i = 0; i < 6; ++i) {
    int e = tid + i * 256;
    Vr[(size_t)(NEWB + t) * DIMM + e] = f2bf(row[3072 + e]);
  }
}

// ---------------- V transpose: Vr[l][h*128+d] -> Vt[h][d][l] ----------------

__global__ __launch_bounds__(256) void k_transv(const short* __restrict__ Vr,
                                                short* __restrict__ Vt) {
  const int h = blockIdx.y;
  const int l0 = blockIdx.x * 32;
  const int tid = threadIdx.x;
  __shared__ short lt[128 * 34];
#pragma unroll
  for (int i = 0; i < 16; ++i) {
    int idx = i * 256 + tid;
    int li = idx >> 7;
    int d = idx & 127;
    lt[d * 34 + li] = Vr[(size_t)(l0 + li) * DIMM + h * HD + d];
  }
  __syncthreads();
#pragma unroll
  for (int i = 0; i < 16; ++i) {
    int idx = i * 256 + tid;
    int d = idx >> 5;
    int li = idx & 31;
    Vt[((size_t)h * HD + d) * LPAD + l0 + li] = lt[d * 34 + li];
  }
}

// ---------------- flash attention, key-split partials ----------------------
// block: 128 thr (2 waves), 16 q/wave; grid (49, 12, NSPLIT).
// split s handles tiles {s, s+4, ...}; writes (m, l, unnormalized O) f32.

__global__ __launch_bounds__(128) void k_attn(const short* __restrict__ Qb,
                                              const short* __restrict__ Kb,
                                              const short* __restrict__ Vt,
                                              float* __restrict__ pO0,
                                              float* __restrict__ pO3,
                                              float2* __restrict__ pML) {
  const int h = blockIdx.y;
  const int s = blockIdx.z;
  const int w = threadIdx.x >> 6;
  const int l = threadIdx.x & 63;
  const int lo = l & 15, hi = l >> 4;
  const int q0 = blockIdx.x * 32 + w * 16;
  __shared__ short lP[2][640];
  short* P = lP[w];

  s16x8 aq[4];
  const short* qp = Qb + (size_t)(q0 + lo) * DIMM + h * HD + hi * 8;
#pragma unroll
  for (int kk = 0; kk < 4; ++kk) aq[kk] = *(const s16x8*)(qp + kk * 32);

  f32x4 oacc[8];
#pragma unroll
  for (int n = 0; n < 8; ++n) oacc[n] = 0;
  float m_r[4], l_r[4];
#pragma unroll
  for (int r = 0; r < 4; ++r) { m_r[r] = -1e30f; l_r[r] = 0.f; }

  const short* Kp = Kb + (size_t)lo * DIMM + h * HD + hi * 8;
  const short* Vp = Vt + (size_t)h * HD * LPAD + hi * 8;

  for (int t = s; t < NTILE; t += NSPLIT) {
    const int kbv = t * 32;
    const short* kRow0 = Kp + (size_t)kbv * DIMM;
    const short* kRow1 = kRow0 + (size_t)16 * DIMM;
    f32x4 s0 = 0, s1 = 0;
#pragma unroll
    for (int kk = 0; kk < 4; ++kk) {
      s16x8 b0 = *(const s16x8*)(kRow0 + kk * 32);
      s16x8 b1 = *(const s16x8*)(kRow1 + kk * 32);
      mfma16(s0, aq[kk], b0);
      mfma16(s1, aq[kk], b1);
    }

    float sv0[4], sv1[4];
    const int key1 = kbv + 16 + lo;   // key0 = kbv+lo is always < LKV
#pragma unroll
    for (int r = 0; r < 4; ++r) {
      sv0[r] = s0[r] * ATT_SCALE;
      sv1[r] = (key1 < LKV) ? s1[r] * ATT_SCALE : -1e30f;
    }
    float mx[4];
#pragma unroll
    for (int r = 0; r < 4; ++r) mx[r] = fmaxf(sv0[r], sv1[r]);
#pragma unroll
    for (int off = 1; off < 16; off <<= 1) {
#pragma unroll
      for (int r = 0; r < 4; ++r) mx[r] = fmaxf(mx[r], __shfl_xor(mx[r], off));
    }
    float alpha[4], ps[4];
    short pb0[4], pb1[4];
#pragma unroll
    for (int r = 0; r < 4; ++r) {
      float mn = fmaxf(m_r[r], mx[r]);
      alpha[r] = __expf(m_r[r] - mn);
      m_r[r] = mn;
      float p0 = __expf(sv0[r] - mn);
      float p1 = __expf(sv1[r] - mn);
      ps[r] = p0 + p1;
      pb0[r] = f2bf(p0);
      pb1[r] = f2bf(p1);
    }
#pragma unroll
    for (int off = 1; off < 16; off <<= 1) {
#pragma unroll
      for (int r = 0; r < 4; ++r) ps[r] += __shfl_xor(ps[r], off);
    }
#pragma unroll
    for (int r = 0; r < 4; ++r) l_r[r] = l_r[r] * alpha[r] + ps[r];
#pragma unroll
    for (int n = 0; n < 8; ++n)
#pragma unroll
      for (int r = 0; r < 4; ++r) oacc[n][r] *= alpha[r];

    // P fragment redistribution through per-wave LDS (row stride 40 shorts)
#pragma unroll
    for (int r = 0; r < 4; ++r) {
      int row = 4 * hi + r;
      P[row * 40 + lo] = pb0[r];
      P[row * 40 + 16 + lo] = pb1[r];
    }
    s16x8 ap = *(const s16x8*)&P[lo * 40 + hi * 8];
#pragma unroll
    for (int n = 0; n < 8; ++n) {
      s16x8 bv = *(const s16x8*)(Vp + (size_t)(n * 16 + lo) * LPAD + kbv);
      mfma16(oacc[n], ap, bv);
    }
  }

  // write partials: O (unnormalized, f32), per-row (m, l)
  float* pOb = (s < 3) ? (pO0 + (size_t)(s * 12 + h) * 1560 * 128)
                       : (pO3 + (size_t)h * 1560 * 128);
#pragma unroll
  for (int n = 0; n < 8; ++n)
#pragma unroll
    for (int r = 0; r < 4; ++r) {
      int rr = q0 + 4 * hi + r;
      if (rr < 1560) pOb[(size_t)rr * 128 + n * 16 + lo] = oacc[n][r];
    }
  if (lo == 0) {
    float2* mlb = pML + (size_t)(s * 12 + h) * 1560;
#pragma unroll
    for (int r = 0; r < 4; ++r) {
      int rr = q0 + 4 * hi + r;
      if (rr < 1560) mlb[rr] = make_float2(m_r[r], l_r[r]);
    }
  }
}

// ---------------- combine partials -> Ob (bf16) ----------------------------
// grid (780, 12), 256 thr: each half-block handles one (t, h); d = tid&127.

__global__ __launch_bounds__(256) void k_comb(const float* __restrict__ pO0,
                                              const float* __restrict__ pO3,
                                              const float2* __restrict__ pML,
                                              short* __restrict__ Ob) {
  const int t = blockIdx.x * 2 + (threadIdx.x >> 7);
  const int h = blockIdx.y;
  const int d = threadIdx.x & 127;
  float2 ml[NSPLIT];
  float M = -1e30f;
#pragma unroll
  for (int s = 0; s < NSPLIT; ++s) {
    ml[s] = pML[((size_t)(s * 12 + h) * 1560) + t];
    M = fmaxf(M, ml[s].x);
  }
  float L = 0.f, o = 0.f;
#pragma unroll
  for (int s = 0; s < NSPLIT; ++s) {
    const float* pOb = (s < 3) ? (pO0 + (size_t)(s * 12 + h) * 1560 * 128)
                               : (pO3 + (size_t)h * 1560 * 128);
    float wgt = __expf(ml[s].x - M);
    L += ml[s].y * wgt;
    o += pOb[(size_t)t * 128 + d] * wgt;
  }
  Ob[(size_t)t * DIMM + h * HD + d] = f2bf(o / L);
}

// ---------------- launch ----------------

extern "C" void kernel_launch(void* const* d_in, const int* in_sizes, int n_in,
                              void* d_out, int out_size, void* d_ws, size_t ws_size,
                              hipStream_t stream) {
  (void)in_sizes; (void)n_in; (void)out_size;
  const float* x  = (const float*)d_in[0];
  const float* fc = (const float*)d_in[1];
  const float* fs = (const float*)d_in[2];
  const float* ck = (const float*)d_in[3];
  const float* cv = (const float*)d_in[4];
  const float* wq = (const float*)d_in[5];
  const float* p_bq = (const float*)d_in[6];
  const float* wk = (const float*)d_in[7];
  const float* p_bk = (const float*)d_in[8];
  const float* wv = (const float*)d_in[9];
  const float* p_bv = (const float*)d_in[10];
  const float* wo = (const float*)d_in[11];
  const float* p_bo = (const float*)d_in[12];
  const float* gq = (const float*)d_in[13];
  const float* gk = (const float*)d_in[14];
  float* out = (float*)d_out;

  char* ws = (char*)d_ws;
  if (ws_size < 117393408ull) return;
  short* xb   = (short*)(ws + 0);                 // 1664x1536 bf16 (alias Ob)
  short* ob   = xb;
  short* wqkv = (short*)(ws + 5111808);           // 4608x1536 bf16; partials s3+ML after QKV GEMM
  short* wob  = (short*)(ws + 19267584);          // 1536x1536 bf16
  float* bqkv = (float*)(ws + 23986176);          // 4608 f32
  float* qkvf = (float*)(ws + 24004608);          // 1664x4608 f32 (alias Vt)
  short* vt   = (short*)(ws + 24004608);          // 12x128x9376 bf16
  short* qb   = (short*)(ws + 54675456);          // 1664x1536 bf16
  short* kb   = (short*)(ws + 59787264);          // 9376x1536 bf16
  short* vr   = (short*)(ws + 88590336);          // 9376x1536 bf16; partials s0-2 after transv
  float*  pO0 = (float*)(ws + 88590336);          // 3 x 12x1560x128 f32 (28.75 MB)
  float*  pO3 = (float*)(ws + 5111808);           // 1 x 12x1560x128 f32 (9.58 MB)
  float2* pML = (float2*)(ws + 5111808 + 9584640);// 4 x 12x1560 float2 (600 KB)

  k_cvt_x<<<1248, 256, 0, stream>>>(x, xb);
  k_cvt<<<1152, 256, 0, stream>>>(wq, wqkv, 294912);
  k_cvt<<<1152, 256, 0, stream>>>(wk, wqkv + 1536 * 1536, 294912);
  k_cvt<<<1152, 256, 0, stream>>>(wv, wqkv + 2 * 1536 * 1536, 294912);
  k_cvt<<<1152, 256, 0, stream>>>(wo, wob, 294912);
  hipMemcpyAsync(bqkv, p_bq, 1536 * 4, hipMemcpyDeviceToDevice, stream);
  hipMemcpyAsync(bqkv + 1536, p_bk, 1536 * 4, hipMemcpyDeviceToDevice, stream);
  hipMemcpyAsync(bqkv + 3072, p_bv, 1536 * 4, hipMemcpyDeviceToDevice, stream);
  k_gather<<<5862, 256, 0, stream>>>(ck, kb);
  k_gather<<<5862, 256, 0, stream>>>(cv, vr);
  hipMemsetAsync(qb + (size_t)1560 * 1536, 0, 104 * 1536 * 2, stream);

  k_gemm<<<dim3(36, 13), 256, 0, stream>>>(xb, wqkv, bqkv, qkvf, 4608, 1536, 1664);
  // zero ob pad rows (combine writes rows < 1560; final GEMM stages 1664)
  hipMemsetAsync(ob + (size_t)1560 * 1536, 0, 104 * 1536 * 2, stream);
  k_post<<<1560, 256, 0, stream>>>(qkvf, fc, fs, gq, gk, qb, kb, vr);
  k_transv<<<dim3(293, 12), 256, 0, stream>>>(vr, vt);
  k_attn<<<dim3(49, 12, NSPLIT), 128, 0, stream>>>(qb, kb, vt, pO0, pO3, pML);
  k_comb<<<dim3(780, 12), 256, 0, stream>>>(pO0, pO3, pML, ob);
  k_gemm<<<dim3(12, 13), 256, 0, stream>>>(ob, wob, p_bo, out, 1536, 1536, 1560);
}

// Round 8
// 696.950 us; speedup vs baseline: 34.4136x; 1.1200x over previous
//
#include <hip/hip_runtime.h>

typedef short s16x8 __attribute__((ext_vector_type(8)));
typedef __bf16 bf16x8 __attribute__((ext_vector_type(8)));
typedef float f32x4 __attribute__((ext_vector_type(4)));

#define T_NEW 1560
#define MPAD  1664
#define DIMM  1536
#define NQKV  4608
#define LKV   9360
#define LPAD  9376
#define NEWB  7800
#define HD    128
#define NSPLIT 4
#define NTILE  293          /* ceil(9360/32) */
#define ATT_SCALE 0.08838834764831845f

static __device__ __forceinline__ short f2bf(float f) {
  unsigned u = __builtin_bit_cast(unsigned, f);
  u = (u + 0x7fffu + ((u >> 16) & 1u)) >> 16;
  return (short)u;
}

static __device__ __forceinline__ float bf2f(short s) {
  unsigned u = ((unsigned)(unsigned short)s) << 16;
  return __builtin_bit_cast(float, u);
}

// builtin MFMA: compiler models latency + inserts MFMA->VALU wait states
// (raw inline-asm MFMA lacks hazard handling -> stale VALU reads; r2-r5 bug)
static __device__ __forceinline__ void mfma16(f32x4& d, s16x8 a, s16x8 b) {
  d = __builtin_amdgcn_mfma_f32_16x16x32_bf16(
      __builtin_bit_cast(bf16x8, a), __builtin_bit_cast(bf16x8, b), d, 0, 0, 0);
}

#define GLD16(gp, lp) __builtin_amdgcn_global_load_lds(                  \
    (const __attribute__((address_space(1))) void*)(gp),                 \
    (__attribute__((address_space(3))) void*)(lp), 16, 0, 0)

// ---------------- conversion kernels ----------------

__global__ __launch_bounds__(256) void k_cvt(const float* __restrict__ s,
                                             short* __restrict__ d, int n8) {
  int i = blockIdx.x * 256 + threadIdx.x;
  if (i >= n8) return;
  const f32x4* p = (const f32x4*)s + (size_t)i * 2;
  f32x4 a = p[0], b = p[1];
  s16x8 o;
  o[0]=f2bf(a[0]); o[1]=f2bf(a[1]); o[2]=f2bf(a[2]); o[3]=f2bf(a[3]);
  o[4]=f2bf(b[0]); o[5]=f2bf(b[1]); o[6]=f2bf(b[2]); o[7]=f2bf(b[3]);
  *((s16x8*)d + i) = o;
}

// x (1560x1536) -> bf16 padded to 1664 rows (pad rows = 0)
__global__ __launch_bounds__(256) void k_cvt_x(const float* __restrict__ s,
                                               short* __restrict__ d) {
  int i = blockIdx.x * 256 + threadIdx.x;   // over MPAD*192
  s16x8 o;
  if (i < T_NEW * (DIMM / 8)) {
    const f32x4* p = (const f32x4*)s + (size_t)i * 2;
    f32x4 a = p[0], b = p[1];
    o[0]=f2bf(a[0]); o[1]=f2bf(a[1]); o[2]=f2bf(a[2]); o[3]=f2bf(a[3]);
    o[4]=f2bf(b[0]); o[5]=f2bf(b[1]); o[6]=f2bf(b[2]); o[7]=f2bf(b[3]);
  } else {
    o = 0;
  }
  *((s16x8*)d + i) = o;
}

// cache (9360x1536 f32) -> dst rows [0,7800) with roll, rows [9360,9376) zero
__global__ __launch_bounds__(256) void k_gather(const float* __restrict__ src,
                                                short* __restrict__ dst) {
  int i = blockIdx.x * 256 + threadIdx.x;   // over 7816*192
  int vrow = i / 192;
  int c8 = i - vrow * 192;
  s16x8 o;
  int drow;
  if (vrow < NEWB) {
    drow = vrow;
    int srow = (vrow < 1560) ? vrow : vrow + 1560;
    const f32x4* p = (const f32x4*)(src + (size_t)srow * DIMM + c8 * 8);
    f32x4 a = p[0], b = p[1];
    o[0]=f2bf(a[0]); o[1]=f2bf(a[1]); o[2]=f2bf(a[2]); o[3]=f2bf(a[3]);
    o[4]=f2bf(b[0]); o[5]=f2bf(b[1]); o[6]=f2bf(b[2]); o[7]=f2bf(b[3]);
  } else {
    drow = LKV + (vrow - NEWB);
    o = 0;
  }
  *(s16x8*)(dst + (size_t)drow * DIMM + c8 * 8) = o;
}

// ---------------- GEMM: C[M,N] = A[M,K] * Bt[N,K]^T + bias ----------------

__global__ __launch_bounds__(256) void k_gemm(const short* __restrict__ A,
                                              const short* __restrict__ Bt,
                                              const float* __restrict__ bias,
                                              float* __restrict__ C,
                                              int N, int K, int Mvalid) {
  __shared__ short lA[4096];
  __shared__ short lB[4096];
  const int tid = threadIdx.x;
  const int w = tid >> 6, l = tid & 63;
  const int lo = l & 15, hi = l >> 4;
  const int wr = w >> 1, wc = w & 1;
  const int brow = blockIdx.y * 128, bcol = blockIdx.x * 128;
  f32x4 acc[4][4] = {};
  const short* gA = A + (size_t)(brow + w * 32 + (l >> 2)) * K + ((l & 3) * 8);
  const short* gB = Bt + (size_t)(bcol + w * 32 + (l >> 2)) * K + ((l & 3) * 8);
  short* lAw = &lA[w * 1024];
  short* lBw = &lB[w * 1024];
  for (int k0 = 0; k0 < K; k0 += 32) {
    GLD16(gA + k0, lAw);
    GLD16(gA + (size_t)16 * K + k0, lAw + 512);
    GLD16(gB + k0, lBw);
    GLD16(gB + (size_t)16 * K + k0, lBw + 512);
    __syncthreads();
    s16x8 af[4], bf[4];
#pragma unroll
    for (int m = 0; m < 4; ++m)
      af[m] = *(const s16x8*)&lA[(wr * 64 + m * 16 + lo) * 32 + hi * 8];
#pragma unroll
    for (int n = 0; n < 4; ++n)
      bf[n] = *(const s16x8*)&lB[(wc * 64 + n * 16 + lo) * 32 + hi * 8];
#pragma unroll
    for (int m = 0; m < 4; ++m)
#pragma unroll
      for (int n = 0; n < 4; ++n)
        mfma16(acc[m][n], af[m], bf[n]);
    __syncthreads();
  }
#pragma unroll
  for (int n = 0; n < 4; ++n) {
    int c = bcol + wc * 64 + n * 16 + lo;
    float bs = bias[c];
#pragma unroll
    for (int m = 0; m < 4; ++m) {
      int r0 = brow + wr * 64 + m * 16 + 4 * hi;
#pragma unroll
      for (int r = 0; r < 4; ++r) {
        int rr = r0 + r;
        if (rr < Mvalid) C[(size_t)rr * N + c] = acc[m][n][r] + bs;
      }
    }
  }
}

// ---------------- bias'd QKV row post: rmsnorm+rope for q,k; v passthrough --

__global__ __launch_bounds__(256) void k_post(const float* __restrict__ qkv,
                                              const float* __restrict__ fc,
                                              const float* __restrict__ fs,
                                              const float* __restrict__ gq,
                                              const float* __restrict__ gk,
                                              short* __restrict__ Qb,
                                              short* __restrict__ Kb,
                                              short* __restrict__ Vr) {
  const int t = blockIdx.x, tid = threadIdx.x;
  __shared__ float buf[DIMM];
  __shared__ float red[4];
  const float* row = qkv + (size_t)t * NQKV;
  for (int sec = 0; sec < 2; ++sec) {
    const float* src = row + sec * DIMM;
    const float* g = sec ? gk : gq;
    float ssq = 0.f;
#pragma unroll
    for (int i = 0; i < 6; ++i) {
      float v = src[tid + i * 256];
      buf[tid + i * 256] = v;
      ssq += v * v;
    }
#pragma unroll
    for (int off = 32; off > 0; off >>= 1) ssq += __shfl_xor(ssq, off);
    if ((tid & 63) == 0) red[tid >> 6] = ssq;
    __syncthreads();
    float rms = rsqrtf((red[0] + red[1] + red[2] + red[3]) * (1.f / 1536.f) + 1e-6f);
    short* dst = sec ? (Kb + (size_t)(NEWB + t) * DIMM) : (Qb + (size_t)t * DIMM);
#pragma unroll
    for (int i = 0; i < 6; ++i) {
      int e = tid + i * 256;
      int d = e & 127;
      float vn = buf[e] * rms * g[e];
      float o;
      if (d < 64) {
        float v2 = buf[e + 64] * rms * g[e + 64];
        o = vn * fc[t * 64 + d] - v2 * fs[t * 64 + d];
      } else {
        float v1 = buf[e - 64] * rms * g[e - 64];
        o = v1 * fs[t * 64 + d - 64] + vn * fc[t * 64 + d - 64];
      }
      dst[e] = f2bf(o);
    }
    __syncthreads();
  }
#pragma unroll
  for (int i = 0; i < 6; ++i) {
    int e = tid + i * 256;
    Vr[(size_t)(NEWB + t) * DIMM + e] = f2bf(row[3072 + e]);
  }
}

// ---------------- V transpose: Vr[l][h*128+d] -> Vt[h][d][l] ----------------

__global__ __launch_bounds__(256) void k_transv(const short* __restrict__ Vr,
                                                short* __restrict__ Vt) {
  const int h = blockIdx.y;
  const int l0 = blockIdx.x * 32;
  const int tid = threadIdx.x;
  __shared__ short lt[128 * 34];
#pragma unroll
  for (int i = 0; i < 16; ++i) {
    int idx = i * 256 + tid;
    int li = idx >> 7;
    int d = idx & 127;
    lt[d * 34 + li] = Vr[(size_t)(l0 + li) * DIMM + h * HD + d];
  }
  __syncthreads();
#pragma unroll
  for (int i = 0; i < 16; ++i) {
    int idx = i * 256 + tid;
    int d = idx >> 5;
    int li = idx & 31;
    Vt[((size_t)h * HD + d) * LPAD + l0 + li] = lt[d * 34 + li];
  }
}

// ---------------- flash attention, key-split + K-tile reg prefetch ---------
// block: 128 thr (2 waves), 16 q/wave; grid (49, 12, NSPLIT).
// Ping-pong K fragment buffers hide K-load latency under prev tile's compute.

#define LOADK(buf, tt) do {                                              \
    const short* nR0 = Kp + (size_t)((tt) * 32) * DIMM;                  \
    const short* nR1 = nR0 + (size_t)16 * DIMM;                          \
    _Pragma("unroll")                                                    \
    for (int kk = 0; kk < 4; ++kk) {                                     \
      buf[kk] = *(const s16x8*)(nR0 + kk * 32);                          \
      buf[4 + kk] = *(const s16x8*)(nR1 + kk * 32);                      \
    } } while (0)

__global__ __launch_bounds__(128, 3) void k_attn(const short* __restrict__ Qb,
                                                 const short* __restrict__ Kb,
                                                 const short* __restrict__ Vt,
                                                 float* __restrict__ pO0,
                                                 float* __restrict__ pO3,
                                                 float2* __restrict__ pML) {
  const int h = blockIdx.y;
  const int s = blockIdx.z;
  const int w = threadIdx.x >> 6;
  const int l = threadIdx.x & 63;
  const int lo = l & 15, hi = l >> 4;
  const int q0 = blockIdx.x * 32 + w * 16;
  __shared__ short lP[2][640];
  short* P = lP[w];

  s16x8 aq[4];
  const short* qp = Qb + (size_t)(q0 + lo) * DIMM + h * HD + hi * 8;
#pragma unroll
  for (int kk = 0; kk < 4; ++kk) aq[kk] = *(const s16x8*)(qp + kk * 32);

  f32x4 oacc[8];
#pragma unroll
  for (int n = 0; n < 8; ++n) oacc[n] = 0;
  float m_r[4], l_r[4];
#pragma unroll
  for (int r = 0; r < 4; ++r) { m_r[r] = -1e30f; l_r[r] = 0.f; }

  const short* Kp = Kb + (size_t)lo * DIMM + h * HD + hi * 8;
  const short* Vp = Vt + (size_t)h * HD * LPAD + hi * 8;

  auto body = [&](int kbv, s16x8* kc) {
    f32x4 s0 = 0, s1 = 0;
#pragma unroll
    for (int kk = 0; kk < 4; ++kk) {
      mfma16(s0, aq[kk], kc[kk]);
      mfma16(s1, aq[kk], kc[4 + kk]);
    }
    float sv0[4], sv1[4];
    const int key1 = kbv + 16 + lo;   // key0 = kbv+lo is always < LKV
#pragma unroll
    for (int r = 0; r < 4; ++r) {
      sv0[r] = s0[r] * ATT_SCALE;
      sv1[r] = (key1 < LKV) ? s1[r] * ATT_SCALE : -1e30f;
    }
    float mx[4];
#pragma unroll
    for (int r = 0; r < 4; ++r) mx[r] = fmaxf(sv0[r], sv1[r]);
#pragma unroll
    for (int off = 1; off < 16; off <<= 1) {
#pragma unroll
      for (int r = 0; r < 4; ++r) mx[r] = fmaxf(mx[r], __shfl_xor(mx[r], off));
    }
    float alpha[4], ps[4];
    short pb0[4], pb1[4];
#pragma unroll
    for (int r = 0; r < 4; ++r) {
      float mn = fmaxf(m_r[r], mx[r]);
      alpha[r] = __expf(m_r[r] - mn);
      m_r[r] = mn;
      float p0 = __expf(sv0[r] - mn);
      float p1 = __expf(sv1[r] - mn);
      ps[r] = p0 + p1;
      pb0[r] = f2bf(p0);
      pb1[r] = f2bf(p1);
    }
#pragma unroll
    for (int off = 1; off < 16; off <<= 1) {
#pragma unroll
      for (int r = 0; r < 4; ++r) ps[r] += __shfl_xor(ps[r], off);
    }
#pragma unroll
    for (int r = 0; r < 4; ++r) l_r[r] = l_r[r] * alpha[r] + ps[r];
#pragma unroll
    for (int n = 0; n < 8; ++n)
#pragma unroll
      for (int r = 0; r < 4; ++r) oacc[n][r] *= alpha[r];

    // P fragment redistribution through per-wave LDS (row stride 40 shorts)
#pragma unroll
    for (int r = 0; r < 4; ++r) {
      int row = 4 * hi + r;
      P[row * 40 + lo] = pb0[r];
      P[row * 40 + 16 + lo] = pb1[r];
    }
    s16x8 ap = *(const s16x8*)&P[lo * 40 + hi * 8];
#pragma unroll
    for (int n = 0; n < 8; ++n) {
      s16x8 bv = *(const s16x8*)(Vp + (size_t)(n * 16 + lo) * LPAD + kbv);
      mfma16(oacc[n], ap, bv);
    }
  };

  s16x8 bufA[8], bufB[8];
  int t = s;
  LOADK(bufA, t);
  while (true) {
    int t1 = t + NSPLIT;
    LOADK(bufB, (t1 < NTILE ? t1 : t));
    body(t * 32, bufA);
    if (t1 >= NTILE) break;
    int t2 = t1 + NSPLIT;
    LOADK(bufA, (t2 < NTILE ? t2 : t1));
    body(t1 * 32, bufB);
    if (t2 >= NTILE) break;
    t = t2;
  }

  // write partials: O (unnormalized, f32), per-row (m, l)
  float* pOb = (s < 3) ? (pO0 + (size_t)(s * 12 + h) * 1560 * 128)
                       : (pO3 + (size_t)h * 1560 * 128);
#pragma unroll
  for (int n = 0; n < 8; ++n)
#pragma unroll
    for (int r = 0; r < 4; ++r) {
      int rr = q0 + 4 * hi + r;
      if (rr < 1560) pOb[(size_t)rr * 128 + n * 16 + lo] = oacc[n][r];
    }
  if (lo == 0) {
    float2* mlb = pML + (size_t)(s * 12 + h) * 1560;
#pragma unroll
    for (int r = 0; r < 4; ++r) {
      int rr = q0 + 4 * hi + r;
      if (rr < 1560) mlb[rr] = make_float2(m_r[r], l_r[r]);
    }
  }
}

// ---------------- combine partials -> Ob (bf16) ----------------------------
// grid (780, 12), 256 thr: each half-block handles one (t, h); d = tid&127.

__global__ __launch_bounds__(256) void k_comb(const float* __restrict__ pO0,
                                              const float* __restrict__ pO3,
                                              const float2* __restrict__ pML,
                                              short* __restrict__ Ob) {
  const int t = blockIdx.x * 2 + (threadIdx.x >> 7);
  const int h = blockIdx.y;
  const int d = threadIdx.x & 127;
  float2 ml[NSPLIT];
  float M = -1e30f;
#pragma unroll
  for (int s = 0; s < NSPLIT; ++s) {
    ml[s] = pML[((size_t)(s * 12 + h) * 1560) + t];
    M = fmaxf(M, ml[s].x);
  }
  float L = 0.f, o = 0.f;
#pragma unroll
  for (int s = 0; s < NSPLIT; ++s) {
    const float* pOb = (s < 3) ? (pO0 + (size_t)(s * 12 + h) * 1560 * 128)
                               : (pO3 + (size_t)h * 1560 * 128);
    float wgt = __expf(ml[s].x - M);
    L += ml[s].y * wgt;
    o += pOb[(size_t)t * 128 + d] * wgt;
  }
  Ob[(size_t)t * DIMM + h * HD + d] = f2bf(o / L);
}

// ---------------- launch ----------------

extern "C" void kernel_launch(void* const* d_in, const int* in_sizes, int n_in,
                              void* d_out, int out_size, void* d_ws, size_t ws_size,
                              hipStream_t stream) {
  (void)in_sizes; (void)n_in; (void)out_size;
  const float* x  = (const float*)d_in[0];
  const float* fc = (const float*)d_in[1];
  const float* fs = (const float*)d_in[2];
  const float* ck = (const float*)d_in[3];
  const float* cv = (const float*)d_in[4];
  const float* wq = (const float*)d_in[5];
  const float* p_bq = (const float*)d_in[6];
  const float* wk = (const float*)d_in[7];
  const float* p_bk = (const float*)d_in[8];
  const float* wv = (const float*)d_in[9];
  const float* p_bv = (const float*)d_in[10];
  const float* wo = (const float*)d_in[11];
  const float* p_bo = (const float*)d_in[12];
  const float* gq = (const float*)d_in[13];
  const float* gk = (const float*)d_in[14];
  float* out = (float*)d_out;

  char* ws = (char*)d_ws;
  if (ws_size < 117393408ull) return;
  short* xb   = (short*)(ws + 0);                 // 1664x1536 bf16 (alias Ob)
  short* ob   = xb;
  short* wqkv = (short*)(ws + 5111808);           // 4608x1536 bf16; partials s3+ML after QKV GEMM
  short* wob  = (short*)(ws + 19267584);          // 1536x1536 bf16
  float* bqkv = (float*)(ws + 23986176);          // 4608 f32
  float* qkvf = (float*)(ws + 24004608);          // 1664x4608 f32 (alias Vt)
  short* vt   = (short*)(ws + 24004608);          // 12x128x9376 bf16
  short* qb   = (short*)(ws + 54675456);          // 1664x1536 bf16
  short* kb   = (short*)(ws + 59787264);          // 9376x1536 bf16
  short* vr   = (short*)(ws + 88590336);          // 9376x1536 bf16; partials s0-2 after transv
  float*  pO0 = (float*)(ws + 88590336);          // 3 x 12x1560x128 f32 (28.75 MB)
  float*  pO3 = (float*)(ws + 5111808);           // 1 x 12x1560x128 f32 (9.58 MB)
  float2* pML = (float2*)(ws + 5111808 + 9584640);// 4 x 12x1560 float2 (600 KB)

  k_cvt_x<<<1248, 256, 0, stream>>>(x, xb);
  k_cvt<<<1152, 256, 0, stream>>>(wq, wqkv, 294912);
  k_cvt<<<1152, 256, 0, stream>>>(wk, wqkv + 1536 * 1536, 294912);
  k_cvt<<<1152, 256, 0, stream>>>(wv, wqkv + 2 * 1536 * 1536, 294912);
  k_cvt<<<1152, 256, 0, stream>>>(wo, wob, 294912);
  hipMemcpyAsync(bqkv, p_bq, 1536 * 4, hipMemcpyDeviceToDevice, stream);
  hipMemcpyAsync(bqkv + 1536, p_bk, 1536 * 4, hipMemcpyDeviceToDevice, stream);
  hipMemcpyAsync(bqkv + 3072, p_bv, 1536 * 4, hipMemcpyDeviceToDevice, stream);
  k_gather<<<5862, 256, 0, stream>>>(ck, kb);
  k_gather<<<5862, 256, 0, stream>>>(cv, vr);
  hipMemsetAsync(qb + (size_t)1560 * 1536, 0, 104 * 1536 * 2, stream);

  k_gemm<<<dim3(36, 13), 256, 0, stream>>>(xb, wqkv, bqkv, qkvf, 4608, 1536, 1664);
  // zero ob pad rows (combine writes rows < 1560; final GEMM stages 1664)
  hipMemsetAsync(ob + (size_t)1560 * 1536, 0, 104 * 1536 * 2, stream);
  k_post<<<1560, 256, 0, stream>>>(qkvf, fc, fs, gq, gk, qb, kb, vr);
  k_transv<<<dim3(293, 12), 256, 0, stream>>>(vr, vt);
  k_attn<<<dim3(49, 12, NSPLIT), 128, 0, stream>>>(qb, kb, vt, pO0, pO3, pML);
  k_comb<<<dim3(780, 12), 256, 0, stream>>>(pO0, pO3, pML, ob);
  k_gemm<<<dim3(12, 13), 256, 0, stream>>>(ob, wob, p_bo, out, 1536, 1536, 1560);
}

// Round 9
// 468.958 us; speedup vs baseline: 51.1444x; 1.4862x over previous
//
#include <hip/hip_runtime.h>

typedef short s16x8 __attribute__((ext_vector_type(8)));
typedef __bf16 bf16x8 __attribute__((ext_vector_type(8)));
typedef float f32x4 __attribute__((ext_vector_type(4)));

#define T_NEW 1560
#define MPAD  1664
#define DIMM  1536
#define NQKV  4608
#define LKV   9360
#define LPAD  9376
#define NEWB  7800
#define HD    128
#define NSPLIT 4
#define NTILE  293          /* ceil(9360/32) */
#define ATT_SCALE 0.08838834764831845f

static __device__ __forceinline__ short f2bf(float f) {
  unsigned u = __builtin_bit_cast(unsigned, f);
  u = (u + 0x7fffu + ((u >> 16) & 1u)) >> 16;
  return (short)u;
}

static __device__ __forceinline__ float bf2f(short s) {
  unsigned u = ((unsigned)(unsigned short)s) << 16;
  return __builtin_bit_cast(float, u);
}

// builtin MFMA: compiler models latency + inserts MFMA->VALU wait states
// (raw inline-asm MFMA lacks hazard handling -> stale VALU reads; r2-r5 bug)
static __device__ __forceinline__ void mfma16(f32x4& d, s16x8 a, s16x8 b) {
  d = __builtin_amdgcn_mfma_f32_16x16x32_bf16(
      __builtin_bit_cast(bf16x8, a), __builtin_bit_cast(bf16x8, b), d, 0, 0, 0);
}

#define GLD16(gp, lp) __builtin_amdgcn_global_load_lds(                  \
    (const __attribute__((address_space(1))) void*)(gp),                 \
    (__attribute__((address_space(3))) void*)(lp), 16, 0, 0)

// ---------------- conversion kernels ----------------

__global__ __launch_bounds__(256) void k_cvt(const float* __restrict__ s,
                                             short* __restrict__ d, int n8) {
  int i = blockIdx.x * 256 + threadIdx.x;
  if (i >= n8) return;
  const f32x4* p = (const f32x4*)s + (size_t)i * 2;
  f32x4 a = p[0], b = p[1];
  s16x8 o;
  o[0]=f2bf(a[0]); o[1]=f2bf(a[1]); o[2]=f2bf(a[2]); o[3]=f2bf(a[3]);
  o[4]=f2bf(b[0]); o[5]=f2bf(b[1]); o[6]=f2bf(b[2]); o[7]=f2bf(b[3]);
  *((s16x8*)d + i) = o;
}

// x (1560x1536) -> bf16 padded to 1664 rows (pad rows = 0)
__global__ __launch_bounds__(256) void k_cvt_x(const float* __restrict__ s,
                                               short* __restrict__ d) {
  int i = blockIdx.x * 256 + threadIdx.x;   // over MPAD*192
  s16x8 o;
  if (i < T_NEW * (DIMM / 8)) {
    const f32x4* p = (const f32x4*)s + (size_t)i * 2;
    f32x4 a = p[0], b = p[1];
    o[0]=f2bf(a[0]); o[1]=f2bf(a[1]); o[2]=f2bf(a[2]); o[3]=f2bf(a[3]);
    o[4]=f2bf(b[0]); o[5]=f2bf(b[1]); o[6]=f2bf(b[2]); o[7]=f2bf(b[3]);
  } else {
    o = 0;
  }
  *((s16x8*)d + i) = o;
}

// cache (9360x1536 f32) -> dst rows [0,7800) with roll, rows [9360,9376) zero
__global__ __launch_bounds__(256) void k_gather(const float* __restrict__ src,
                                                short* __restrict__ dst) {
  int i = blockIdx.x * 256 + threadIdx.x;   // over 7816*192
  int vrow = i / 192;
  int c8 = i - vrow * 192;
  s16x8 o;
  int drow;
  if (vrow < NEWB) {
    drow = vrow;
    int srow = (vrow < 1560) ? vrow : vrow + 1560;
    const f32x4* p = (const f32x4*)(src + (size_t)srow * DIMM + c8 * 8);
    f32x4 a = p[0], b = p[1];
    o[0]=f2bf(a[0]); o[1]=f2bf(a[1]); o[2]=f2bf(a[2]); o[3]=f2bf(a[3]);
    o[4]=f2bf(b[0]); o[5]=f2bf(b[1]); o[6]=f2bf(b[2]); o[7]=f2bf(b[3]);
  } else {
    drow = LKV + (vrow - NEWB);
    o = 0;
  }
  *(s16x8*)(dst + (size_t)drow * DIMM + c8 * 8) = o;
}

// ---------------- GEMM: C[M,N] = A[M,K] * Bt[N,K]^T + bias ----------------

__global__ __launch_bounds__(256) void k_gemm(const short* __restrict__ A,
                                              const short* __restrict__ Bt,
                                              const float* __restrict__ bias,
                                              float* __restrict__ C,
                                              int N, int K, int Mvalid) {
  __shared__ short lA[4096];
  __shared__ short lB[4096];
  const int tid = threadIdx.x;
  const int w = tid >> 6, l = tid & 63;
  const int lo = l & 15, hi = l >> 4;
  const int wr = w >> 1, wc = w & 1;
  const int brow = blockIdx.y * 128, bcol = blockIdx.x * 128;
  f32x4 acc[4][4] = {};
  const short* gA = A + (size_t)(brow + w * 32 + (l >> 2)) * K + ((l & 3) * 8);
  const short* gB = Bt + (size_t)(bcol + w * 32 + (l >> 2)) * K + ((l & 3) * 8);
  short* lAw = &lA[w * 1024];
  short* lBw = &lB[w * 1024];
  for (int k0 = 0; k0 < K; k0 += 32) {
    GLD16(gA + k0, lAw);
    GLD16(gA + (size_t)16 * K + k0, lAw + 512);
    GLD16(gB + k0, lBw);
    GLD16(gB + (size_t)16 * K + k0, lBw + 512);
    __syncthreads();
    s16x8 af[4], bf[4];
#pragma unroll
    for (int m = 0; m < 4; ++m)
      af[m] = *(const s16x8*)&lA[(wr * 64 + m * 16 + lo) * 32 + hi * 8];
#pragma unroll
    for (int n = 0; n < 4; ++n)
      bf[n] = *(const s16x8*)&lB[(wc * 64 + n * 16 + lo) * 32 + hi * 8];
#pragma unroll
    for (int m = 0; m < 4; ++m)
#pragma unroll
      for (int n = 0; n < 4; ++n)
        mfma16(acc[m][n], af[m], bf[n]);
    __syncthreads();
  }
#pragma unroll
  for (int n = 0; n < 4; ++n) {
    int c = bcol + wc * 64 + n * 16 + lo;
    float bs = bias[c];
#pragma unroll
    for (int m = 0; m < 4; ++m) {
      int r0 = brow + wr * 64 + m * 16 + 4 * hi;
#pragma unroll
      for (int r = 0; r < 4; ++r) {
        int rr = r0 + r;
        if (rr < Mvalid) C[(size_t)rr * N + c] = acc[m][n][r] + bs;
      }
    }
  }
}

// ---------------- bias'd QKV row post: rmsnorm+rope for q,k; v passthrough --

__global__ __launch_bounds__(256) void k_post(const float* __restrict__ qkv,
                                              const float* __restrict__ fc,
                                              const float* __restrict__ fs,
                                              const float* __restrict__ gq,
                                              const float* __restrict__ gk,
                                              short* __restrict__ Qb,
                                              short* __restrict__ Kb,
                                              short* __restrict__ Vr) {
  const int t = blockIdx.x, tid = threadIdx.x;
  __shared__ float buf[DIMM];
  __shared__ float red[4];
  const float* row = qkv + (size_t)t * NQKV;
  for (int sec = 0; sec < 2; ++sec) {
    const float* src = row + sec * DIMM;
    const float* g = sec ? gk : gq;
    float ssq = 0.f;
#pragma unroll
    for (int i = 0; i < 6; ++i) {
      float v = src[tid + i * 256];
      buf[tid + i * 256] = v;
      ssq += v * v;
    }
#pragma unroll
    for (int off = 32; off > 0; off >>= 1) ssq += __shfl_xor(ssq, off);
    if ((tid & 63) == 0) red[tid >> 6] = ssq;
    __syncthreads();
    float rms = rsqrtf((red[0] + red[1] + red[2] + red[3]) * (1.f / 1536.f) + 1e-6f);
    short* dst = sec ? (Kb + (size_t)(NEWB + t) * DIMM) : (Qb + (size_t)t * DIMM);
#pragma unroll
    for (int i = 0; i < 6; ++i) {
      int e = tid + i * 256;
      int d = e & 127;
      float vn = buf[e] * rms * g[e];
      float o;
      if (d < 64) {
        float v2 = buf[e + 64] * rms * g[e + 64];
        o = vn * fc[t * 64 + d] - v2 * fs[t * 64 + d];
      } else {
        float v1 = buf[e - 64] * rms * g[e - 64];
        o = v1 * fs[t * 64 + d - 64] + vn * fc[t * 64 + d - 64];
      }
      dst[e] = f2bf(o);
    }
    __syncthreads();
  }
#pragma unroll
  for (int i = 0; i < 6; ++i) {
    int e = tid + i * 256;
    Vr[(size_t)(NEWB + t) * DIMM + e] = f2bf(row[3072 + e]);
  }
}

// ---------------- V transpose: Vr[l][h*128+d] -> Vt[h][d][l] ----------------

__global__ __launch_bounds__(256) void k_transv(const short* __restrict__ Vr,
                                                short* __restrict__ Vt) {
  const int h = blockIdx.y;
  const int l0 = blockIdx.x * 32;
  const int tid = threadIdx.x;
  __shared__ short lt[128 * 34];
#pragma unroll
  for (int i = 0; i < 16; ++i) {
    int idx = i * 256 + tid;
    int li = idx >> 7;
    int d = idx & 127;
    lt[d * 34 + li] = Vr[(size_t)(l0 + li) * DIMM + h * HD + d];
  }
  __syncthreads();
#pragma unroll
  for (int i = 0; i < 16; ++i) {
    int idx = i * 256 + tid;
    int d = idx >> 5;
    int li = idx & 31;
    Vt[((size_t)h * HD + d) * LPAD + l0 + li] = lt[d * 34 + li];
  }
}

// ---------------- flash attention: key-split + LDS-staged K/V double-buffer -
// block: 256 thr (4 waves), 16 q/wave = 64 q/block; grid (25, 12, NSPLIT).
// K/V tiles staged once per block via global_load_lds; K swizzled (row&7)<<4
// with pre-swizzled global source (both-sides involution); V rows 64B: no swz.

__global__ __launch_bounds__(256, 4) void k_attn(const short* __restrict__ Qb,
                                                 const short* __restrict__ Kb,
                                                 const short* __restrict__ Vt,
                                                 float* __restrict__ pO0,
                                                 float* __restrict__ pO3,
                                                 float2* __restrict__ pML) {
  const int h = blockIdx.y;
  const int s = blockIdx.z;
  const int w = threadIdx.x >> 6;
  const int l = threadIdx.x & 63;
  const int lo = l & 15, hi = l >> 4;
  const int q0 = blockIdx.x * 64 + w * 16;
  __shared__ __align__(16) char lK[2][8192];   // 32 keys x 256B, swizzled
  __shared__ __align__(16) char lV[2][8192];   // 128 dims x 64B, linear
  __shared__ short lP[4][640];
  short* P = lP[w];

  s16x8 aq[4];
  const short* qp = Qb + (size_t)(q0 + lo) * DIMM + h * HD + hi * 8;
#pragma unroll
  for (int kk = 0; kk < 4; ++kk) aq[kk] = *(const s16x8*)(qp + kk * 32);

  f32x4 oacc[8];
#pragma unroll
  for (int n = 0; n < 8; ++n) oacc[n] = 0;
  float m_r[4], l_r[4];
#pragma unroll
  for (int r = 0; r < 4; ++r) { m_r[r] = -1e30f; l_r[r] = 0.f; }

  const short* Kh = Kb + h * HD;
  const short* Vh = Vt + (size_t)h * HD * LPAD;

  // stage one 8KB K tile + 8KB V tile (block-cooperative, 2 chunks/wave each)
  auto stage = [&](int cur, int tile) {
#pragma unroll
    for (int j = 0; j < 2; ++j) {
      int chunk = j * 4 + w;
      int r = chunk * 4 + (l >> 4);
      int cb = ((l & 15) * 16) ^ ((r & 7) << 4);   // pre-swizzled source col
      GLD16(Kh + (size_t)(tile * 32 + r) * DIMM + (cb >> 1),
            &lK[cur][chunk * 1024]);
    }
#pragma unroll
    for (int j = 0; j < 2; ++j) {
      int chunk = j * 4 + w;
      int dim = chunk * 16 + (l >> 2);
      GLD16(Vh + (size_t)dim * LPAD + tile * 32 + (l & 3) * 8,
            &lV[cur][chunk * 1024]);
    }
  };

  auto body = [&](int kbv, int cur) {
    const int swz = (lo & 7) << 4;
    f32x4 s0 = 0, s1 = 0;
#pragma unroll
    for (int kk = 0; kk < 4; ++kk) {
      s16x8 b0 = *(const s16x8*)(lK[cur] + lo * 256 + ((kk * 64 + hi * 16) ^ swz));
      s16x8 b1 = *(const s16x8*)(lK[cur] + (16 + lo) * 256 + ((kk * 64 + hi * 16) ^ swz));
      mfma16(s0, aq[kk], b0);
      mfma16(s1, aq[kk], b1);
    }
    float sv0[4], sv1[4];
    const int key1 = kbv + 16 + lo;   // key0 = kbv+lo is always < LKV
#pragma unroll
    for (int r = 0; r < 4; ++r) {
      sv0[r] = s0[r] * ATT_SCALE;
      sv1[r] = (key1 < LKV) ? s1[r] * ATT_SCALE : -1e30f;
    }
    float mx[4];
#pragma unroll
    for (int r = 0; r < 4; ++r) mx[r] = fmaxf(sv0[r], sv1[r]);
#pragma unroll
    for (int off = 1; off < 16; off <<= 1) {
#pragma unroll
      for (int r = 0; r < 4; ++r) mx[r] = fmaxf(mx[r], __shfl_xor(mx[r], off));
    }
    float alpha[4], ps[4];
    short pb0[4], pb1[4];
#pragma unroll
    for (int r = 0; r < 4; ++r) {
      float mn = fmaxf(m_r[r], mx[r]);
      alpha[r] = __expf(m_r[r] - mn);
      m_r[r] = mn;
      float p0 = __expf(sv0[r] - mn);
      float p1 = __expf(sv1[r] - mn);
      ps[r] = p0 + p1;
      pb0[r] = f2bf(p0);
      pb1[r] = f2bf(p1);
    }
#pragma unroll
    for (int off = 1; off < 16; off <<= 1) {
#pragma unroll
      for (int r = 0; r < 4; ++r) ps[r] += __shfl_xor(ps[r], off);
    }
#pragma unroll
    for (int r = 0; r < 4; ++r) l_r[r] = l_r[r] * alpha[r] + ps[r];
#pragma unroll
    for (int n = 0; n < 8; ++n)
#pragma unroll
      for (int r = 0; r < 4; ++r) oacc[n][r] *= alpha[r];

    // P fragment redistribution through per-wave LDS (row stride 40 shorts)
#pragma unroll
    for (int r = 0; r < 4; ++r) {
      int row = 4 * hi + r;
      P[row * 40 + lo] = pb0[r];
      P[row * 40 + 16 + lo] = pb1[r];
    }
    s16x8 ap = *(const s16x8*)&P[lo * 40 + hi * 8];
#pragma unroll
    for (int n = 0; n < 8; ++n) {
      s16x8 bv = *(const s16x8*)(lV[cur] + (n * 16 + lo) * 64 + hi * 16);
      mfma16(oacc[n], ap, bv);
    }
  };

  int t = s, cur = 0;
  stage(0, t);
  __syncthreads();              // implicit vmcnt(0) drain before barrier
  while (true) {
    int tn = t + NSPLIT;
    if (tn < NTILE) stage(cur ^ 1, tn);
    body(t * 32, cur);
    __syncthreads();            // drains stage vmcnt + all waves done reading
    if (tn >= NTILE) break;
    t = tn;
    cur ^= 1;
  }

  // write partials: O (unnormalized, f32), per-row (m, l)
  float* pOb = (s < 3) ? (pO0 + (size_t)(s * 12 + h) * 1560 * 128)
                       : (pO3 + (size_t)h * 1560 * 128);
#pragma unroll
  for (int n = 0; n < 8; ++n)
#pragma unroll
    for (int r = 0; r < 4; ++r) {
      int rr = q0 + 4 * hi + r;
      if (rr < 1560) pOb[(size_t)rr * 128 + n * 16 + lo] = oacc[n][r];
    }
  if (lo == 0) {
    float2* mlb = pML + (size_t)(s * 12 + h) * 1560;
#pragma unroll
    for (int r = 0; r < 4; ++r) {
      int rr = q0 + 4 * hi + r;
      if (rr < 1560) mlb[rr] = make_float2(m_r[r], l_r[r]);
    }
  }
}

// ---------------- combine partials -> Ob (bf16) ----------------------------
// grid (780, 12), 256 thr: each half-block handles one (t, h); d = tid&127.

__global__ __launch_bounds__(256) void k_comb(const float* __restrict__ pO0,
                                              const float* __restrict__ pO3,
                                              const float2* __restrict__ pML,
                                              short* __restrict__ Ob) {
  const int t = blockIdx.x * 2 + (threadIdx.x >> 7);
  const int h = blockIdx.y;
  const int d = threadIdx.x & 127;
  float2 ml[NSPLIT];
  float M = -1e30f;
#pragma unroll
  for (int s = 0; s < NSPLIT; ++s) {
    ml[s] = pML[((size_t)(s * 12 + h) * 1560) + t];
    M = fmaxf(M, ml[s].x);
  }
  float L = 0.f, o = 0.f;
#pragma unroll
  for (int s = 0; s < NSPLIT; ++s) {
    const float* pOb = (s < 3) ? (pO0 + (size_t)(s * 12 + h) * 1560 * 128)
                               : (pO3 + (size_t)h * 1560 * 128);
    float wgt = __expf(ml[s].x - M);
    L += ml[s].y * wgt;
    o += pOb[(size_t)t * 128 + d] * wgt;
  }
  Ob[(size_t)t * DIMM + h * HD + d] = f2bf(o / L);
}

// ---------------- launch ----------------

extern "C" void kernel_launch(void* const* d_in, const int* in_sizes, int n_in,
                              void* d_out, int out_size, void* d_ws, size_t ws_size,
                              hipStream_t stream) {
  (void)in_sizes; (void)n_in; (void)out_size;
  const float* x  = (const float*)d_in[0];
  const float* fc = (const float*)d_in[1];
  const float* fs = (const float*)d_in[2];
  const float* ck = (const float*)d_in[3];
  const float* cv = (const float*)d_in[4];
  const float* wq = (const float*)d_in[5];
  const float* p_bq = (const float*)d_in[6];
  const float* wk = (const float*)d_in[7];
  const float* p_bk = (const float*)d_in[8];
  const float* wv = (const float*)d_in[9];
  const float* p_bv = (const float*)d_in[10];
  const float* wo = (const float*)d_in[11];
  const float* p_bo = (const float*)d_in[12];
  const float* gq = (const float*)d_in[13];
  const float* gk = (const float*)d_in[14];
  float* out = (float*)d_out;

  char* ws = (char*)d_ws;
  if (ws_size < 117393408ull) return;
  short* xb   = (short*)(ws + 0);                 // 1664x1536 bf16 (alias Ob)
  short* ob   = xb;
  short* wqkv = (short*)(ws + 5111808);           // 4608x1536 bf16; partials s3+ML after QKV GEMM
  short* wob  = (short*)(ws + 19267584);          // 1536x1536 bf16
  float* bqkv = (float*)(ws + 23986176);          // 4608 f32
  float* qkvf = (float*)(ws + 24004608);          // 1664x4608 f32 (alias Vt)
  short* vt   = (short*)(ws + 24004608);          // 12x128x9376 bf16
  short* qb   = (short*)(ws + 54675456);          // 1664x1536 bf16
  short* kb   = (short*)(ws + 59787264);          // 9376x1536 bf16
  short* vr   = (short*)(ws + 88590336);          // 9376x1536 bf16; partials s0-2 after transv
  float*  pO0 = (float*)(ws + 88590336);          // 3 x 12x1560x128 f32 (28.75 MB)
  float*  pO3 = (float*)(ws + 5111808);           // 1 x 12x1560x128 f32 (9.58 MB)
  float2* pML = (float2*)(ws + 5111808 + 9584640);// 4 x 12x1560 float2 (600 KB)

  k_cvt_x<<<1248, 256, 0, stream>>>(x, xb);
  k_cvt<<<1152, 256, 0, stream>>>(wq, wqkv, 294912);
  k_cvt<<<1152, 256, 0, stream>>>(wk, wqkv + 1536 * 1536, 294912);
  k_cvt<<<1152, 256, 0, stream>>>(wv, wqkv + 2 * 1536 * 1536, 294912);
  k_cvt<<<1152, 256, 0, stream>>>(wo, wob, 294912);
  hipMemcpyAsync(bqkv, p_bq, 1536 * 4, hipMemcpyDeviceToDevice, stream);
  hipMemcpyAsync(bqkv + 1536, p_bk, 1536 * 4, hipMemcpyDeviceToDevice, stream);
  hipMemcpyAsync(bqkv + 3072, p_bv, 1536 * 4, hipMemcpyDeviceToDevice, stream);
  k_gather<<<5862, 256, 0, stream>>>(ck, kb);
  k_gather<<<5862, 256, 0, stream>>>(cv, vr);
  hipMemsetAsync(qb + (size_t)1560 * 1536, 0, 104 * 1536 * 2, stream);

  k_gemm<<<dim3(36, 13), 256, 0, stream>>>(xb, wqkv, bqkv, qkvf, 4608, 1536, 1664);
  // zero ob pad rows (combine writes rows < 1560; final GEMM stages 1664)
  hipMemsetAsync(ob + (size_t)1560 * 1536, 0, 104 * 1536 * 2, stream);
  k_post<<<1560, 256, 0, stream>>>(qkvf, fc, fs, gq, gk, qb, kb, vr);
  k_transv<<<dim3(293, 12), 256, 0, stream>>>(vr, vt);
  k_attn<<<dim3(25, 12, NSPLIT), 256, 0, stream>>>(qb, kb, vt, pO0, pO3, pML);
  k_comb<<<dim3(780, 12), 256, 0, stream>>>(pO0, pO3, pML, ob);
  k_gemm<<<dim3(12, 13), 256, 0, stream>>>(ob, wob, p_bo, out, 1536, 1536, 1560);
}

// Round 10
// 392.177 us; speedup vs baseline: 61.1575x; 1.1958x over previous
//
#include <hip/hip_runtime.h>

typedef short s16x8 __attribute__((ext_vector_type(8)));
typedef __bf16 bf16x8 __attribute__((ext_vector_type(8)));
typedef float f32x4 __attribute__((ext_vector_type(4)));

#define T_NEW 1560
#define MPAD  1664
#define DIMM  1536
#define NQKV  4608
#define LKV   9360
#define LPAD  9376
#define NEWB  7800
#define HD    128
#define NSPLIT 4
#define NTILE  293          /* ceil(9360/32) */
#define ATT_SCALE 0.08838834764831845f

static __device__ __forceinline__ short f2bf(float f) {
  unsigned u = __builtin_bit_cast(unsigned, f);
  u = (u + 0x7fffu + ((u >> 16) & 1u)) >> 16;
  return (short)u;
}

static __device__ __forceinline__ float bf2f(short s) {
  unsigned u = ((unsigned)(unsigned short)s) << 16;
  return __builtin_bit_cast(float, u);
}

// builtin MFMA: compiler models latency + inserts MFMA->VALU wait states
// (raw inline-asm MFMA lacks hazard handling -> stale VALU reads; r2-r5 bug)
static __device__ __forceinline__ void mfma16(f32x4& d, s16x8 a, s16x8 b) {
  d = __builtin_amdgcn_mfma_f32_16x16x32_bf16(
      __builtin_bit_cast(bf16x8, a), __builtin_bit_cast(bf16x8, b), d, 0, 0, 0);
}

#define GLD16(gp, lp) __builtin_amdgcn_global_load_lds(                  \
    (const __attribute__((address_space(1))) void*)(gp),                 \
    (__attribute__((address_space(3))) void*)(lp), 16, 0, 0)

// ---------------- conversion kernels ----------------

__global__ __launch_bounds__(256) void k_cvt(const float* __restrict__ s,
                                             short* __restrict__ d, int n8) {
  int i = blockIdx.x * 256 + threadIdx.x;
  if (i >= n8) return;
  const f32x4* p = (const f32x4*)s + (size_t)i * 2;
  f32x4 a = p[0], b = p[1];
  s16x8 o;
  o[0]=f2bf(a[0]); o[1]=f2bf(a[1]); o[2]=f2bf(a[2]); o[3]=f2bf(a[3]);
  o[4]=f2bf(b[0]); o[5]=f2bf(b[1]); o[6]=f2bf(b[2]); o[7]=f2bf(b[3]);
  *((s16x8*)d + i) = o;
}

// x (1560x1536) -> bf16 padded to 1664 rows (pad rows = 0)
__global__ __launch_bounds__(256) void k_cvt_x(const float* __restrict__ s,
                                               short* __restrict__ d) {
  int i = blockIdx.x * 256 + threadIdx.x;   // over MPAD*192
  s16x8 o;
  if (i < T_NEW * (DIMM / 8)) {
    const f32x4* p = (const f32x4*)s + (size_t)i * 2;
    f32x4 a = p[0], b = p[1];
    o[0]=f2bf(a[0]); o[1]=f2bf(a[1]); o[2]=f2bf(a[2]); o[3]=f2bf(a[3]);
    o[4]=f2bf(b[0]); o[5]=f2bf(b[1]); o[6]=f2bf(b[2]); o[7]=f2bf(b[3]);
  } else {
    o = 0;
  }
  *((s16x8*)d + i) = o;
}

// cache (9360x1536 f32) -> dst rows [0,7800) with roll, rows [9360,9376) zero
__global__ __launch_bounds__(256) void k_gather(const float* __restrict__ src,
                                                short* __restrict__ dst) {
  int i = blockIdx.x * 256 + threadIdx.x;   // over 7816*192
  int vrow = i / 192;
  int c8 = i - vrow * 192;
  s16x8 o;
  int drow;
  if (vrow < NEWB) {
    drow = vrow;
    int srow = (vrow < 1560) ? vrow : vrow + 1560;
    const f32x4* p = (const f32x4*)(src + (size_t)srow * DIMM + c8 * 8);
    f32x4 a = p[0], b = p[1];
    o[0]=f2bf(a[0]); o[1]=f2bf(a[1]); o[2]=f2bf(a[2]); o[3]=f2bf(a[3]);
    o[4]=f2bf(b[0]); o[5]=f2bf(b[1]); o[6]=f2bf(b[2]); o[7]=f2bf(b[3]);
  } else {
    drow = LKV + (vrow - NEWB);
    o = 0;
  }
  *(s16x8*)(dst + (size_t)drow * DIMM + c8 * 8) = o;
}

// ---------------- GEMM: C[M,N] = A[M,K] * Bt[N,K]^T + bias ----------------

__global__ __launch_bounds__(256) void k_gemm(const short* __restrict__ A,
                                              const short* __restrict__ Bt,
                                              const float* __restrict__ bias,
                                              float* __restrict__ C,
                                              int N, int K, int Mvalid) {
  __shared__ short lA[4096];
  __shared__ short lB[4096];
  const int tid = threadIdx.x;
  const int w = tid >> 6, l = tid & 63;
  const int lo = l & 15, hi = l >> 4;
  const int wr = w >> 1, wc = w & 1;
  const int brow = blockIdx.y * 128, bcol = blockIdx.x * 128;
  f32x4 acc[4][4] = {};
  const short* gA = A + (size_t)(brow + w * 32 + (l >> 2)) * K + ((l & 3) * 8);
  const short* gB = Bt + (size_t)(bcol + w * 32 + (l >> 2)) * K + ((l & 3) * 8);
  short* lAw = &lA[w * 1024];
  short* lBw = &lB[w * 1024];
  for (int k0 = 0; k0 < K; k0 += 32) {
    GLD16(gA + k0, lAw);
    GLD16(gA + (size_t)16 * K + k0, lAw + 512);
    GLD16(gB + k0, lBw);
    GLD16(gB + (size_t)16 * K + k0, lBw + 512);
    __syncthreads();
    s16x8 af[4], bf[4];
#pragma unroll
    for (int m = 0; m < 4; ++m)
      af[m] = *(const s16x8*)&lA[(wr * 64 + m * 16 + lo) * 32 + hi * 8];
#pragma unroll
    for (int n = 0; n < 4; ++n)
      bf[n] = *(const s16x8*)&lB[(wc * 64 + n * 16 + lo) * 32 + hi * 8];
#pragma unroll
    for (int m = 0; m < 4; ++m)
#pragma unroll
      for (int n = 0; n < 4; ++n)
        mfma16(acc[m][n], af[m], bf[n]);
    __syncthreads();
  }
#pragma unroll
  for (int n = 0; n < 4; ++n) {
    int c = bcol + wc * 64 + n * 16 + lo;
    float bs = bias[c];
#pragma unroll
    for (int m = 0; m < 4; ++m) {
      int r0 = brow + wr * 64 + m * 16 + 4 * hi;
#pragma unroll
      for (int r = 0; r < 4; ++r) {
        int rr = r0 + r;
        if (rr < Mvalid) C[(size_t)rr * N + c] = acc[m][n][r] + bs;
      }
    }
  }
}

// ---------------- bias'd QKV row post: rmsnorm+rope for q,k; v passthrough --
// Q rows are pre-scaled by ATT_SCALE (f32) so attention skips the score scale.

__global__ __launch_bounds__(256) void k_post(const float* __restrict__ qkv,
                                              const float* __restrict__ fc,
                                              const float* __restrict__ fs,
                                              const float* __restrict__ gq,
                                              const float* __restrict__ gk,
                                              short* __restrict__ Qb,
                                              short* __restrict__ Kb,
                                              short* __restrict__ Vr) {
  const int t = blockIdx.x, tid = threadIdx.x;
  __shared__ float buf[DIMM];
  __shared__ float red[4];
  const float* row = qkv + (size_t)t * NQKV;
  for (int sec = 0; sec < 2; ++sec) {
    const float* src = row + sec * DIMM;
    const float* g = sec ? gk : gq;
    float ssq = 0.f;
#pragma unroll
    for (int i = 0; i < 6; ++i) {
      float v = src[tid + i * 256];
      buf[tid + i * 256] = v;
      ssq += v * v;
    }
#pragma unroll
    for (int off = 32; off > 0; off >>= 1) ssq += __shfl_xor(ssq, off);
    if ((tid & 63) == 0) red[tid >> 6] = ssq;
    __syncthreads();
    float rms = rsqrtf((red[0] + red[1] + red[2] + red[3]) * (1.f / 1536.f) + 1e-6f);
    short* dst = sec ? (Kb + (size_t)(NEWB + t) * DIMM) : (Qb + (size_t)t * DIMM);
#pragma unroll
    for (int i = 0; i < 6; ++i) {
      int e = tid + i * 256;
      int d = e & 127;
      float vn = buf[e] * rms * g[e];
      float o;
      if (d < 64) {
        float v2 = buf[e + 64] * rms * g[e + 64];
        o = vn * fc[t * 64 + d] - v2 * fs[t * 64 + d];
      } else {
        float v1 = buf[e - 64] * rms * g[e - 64];
        o = v1 * fs[t * 64 + d - 64] + vn * fc[t * 64 + d - 64];
      }
      dst[e] = f2bf(sec ? o : o * ATT_SCALE);
    }
    __syncthreads();
  }
#pragma unroll
  for (int i = 0; i < 6; ++i) {
    int e = tid + i * 256;
    Vr[(size_t)(NEWB + t) * DIMM + e] = f2bf(row[3072 + e]);
  }
}

// ---------------- V transpose: Vr[l][h*128+d] -> Vt[h][d][l] ----------------

__global__ __launch_bounds__(256) void k_transv(const short* __restrict__ Vr,
                                                short* __restrict__ Vt) {
  const int h = blockIdx.y;
  const int l0 = blockIdx.x * 32;
  const int tid = threadIdx.x;
  __shared__ short lt[128 * 34];
#pragma unroll
  for (int i = 0; i < 16; ++i) {
    int idx = i * 256 + tid;
    int li = idx >> 7;
    int d = idx & 127;
    lt[d * 34 + li] = Vr[(size_t)(l0 + li) * DIMM + h * HD + d];
  }
  __syncthreads();
#pragma unroll
  for (int i = 0; i < 16; ++i) {
    int idx = i * 256 + tid;
    int d = idx >> 5;
    int li = idx & 31;
    Vt[((size_t)h * HD + d) * LPAD + l0 + li] = lt[d * 34 + li];
  }
}

// ---------------- flash attention: key-split + LDS dbuf + lean softmax -----
// block: 256 thr (4 waves), 16 q/wave = 64 q/block; grid (25, 12, NSPLIT).
// Wave-uniform running max (defer-max THR=8), per-lane l partials reduced
// once at the end, cvt_pk bf16 P-pack, setprio around MFMA clusters.

__global__ __launch_bounds__(256, 4) void k_attn(const short* __restrict__ Qb,
                                                 const short* __restrict__ Kb,
                                                 const short* __restrict__ Vt,
                                                 float* __restrict__ pO0,
                                                 float* __restrict__ pO3,
                                                 float2* __restrict__ pML) {
  const int h = blockIdx.y;
  const int s = blockIdx.z;
  const int w = threadIdx.x >> 6;
  const int l = threadIdx.x & 63;
  const int lo = l & 15, hi = l >> 4;
  const int q0 = blockIdx.x * 64 + w * 16;
  __shared__ __align__(16) char lK[2][8192];   // 32 keys x 256B, swizzled
  __shared__ __align__(16) char lV[2][8192];   // 128 dims x 64B, linear
  __shared__ short lP[4][640];
  short* P = lP[w];

  s16x8 aq[4];
  const short* qp = Qb + (size_t)(q0 + lo) * DIMM + h * HD + hi * 8;
#pragma unroll
  for (int kk = 0; kk < 4; ++kk) aq[kk] = *(const s16x8*)(qp + kk * 32);

  f32x4 oacc[8];
#pragma unroll
  for (int n = 0; n < 8; ++n) oacc[n] = 0;
  float m_w = -1e30f;
  float l_r[4];
#pragma unroll
  for (int r = 0; r < 4; ++r) l_r[r] = 0.f;

  const short* Kh = Kb + h * HD;
  const short* Vh = Vt + (size_t)h * HD * LPAD;

  // stage one 8KB K tile + 8KB V tile (block-cooperative, 2 chunks/wave each)
  auto stage = [&](int cur, int tile) {
#pragma unroll
    for (int j = 0; j < 2; ++j) {
      int chunk = j * 4 + w;
      int r = chunk * 4 + (l >> 4);
      int cb = ((l & 15) * 16) ^ ((r & 7) << 4);   // pre-swizzled source col
      GLD16(Kh + (size_t)(tile * 32 + r) * DIMM + (cb >> 1),
            &lK[cur][chunk * 1024]);
    }
#pragma unroll
    for (int j = 0; j < 2; ++j) {
      int chunk = j * 4 + w;
      int dim = chunk * 16 + (l >> 2);
      GLD16(Vh + (size_t)dim * LPAD + tile * 32 + (l & 3) * 8,
            &lV[cur][chunk * 1024]);
    }
  };

  auto body = [&](int kbv, int cur) {
    const int swz = (lo & 7) << 4;
    f32x4 s0 = 0, s1 = 0;
    __builtin_amdgcn_s_setprio(1);
#pragma unroll
    for (int kk = 0; kk < 4; ++kk) {
      s16x8 b0 = *(const s16x8*)(lK[cur] + lo * 256 + ((kk * 64 + hi * 16) ^ swz));
      s16x8 b1 = *(const s16x8*)(lK[cur] + (16 + lo) * 256 + ((kk * 64 + hi * 16) ^ swz));
      mfma16(s0, aq[kk], b0);
      mfma16(s1, aq[kk], b1);
    }
    __builtin_amdgcn_s_setprio(0);
    if (kbv + 32 > LKV) {            // boundary tile only (wave-uniform)
      const int key1 = kbv + 16 + lo;
#pragma unroll
      for (int r = 0; r < 4; ++r)
        if (key1 >= LKV) s1[r] = -1e30f;
    }
    // wave-uniform tile max
    float tmx = fmaxf(fmaxf(fmaxf(s0[0], s0[1]), fmaxf(s0[2], s0[3])),
                      fmaxf(fmaxf(s1[0], s1[1]), fmaxf(s1[2], s1[3])));
#pragma unroll
    for (int off = 1; off < 64; off <<= 1)
      tmx = fmaxf(tmx, __shfl_xor(tmx, off));
    // defer-max: rescale only when max grows by > 8
    if (tmx > m_w + 8.0f) {
      float alpha = __expf(m_w - tmx);
      m_w = tmx;
#pragma unroll
      for (int r = 0; r < 4; ++r) l_r[r] *= alpha;
#pragma unroll
      for (int n = 0; n < 8; ++n)
#pragma unroll
        for (int r = 0; r < 4; ++r) oacc[n][r] *= alpha;
    }
#pragma unroll
    for (int r = 0; r < 4; ++r) {
      float p0 = __expf(s0[r] - m_w);
      float p1 = __expf(s1[r] - m_w);
      l_r[r] += p0 + p1;
      unsigned pk;
      asm("v_cvt_pk_bf16_f32 %0, %1, %2" : "=v"(pk) : "v"(p0), "v"(p1));
      int row = 4 * hi + r;
      P[row * 40 + lo] = (short)(pk & 0xffffu);
      P[row * 40 + 16 + lo] = (short)(pk >> 16);
    }
    s16x8 ap = *(const s16x8*)&P[lo * 40 + hi * 8];
    __builtin_amdgcn_s_setprio(1);
#pragma unroll
    for (int n = 0; n < 8; ++n) {
      s16x8 bv = *(const s16x8*)(lV[cur] + (n * 16 + lo) * 64 + hi * 16);
      mfma16(oacc[n], ap, bv);
    }
    __builtin_amdgcn_s_setprio(0);
  };

  int t = s, cur = 0;
  stage(0, t);
  __syncthreads();              // implicit vmcnt(0) drain before barrier
  while (true) {
    int tn = t + NSPLIT;
    if (tn < NTILE) stage(cur ^ 1, tn);
    body(t * 32, cur);
    __syncthreads();            // drains stage vmcnt + all waves done reading
    if (tn >= NTILE) break;
    t = tn;
    cur ^= 1;
  }

  // final cross-lane l reduction (within each hi group's 16 lanes)
#pragma unroll
  for (int off = 1; off < 16; off <<= 1)
#pragma unroll
    for (int r = 0; r < 4; ++r) l_r[r] += __shfl_xor(l_r[r], off);

  // write partials: O (unnormalized, f32), per-row (m, l)
  float* pOb = (s < 3) ? (pO0 + (size_t)(s * 12 + h) * 1560 * 128)
                       : (pO3 + (size_t)h * 1560 * 128);
#pragma unroll
  for (int n = 0; n < 8; ++n)
#pragma unroll
    for (int r = 0; r < 4; ++r) {
      int rr = q0 + 4 * hi + r;
      if (rr < 1560) pOb[(size_t)rr * 128 + n * 16 + lo] = oacc[n][r];
    }
  if (lo == 0) {
    float2* mlb = pML + (size_t)(s * 12 + h) * 1560;
#pragma unroll
    for (int r = 0; r < 4; ++r) {
      int rr = q0 + 4 * hi + r;
      if (rr < 1560) mlb[rr] = make_float2(m_w, l_r[r]);
    }
  }
}

// ---------------- combine partials -> Ob (bf16) ----------------------------
// grid (780, 12), 256 thr: each half-block handles one (t, h); d = tid&127.

__global__ __launch_bounds__(256) void k_comb(const float* __restrict__ pO0,
                                              const float* __restrict__ pO3,
                                              const float2* __restrict__ pML,
                                              short* __restrict__ Ob) {
  const int t = blockIdx.x * 2 + (threadIdx.x >> 7);
  const int h = blockIdx.y;
  const int d = threadIdx.x & 127;
  float2 ml[NSPLIT];
  float M = -1e30f;
#pragma unroll
  for (int s = 0; s < NSPLIT; ++s) {
    ml[s] = pML[((size_t)(s * 12 + h) * 1560) + t];
    M = fmaxf(M, ml[s].x);
  }
  float L = 0.f, o = 0.f;
#pragma unroll
  for (int s = 0; s < NSPLIT; ++s) {
    const float* pOb = (s < 3) ? (pO0 + (size_t)(s * 12 + h) * 1560 * 128)
                               : (pO3 + (size_t)h * 1560 * 128);
    float wgt = __expf(ml[s].x - M);
    L += ml[s].y * wgt;
    o += pOb[(size_t)t * 128 + d] * wgt;
  }
  Ob[(size_t)t * DIMM + h * HD + d] = f2bf(o / L);
}

// ---------------- launch ----------------

extern "C" void kernel_launch(void* const* d_in, const int* in_sizes, int n_in,
                              void* d_out, int out_size, void* d_ws, size_t ws_size,
                              hipStream_t stream) {
  (void)in_sizes; (void)n_in; (void)out_size;
  const float* x  = (const float*)d_in[0];
  const float* fc = (const float*)d_in[1];
  const float* fs = (const float*)d_in[2];
  const float* ck = (const float*)d_in[3];
  const float* cv = (const float*)d_in[4];
  const float* wq = (const float*)d_in[5];
  const float* p_bq = (const float*)d_in[6];
  const float* wk = (const float*)d_in[7];
  const float* p_bk = (const float*)d_in[8];
  const float* wv = (const float*)d_in[9];
  const float* p_bv = (const float*)d_in[10];
  const float* wo = (const float*)d_in[11];
  const float* p_bo = (const float*)d_in[12];
  const float* gq = (const float*)d_in[13];
  const float* gk = (const float*)d_in[14];
  float* out = (float*)d_out;

  char* ws = (char*)d_ws;
  if (ws_size < 117393408ull) return;
  short* xb   = (short*)(ws + 0);                 // 1664x1536 bf16 (alias Ob)
  short* ob   = xb;
  short* wqkv = (short*)(ws + 5111808);           // 4608x1536 bf16; partials s3+ML after QKV GEMM
  short* wob  = (short*)(ws + 19267584);          // 1536x1536 bf16
  float* bqkv = (float*)(ws + 23986176);          // 4608 f32
  float* qkvf = (float*)(ws + 24004608);          // 1664x4608 f32 (alias Vt)
  short* vt   = (short*)(ws + 24004608);          // 12x128x9376 bf16
  short* qb   = (short*)(ws + 54675456);          // 1664x1536 bf16
  short* kb   = (short*)(ws + 59787264);          // 9376x1536 bf16
  short* vr   = (short*)(ws + 88590336);          // 9376x1536 bf16; partials s0-2 after transv
  float*  pO0 = (float*)(ws + 88590336);          // 3 x 12x1560x128 f32 (28.75 MB)
  float*  pO3 = (float*)(ws + 5111808);           // 1 x 12x1560x128 f32 (9.58 MB)
  float2* pML = (float2*)(ws + 5111808 + 9584640);// 4 x 12x1560 float2 (600 KB)

  k_cvt_x<<<1248, 256, 0, stream>>>(x, xb);
  k_cvt<<<1152, 256, 0, stream>>>(wq, wqkv, 294912);
  k_cvt<<<1152, 256, 0, stream>>>(wk, wqkv + 1536 * 1536, 294912);
  k_cvt<<<1152, 256, 0, stream>>>(wv, wqkv + 2 * 1536 * 1536, 294912);
  k_cvt<<<1152, 256, 0, stream>>>(wo, wob, 294912);
  hipMemcpyAsync(bqkv, p_bq, 1536 * 4, hipMemcpyDeviceToDevice, stream);
  hipMemcpyAsync(bqkv + 1536, p_bk, 1536 * 4, hipMemcpyDeviceToDevice, stream);
  hipMemcpyAsync(bqkv + 3072, p_bv, 1536 * 4, hipMemcpyDeviceToDevice, stream);
  k_gather<<<5862, 256, 0, stream>>>(ck, kb);
  k_gather<<<5862, 256, 0, stream>>>(cv, vr);
  hipMemsetAsync(qb + (size_t)1560 * 1536, 0, 104 * 1536 * 2, stream);

  k_gemm<<<dim3(36, 13), 256, 0, stream>>>(xb, wqkv, bqkv, qkvf, 4608, 1536, 1664);
  // zero ob pad rows (combine writes rows < 1560; final GEMM stages 1664)
  hipMemsetAsync(ob + (size_t)1560 * 1536, 0, 104 * 1536 * 2, stream);
  k_post<<<1560, 256, 0, stream>>>(qkvf, fc, fs, gq, gk, qb, kb, vr);
  k_transv<<<dim3(293, 12), 256, 0, stream>>>(vr, vt);
  k_attn<<<dim3(25, 12, NSPLIT), 256, 0, stream>>>(qb, kb, vt, pO0, pO3, pML);
  k_comb<<<dim3(780, 12), 256, 0, stream>>>(pO0, pO3, pML, ob);
  k_gemm<<<dim3(12, 13), 256, 0, stream>>>(ob, wob, p_bo, out, 1536, 1536, 1560);
}

// Round 15
// 384.855 us; speedup vs baseline: 62.3211x; 1.0190x over previous
//
#include <hip/hip_runtime.h>

typedef short s16x8 __attribute__((ext_vector_type(8)));
typedef __bf16 bf16x8 __attribute__((ext_vector_type(8)));
typedef float f32x4 __attribute__((ext_vector_type(4)));

#define T_NEW 1560
#define MPAD  1664
#define DIMM  1536
#define NQKV  4608
#define LKV   9360
#define LPAD  9376
#define NEWB  7800
#define HD    128
#define NSPLIT 4
#define NTILE  293          /* ceil(9360/32) */
#define ATT_SCALE 0.08838834764831845f

static __device__ __forceinline__ short f2bf(float f) {
  unsigned u = __builtin_bit_cast(unsigned, f);
  u = (u + 0x7fffu + ((u >> 16) & 1u)) >> 16;
  return (short)u;
}

static __device__ __forceinline__ float bf2f(short s) {
  unsigned u = ((unsigned)(unsigned short)s) << 16;
  return __builtin_bit_cast(float, u);
}

// builtin MFMA: compiler models latency + inserts MFMA->VALU wait states
// (raw inline-asm MFMA lacks hazard handling -> stale VALU reads; r2-r5 bug)
static __device__ __forceinline__ void mfma16(f32x4& d, s16x8 a, s16x8 b) {
  d = __builtin_amdgcn_mfma_f32_16x16x32_bf16(
      __builtin_bit_cast(bf16x8, a), __builtin_bit_cast(bf16x8, b), d, 0, 0, 0);
}

#define GLD16(gp, lp) __builtin_amdgcn_global_load_lds(                  \
    (const __attribute__((address_space(1))) void*)(gp),                 \
    (__attribute__((address_space(3))) void*)(lp), 16, 0, 0)

// ---------------- conversion kernels ----------------

// all four weight matrices in one launch; blockIdx.y selects (uniform branch)
__global__ __launch_bounds__(256) void k_cvtw(const float* __restrict__ wq,
                                              const float* __restrict__ wk,
                                              const float* __restrict__ wv,
                                              const float* __restrict__ wo,
                                              short* __restrict__ dqkv,
                                              short* __restrict__ dob) {
  const int m = blockIdx.y;
  const float* s = (m == 0) ? wq : (m == 1) ? wk : (m == 2) ? wv : wo;
  short* d = (m < 3) ? (dqkv + (size_t)m * DIMM * DIMM) : dob;
  int i = blockIdx.x * 256 + threadIdx.x;   // < 294912
  const f32x4* p = (const f32x4*)s + (size_t)i * 2;
  f32x4 a = p[0], b = p[1];
  s16x8 o;
  o[0]=f2bf(a[0]); o[1]=f2bf(a[1]); o[2]=f2bf(a[2]); o[3]=f2bf(a[3]);
  o[4]=f2bf(b[0]); o[5]=f2bf(b[1]); o[6]=f2bf(b[2]); o[7]=f2bf(b[3]);
  *((s16x8*)d + i) = o;
}

// x (1560x1536) -> bf16 padded to 1664 rows (pad rows = 0)
__global__ __launch_bounds__(256) void k_cvt_x(const float* __restrict__ s,
                                               short* __restrict__ d) {
  int i = blockIdx.x * 256 + threadIdx.x;   // over MPAD*192
  s16x8 o;
  if (i < T_NEW * (DIMM / 8)) {
    const f32x4* p = (const f32x4*)s + (size_t)i * 2;
    f32x4 a = p[0], b = p[1];
    o[0]=f2bf(a[0]); o[1]=f2bf(a[1]); o[2]=f2bf(a[2]); o[3]=f2bf(a[3]);
    o[4]=f2bf(b[0]); o[5]=f2bf(b[1]); o[6]=f2bf(b[2]); o[7]=f2bf(b[3]);
  } else {
    o = 0;
  }
  *((s16x8*)d + i) = o;
}

// three bias vectors -> contiguous bqkv (one launch).
// NOTE: 1536 is NOT a power of two -> must subtract, not mask (r14 bug:
// i & 1535 scrambled bk/bv -> absmax 1.84e-2).
__global__ __launch_bounds__(256) void k_bias3(const float* __restrict__ bq,
                                               const float* __restrict__ bk,
                                               const float* __restrict__ bv,
                                               float* __restrict__ dst) {
  int i = blockIdx.x * 256 + threadIdx.x;   // < 4608
  const float* s;
  int j;
  if (i < 1536)      { s = bq; j = i; }
  else if (i < 3072) { s = bk; j = i - 1536; }
  else               { s = bv; j = i - 3072; }
  dst[i] = s[j];
}

// both caches (K and V) in one launch; blockIdx.y selects (uniform branch).
// cache (9360x1536 f32) -> dst rows [0,7800) with roll, rows [9360,9376) zero
__global__ __launch_bounds__(256) void k_gather2(const float* __restrict__ ck,
                                                 const float* __restrict__ cv,
                                                 short* __restrict__ kb,
                                                 short* __restrict__ vr) {
  const float* src = blockIdx.y ? cv : ck;
  short* dst = blockIdx.y ? vr : kb;
  int i = blockIdx.x * 256 + threadIdx.x;   // over 7816*192
  int vrow = i / 192;
  int c8 = i - vrow * 192;
  s16x8 o;
  int drow;
  if (vrow < NEWB) {
    drow = vrow;
    int srow = (vrow < 1560) ? vrow : vrow + 1560;
    const f32x4* p = (const f32x4*)(src + (size_t)srow * DIMM + c8 * 8);
    f32x4 a = p[0], b = p[1];
    o[0]=f2bf(a[0]); o[1]=f2bf(a[1]); o[2]=f2bf(a[2]); o[3]=f2bf(a[3]);
    o[4]=f2bf(b[0]); o[5]=f2bf(b[1]); o[6]=f2bf(b[2]); o[7]=f2bf(b[3]);
  } else {
    drow = LKV + (vrow - NEWB);
    o = 0;
  }
  *(s16x8*)(dst + (size_t)drow * DIMM + c8 * 8) = o;
}

// ---------------- GEMM: C[M,N] = A[M,K] * Bt[N,K]^T + bias ----------------

__global__ __launch_bounds__(256) void k_gemm(const short* __restrict__ A,
                                              const short* __restrict__ Bt,
                                              const float* __restrict__ bias,
                                              float* __restrict__ C,
                                              int N, int K, int Mvalid) {
  __shared__ short lA[4096];
  __shared__ short lB[4096];
  const int tid = threadIdx.x;
  const int w = tid >> 6, l = tid & 63;
  const int lo = l & 15, hi = l >> 4;
  const int wr = w >> 1, wc = w & 1;
  const int brow = blockIdx.y * 128, bcol = blockIdx.x * 128;
  f32x4 acc[4][4] = {};
  const short* gA = A + (size_t)(brow + w * 32 + (l >> 2)) * K + ((l & 3) * 8);
  const short* gB = Bt + (size_t)(bcol + w * 32 + (l >> 2)) * K + ((l & 3) * 8);
  short* lAw = &lA[w * 1024];
  short* lBw = &lB[w * 1024];
  for (int k0 = 0; k0 < K; k0 += 32) {
    GLD16(gA + k0, lAw);
    GLD16(gA + (size_t)16 * K + k0, lAw + 512);
    GLD16(gB + k0, lBw);
    GLD16(gB + (size_t)16 * K + k0, lBw + 512);
    __syncthreads();
    s16x8 af[4], bf[4];
#pragma unroll
    for (int m = 0; m < 4; ++m)
      af[m] = *(const s16x8*)&lA[(wr * 64 + m * 16 + lo) * 32 + hi * 8];
#pragma unroll
    for (int n = 0; n < 4; ++n)
      bf[n] = *(const s16x8*)&lB[(wc * 64 + n * 16 + lo) * 32 + hi * 8];
#pragma unroll
    for (int m = 0; m < 4; ++m)
#pragma unroll
      for (int n = 0; n < 4; ++n)
        mfma16(acc[m][n], af[m], bf[n]);
    __syncthreads();
  }
#pragma unroll
  for (int n = 0; n < 4; ++n) {
    int c = bcol + wc * 64 + n * 16 + lo;
    float bs = bias[c];
#pragma unroll
    for (int m = 0; m < 4; ++m) {
      int r0 = brow + wr * 64 + m * 16 + 4 * hi;
#pragma unroll
      for (int r = 0; r < 4; ++r) {
        int rr = r0 + r;
        if (rr < Mvalid) C[(size_t)rr * N + c] = acc[m][n][r] + bs;
      }
    }
  }
}

// ---------------- bias'd QKV row post: rmsnorm+rope for q,k; v passthrough --
// Q rows are pre-scaled by ATT_SCALE (f32) so attention skips the score scale.

__global__ __launch_bounds__(256) void k_post(const float* __restrict__ qkv,
                                              const float* __restrict__ fc,
                                              const float* __restrict__ fs,
                                              const float* __restrict__ gq,
                                              const float* __restrict__ gk,
                                              short* __restrict__ Qb,
                                              short* __restrict__ Kb,
                                              short* __restrict__ Vr) {
  const int t = blockIdx.x, tid = threadIdx.x;
  __shared__ float buf[DIMM];
  __shared__ float red[4];
  const float* row = qkv + (size_t)t * NQKV;
  for (int sec = 0; sec < 2; ++sec) {
    const float* src = row + sec * DIMM;
    const float* g = sec ? gk : gq;
    float ssq = 0.f;
#pragma unroll
    for (int i = 0; i < 6; ++i) {
      float v = src[tid + i * 256];
      buf[tid + i * 256] = v;
      ssq += v * v;
    }
#pragma unroll
    for (int off = 32; off > 0; off >>= 1) ssq += __shfl_xor(ssq, off);
    if ((tid & 63) == 0) red[tid >> 6] = ssq;
    __syncthreads();
    float rms = rsqrtf((red[0] + red[1] + red[2] + red[3]) * (1.f / 1536.f) + 1e-6f);
    short* dst = sec ? (Kb + (size_t)(NEWB + t) * DIMM) : (Qb + (size_t)t * DIMM);
#pragma unroll
    for (int i = 0; i < 6; ++i) {
      int e = tid + i * 256;
      int d = e & 127;
      float vn = buf[e] * rms * g[e];
      float o;
      if (d < 64) {
        float v2 = buf[e + 64] * rms * g[e + 64];
        o = vn * fc[t * 64 + d] - v2 * fs[t * 64 + d];
      } else {
        float v1 = buf[e - 64] * rms * g[e - 64];
        o = v1 * fs[t * 64 + d - 64] + vn * fc[t * 64 + d - 64];
      }
      dst[e] = f2bf(sec ? o : o * ATT_SCALE);
    }
    __syncthreads();
  }
#pragma unroll
  for (int i = 0; i < 6; ++i) {
    int e = tid + i * 256;
    Vr[(size_t)(NEWB + t) * DIMM + e] = f2bf(row[3072 + e]);
  }
}

// ---------------- V transpose: Vr[l][h*128+d] -> Vt[h][d][l] ----------------

__global__ __launch_bounds__(256) void k_transv(const short* __restrict__ Vr,
                                                short* __restrict__ Vt) {
  const int h = blockIdx.y;
  const int l0 = blockIdx.x * 32;
  const int tid = threadIdx.x;
  __shared__ short lt[128 * 34];
#pragma unroll
  for (int i = 0; i < 16; ++i) {
    int idx = i * 256 + tid;
    int li = idx >> 7;
    int d = idx & 127;
    lt[d * 34 + li] = Vr[(size_t)(l0 + li) * DIMM + h * HD + d];
  }
  __syncthreads();
#pragma unroll
  for (int i = 0; i < 16; ++i) {
    int idx = i * 256 + tid;
    int d = idx >> 5;
    int li = idx & 31;
    Vt[((size_t)h * HD + d) * LPAD + l0 + li] = lt[d * 34 + li];
  }
}

// ---------------- flash attention: key-split + LDS dbuf + lean softmax -----
// VERBATIM r10 (hardware-validated PASS @ 239 us). r11-r13 restructures all
// failed on HW; do not modify this kernel without single-change discipline.
// block: 256 thr (4 waves), 16 q/wave = 64 q/block; grid (25, 12, NSPLIT).

__global__ __launch_bounds__(256, 4) void k_attn(const short* __restrict__ Qb,
                                                 const short* __restrict__ Kb,
                                                 const short* __restrict__ Vt,
                                                 float* __restrict__ pO0,
                                                 float* __restrict__ pO3,
                                                 float2* __restrict__ pML) {
  const int h = blockIdx.y;
  const int s = blockIdx.z;
  const int w = threadIdx.x >> 6;
  const int l = threadIdx.x & 63;
  const int lo = l & 15, hi = l >> 4;
  const int q0 = blockIdx.x * 64 + w * 16;
  __shared__ __align__(16) char lK[2][8192];   // 32 keys x 256B, swizzled
  __shared__ __align__(16) char lV[2][8192];   // 128 dims x 64B, linear
  __shared__ short lP[4][640];
  short* P = lP[w];

  s16x8 aq[4];
  const short* qp = Qb + (size_t)(q0 + lo) * DIMM + h * HD + hi * 8;
#pragma unroll
  for (int kk = 0; kk < 4; ++kk) aq[kk] = *(const s16x8*)(qp + kk * 32);

  f32x4 oacc[8];
#pragma unroll
  for (int n = 0; n < 8; ++n) oacc[n] = 0;
  float m_w = -1e30f;
  float l_r[4];
#pragma unroll
  for (int r = 0; r < 4; ++r) l_r[r] = 0.f;

  const short* Kh = Kb + h * HD;
  const short* Vh = Vt + (size_t)h * HD * LPAD;

  // stage one 8KB K tile + 8KB V tile (block-cooperative, 2 chunks/wave each)
  auto stage = [&](int cur, int tile) {
#pragma unroll
    for (int j = 0; j < 2; ++j) {
      int chunk = j * 4 + w;
      int r = chunk * 4 + (l >> 4);
      int cb = ((l & 15) * 16) ^ ((r & 7) << 4);   // pre-swizzled source col
      GLD16(Kh + (size_t)(tile * 32 + r) * DIMM + (cb >> 1),
            &lK[cur][chunk * 1024]);
    }
#pragma unroll
    for (int j = 0; j < 2; ++j) {
      int chunk = j * 4 + w;
      int dim = chunk * 16 + (l >> 2);
      GLD16(Vh + (size_t)dim * LPAD + tile * 32 + (l & 3) * 8,
            &lV[cur][chunk * 1024]);
    }
  };

  auto body = [&](int kbv, int cur) {
    const int swz = (lo & 7) << 4;
    f32x4 s0 = 0, s1 = 0;
    __builtin_amdgcn_s_setprio(1);
#pragma unroll
    for (int kk = 0; kk < 4; ++kk) {
      s16x8 b0 = *(const s16x8*)(lK[cur] + lo * 256 + ((kk * 64 + hi * 16) ^ swz));
      s16x8 b1 = *(const s16x8*)(lK[cur] + (16 + lo) * 256 + ((kk * 64 + hi * 16) ^ swz));
      mfma16(s0, aq[kk], b0);
      mfma16(s1, aq[kk], b1);
    }
    __builtin_amdgcn_s_setprio(0);
    if (kbv + 32 > LKV) {            // boundary tile only (block-uniform)
      const int key1 = kbv + 16 + lo;
#pragma unroll
      for (int r = 0; r < 4; ++r)
        if (key1 >= LKV) s1[r] = -1e30f;
    }
    // wave-uniform tile max
    float tmx = fmaxf(fmaxf(fmaxf(s0[0], s0[1]), fmaxf(s0[2], s0[3])),
                      fmaxf(fmaxf(s1[0], s1[1]), fmaxf(s1[2], s1[3])));
#pragma unroll
    for (int off = 1; off < 64; off <<= 1)
      tmx = fmaxf(tmx, __shfl_xor(tmx, off));
    // defer-max: rescale only when max grows by > 8
    if (tmx > m_w + 8.0f) {
      float alpha = __expf(m_w - tmx);
      m_w = tmx;
#pragma unroll
      for (int r = 0; r < 4; ++r) l_r[r] *= alpha;
#pragma unroll
      for (int n = 0; n < 8; ++n)
#pragma unroll
        for (int r = 0; r < 4; ++r) oacc[n][r] *= alpha;
    }
#pragma unroll
    for (int r = 0; r < 4; ++r) {
      float p0 = __expf(s0[r] - m_w);
      float p1 = __expf(s1[r] - m_w);
      l_r[r] += p0 + p1;
      unsigned pk;
      asm("v_cvt_pk_bf16_f32 %0, %1, %2" : "=v"(pk) : "v"(p0), "v"(p1));
      int row = 4 * hi + r;
      P[row * 40 + lo] = (short)(pk & 0xffffu);
      P[row * 40 + 16 + lo] = (short)(pk >> 16);
    }
    s16x8 ap = *(const s16x8*)&P[lo * 40 + hi * 8];
    __builtin_amdgcn_s_setprio(1);
#pragma unroll
    for (int n = 0; n < 8; ++n) {
      int rv = n * 16 + lo;
      s16x8 bv = *(const s16x8*)(lV[cur] + rv * 64 + hi * 16);
      mfma16(oacc[n], ap, bv);
    }
    __builtin_amdgcn_s_setprio(0);
  };

  int t = s, cur = 0;
  stage(0, t);
  __syncthreads();              // implicit vmcnt(0) drain before barrier
  while (true) {
    int tn = t + NSPLIT;
    if (tn < NTILE) stage(cur ^ 1, tn);
    body(t * 32, cur);
    __syncthreads();            // drains stage vmcnt + all waves done reading
    if (tn >= NTILE) break;
    t = tn;
    cur ^= 1;
  }

  // final cross-lane l reduction (within each hi group's 16 lanes)
#pragma unroll
  for (int off = 1; off < 16; off <<= 1)
#pragma unroll
    for (int r = 0; r < 4; ++r) l_r[r] += __shfl_xor(l_r[r], off);

  // write partials: O (unnormalized, f32), per-row (m, l)
  float* pOb = (s < 3) ? (pO0 + (size_t)(s * 12 + h) * 1560 * 128)
                       : (pO3 + (size_t)h * 1560 * 128);
#pragma unroll
  for (int n = 0; n < 8; ++n)
#pragma unroll
    for (int r = 0; r < 4; ++r) {
      int rr = q0 + 4 * hi + r;
      if (rr < 1560) pOb[(size_t)rr * 128 + n * 16 + lo] = oacc[n][r];
    }
  if (lo == 0) {
    float2* mlb = pML + (size_t)(s * 12 + h) * 1560;
#pragma unroll
    for (int r = 0; r < 4; ++r) {
      int rr = q0 + 4 * hi + r;
      if (rr < 1560) mlb[rr] = make_float2(m_w, l_r[r]);
    }
  }
}

// ---------------- combine partials -> Ob (bf16) ----------------------------
// grid (780, 12), 256 thr: each half-block handles one (t, h); d = tid&127.

__global__ __launch_bounds__(256) void k_comb(const float* __restrict__ pO0,
                                              const float* __restrict__ pO3,
                                              const float2* __restrict__ pML,
                                              short* __restrict__ Ob) {
  const int t = blockIdx.x * 2 + (threadIdx.x >> 7);
  const int h = blockIdx.y;
  const int d = threadIdx.x & 127;
  float2 ml[NSPLIT];
  float M = -1e30f;
#pragma unroll
  for (int s = 0; s < NSPLIT; ++s) {
    ml[s] = pML[((size_t)(s * 12 + h) * 1560) + t];
    M = fmaxf(M, ml[s].x);
  }
  float L = 0.f, o = 0.f;
#pragma unroll
  for (int s = 0; s < NSPLIT; ++s) {
    const float* pOb = (s < 3) ? (pO0 + (size_t)(s * 12 + h) * 1560 * 128)
                               : (pO3 + (size_t)h * 1560 * 128);
    float wgt = __expf(ml[s].x - M);
    L += ml[s].y * wgt;
    o += pOb[(size_t)t * 128 + d] * wgt;
  }
  Ob[(size_t)t * DIMM + h * HD + d] = f2bf(o / L);
}

// ---------------- launch ----------------

extern "C" void kernel_launch(void* const* d_in, const int* in_sizes, int n_in,
                              void* d_out, int out_size, void* d_ws, size_t ws_size,
                              hipStream_t stream) {
  (void)in_sizes; (void)n_in; (void)out_size;
  const float* x  = (const float*)d_in[0];
  const float* fc = (const float*)d_in[1];
  const float* fs = (const float*)d_in[2];
  const float* ck = (const float*)d_in[3];
  const float* cv = (const float*)d_in[4];
  const float* wq = (const float*)d_in[5];
  const float* p_bq = (const float*)d_in[6];
  const float* wk = (const float*)d_in[7];
  const float* p_bk = (const float*)d_in[8];
  const float* wv = (const float*)d_in[9];
  const float* p_bv = (const float*)d_in[10];
  const float* wo = (const float*)d_in[11];
  const float* p_bo = (const float*)d_in[12];
  const float* gq = (const float*)d_in[13];
  const float* gk = (const float*)d_in[14];
  float* out = (float*)d_out;

  char* ws = (char*)d_ws;
  if (ws_size < 117393408ull) return;
  short* xb   = (short*)(ws + 0);                 // 1664x1536 bf16 (alias Ob)
  short* ob   = xb;
  short* wqkv = (short*)(ws + 5111808);           // 4608x1536 bf16; partials s3+ML after QKV GEMM
  short* wob  = (short*)(ws + 19267584);          // 1536x1536 bf16
  float* bqkv = (float*)(ws + 23986176);          // 4608 f32
  float* qkvf = (float*)(ws + 24004608);          // 1664x4608 f32 (alias Vt)
  short* vt   = (short*)(ws + 24004608);          // 12x128x9376 bf16
  short* qb   = (short*)(ws + 54675456);          // 1664x1536 bf16
  short* kb   = (short*)(ws + 59787264);          // 9376x1536 bf16
  short* vr   = (short*)(ws + 88590336);          // 9376x1536 bf16; partials s0-2 after transv
  float*  pO0 = (float*)(ws + 88590336);          // 3 x 12x1560x128 f32 (28.75 MB)
  float*  pO3 = (float*)(ws + 5111808);           // 1 x 12x1560x128 f32 (9.58 MB)
  float2* pML = (float2*)(ws + 5111808 + 9584640);// 4 x 12x1560 float2 (600 KB)

  k_cvt_x<<<1248, 256, 0, stream>>>(x, xb);
  k_cvtw<<<dim3(1152, 4), 256, 0, stream>>>(wq, wk, wv, wo, wqkv, wob);
  k_bias3<<<18, 256, 0, stream>>>(p_bq, p_bk, p_bv, bqkv);
  k_gather2<<<dim3(5862, 2), 256, 0, stream>>>(ck, cv, kb, vr);
  hipMemsetAsync(qb + (size_t)1560 * 1536, 0, 104 * 1536 * 2, stream);

  k_gemm<<<dim3(36, 13), 256, 0, stream>>>(xb, wqkv, bqkv, qkvf, 4608, 1536, 1664);
  // zero ob pad rows (combine writes rows < 1560; final GEMM stages 1664)
  hipMemsetAsync(ob + (size_t)1560 * 1536, 0, 104 * 1536 * 2, stream);
  k_post<<<1560, 256, 0, stream>>>(qkvf, fc, fs, gq, gk, qb, kb, vr);
  k_transv<<<dim3(293, 12), 256, 0, stream>>>(vr, vt);
  k_attn<<<dim3(25, 12, NSPLIT), 256, 0, stream>>>(qb, kb, vt, pO0, pO3, pML);
  k_comb<<<dim3(780, 12), 256, 0, stream>>>(pO0, pO3, pML, ob);
  k_gemm<<<dim3(12, 13), 256, 0, stream>>>(ob, wob, p_bo, out, 1536, 1536, 1560);
}

// Round 16
// 376.502 us; speedup vs baseline: 63.7037x; 1.0222x over previous
//
#include <hip/hip_runtime.h>

typedef short s16x8 __attribute__((ext_vector_type(8)));
typedef __bf16 bf16x8 __attribute__((ext_vector_type(8)));
typedef float f32x4 __attribute__((ext_vector_type(4)));

#define T_NEW 1560
#define MPAD  1664
#define DIMM  1536
#define NQKV  4608
#define LKV   9360
#define LPAD  9376
#define NEWB  7800
#define HD    128
#define NSPLIT 4
#define NTILE  293          /* ceil(9360/32) */
#define ATT_SCALE 0.08838834764831845f

static __device__ __forceinline__ short f2bf(float f) {
  unsigned u = __builtin_bit_cast(unsigned, f);
  u = (u + 0x7fffu + ((u >> 16) & 1u)) >> 16;
  return (short)u;
}

static __device__ __forceinline__ float bf2f(short s) {
  unsigned u = ((unsigned)(unsigned short)s) << 16;
  return __builtin_bit_cast(float, u);
}

// builtin MFMA: compiler models latency + inserts MFMA->VALU wait states
// (raw inline-asm MFMA lacks hazard handling -> stale VALU reads; r2-r5 bug)
static __device__ __forceinline__ void mfma16(f32x4& d, s16x8 a, s16x8 b) {
  d = __builtin_amdgcn_mfma_f32_16x16x32_bf16(
      __builtin_bit_cast(bf16x8, a), __builtin_bit_cast(bf16x8, b), d, 0, 0, 0);
}

#define GLD16(gp, lp) __builtin_amdgcn_global_load_lds(                  \
    (const __attribute__((address_space(1))) void*)(gp),                 \
    (__attribute__((address_space(3))) void*)(lp), 16, 0, 0)

// ---------------- conversion kernels ----------------

// all four weight matrices in one launch; blockIdx.y selects (uniform branch)
__global__ __launch_bounds__(256) void k_cvtw(const float* __restrict__ wq,
                                              const float* __restrict__ wk,
                                              const float* __restrict__ wv,
                                              const float* __restrict__ wo,
                                              short* __restrict__ dqkv,
                                              short* __restrict__ dob) {
  const int m = blockIdx.y;
  const float* s = (m == 0) ? wq : (m == 1) ? wk : (m == 2) ? wv : wo;
  short* d = (m < 3) ? (dqkv + (size_t)m * DIMM * DIMM) : dob;
  int i = blockIdx.x * 256 + threadIdx.x;   // < 294912
  const f32x4* p = (const f32x4*)s + (size_t)i * 2;
  f32x4 a = p[0], b = p[1];
  s16x8 o;
  o[0]=f2bf(a[0]); o[1]=f2bf(a[1]); o[2]=f2bf(a[2]); o[3]=f2bf(a[3]);
  o[4]=f2bf(b[0]); o[5]=f2bf(b[1]); o[6]=f2bf(b[2]); o[7]=f2bf(b[3]);
  *((s16x8*)d + i) = o;
}

// x (1560x1536) -> bf16 padded to 1664 rows (pad rows = 0)
__global__ __launch_bounds__(256) void k_cvt_x(const float* __restrict__ s,
                                               short* __restrict__ d) {
  int i = blockIdx.x * 256 + threadIdx.x;   // over MPAD*192
  s16x8 o;
  if (i < T_NEW * (DIMM / 8)) {
    const f32x4* p = (const f32x4*)s + (size_t)i * 2;
    f32x4 a = p[0], b = p[1];
    o[0]=f2bf(a[0]); o[1]=f2bf(a[1]); o[2]=f2bf(a[2]); o[3]=f2bf(a[3]);
    o[4]=f2bf(b[0]); o[5]=f2bf(b[1]); o[6]=f2bf(b[2]); o[7]=f2bf(b[3]);
  } else {
    o = 0;
  }
  *((s16x8*)d + i) = o;
}

// three bias vectors -> contiguous bqkv (one launch).
// NOTE: 1536 is NOT a power of two -> must subtract, not mask (r14 bug:
// i & 1535 scrambled bk/bv -> absmax 1.84e-2).
__global__ __launch_bounds__(256) void k_bias3(const float* __restrict__ bq,
                                               const float* __restrict__ bk,
                                               const float* __restrict__ bv,
                                               float* __restrict__ dst) {
  int i = blockIdx.x * 256 + threadIdx.x;   // < 4608
  const float* s;
  int j;
  if (i < 1536)      { s = bq; j = i; }
  else if (i < 3072) { s = bk; j = i - 1536; }
  else               { s = bv; j = i - 3072; }
  dst[i] = s[j];
}

// both caches (K and V) in one launch; blockIdx.y selects (uniform branch).
// cache (9360x1536 f32) -> dst rows [0,7800) with roll, rows [9360,9376) zero
__global__ __launch_bounds__(256) void k_gather2(const float* __restrict__ ck,
                                                 const float* __restrict__ cv,
                                                 short* __restrict__ kb,
                                                 short* __restrict__ vr) {
  const float* src = blockIdx.y ? cv : ck;
  short* dst = blockIdx.y ? vr : kb;
  int i = blockIdx.x * 256 + threadIdx.x;   // over 7816*192
  int vrow = i / 192;
  int c8 = i - vrow * 192;
  s16x8 o;
  int drow;
  if (vrow < NEWB) {
    drow = vrow;
    int srow = (vrow < 1560) ? vrow : vrow + 1560;
    const f32x4* p = (const f32x4*)(src + (size_t)srow * DIMM + c8 * 8);
    f32x4 a = p[0], b = p[1];
    o[0]=f2bf(a[0]); o[1]=f2bf(a[1]); o[2]=f2bf(a[2]); o[3]=f2bf(a[3]);
    o[4]=f2bf(b[0]); o[5]=f2bf(b[1]); o[6]=f2bf(b[2]); o[7]=f2bf(b[3]);
  } else {
    drow = LKV + (vrow - NEWB);
    o = 0;
  }
  *(s16x8*)(dst + (size_t)drow * DIMM + c8 * 8) = o;
}

// ---------------- GEMM: C[M,N] = A[M,K] * Bt[N,K]^T + bias ----------------

__global__ __launch_bounds__(256) void k_gemm(const short* __restrict__ A,
                                              const short* __restrict__ Bt,
                                              const float* __restrict__ bias,
                                              float* __restrict__ C,
                                              int N, int K, int Mvalid) {
  __shared__ short lA[4096];
  __shared__ short lB[4096];
  const int tid = threadIdx.x;
  const int w = tid >> 6, l = tid & 63;
  const int lo = l & 15, hi = l >> 4;
  const int wr = w >> 1, wc = w & 1;
  const int brow = blockIdx.y * 128, bcol = blockIdx.x * 128;
  f32x4 acc[4][4] = {};
  const short* gA = A + (size_t)(brow + w * 32 + (l >> 2)) * K + ((l & 3) * 8);
  const short* gB = Bt + (size_t)(bcol + w * 32 + (l >> 2)) * K + ((l & 3) * 8);
  short* lAw = &lA[w * 1024];
  short* lBw = &lB[w * 1024];
  for (int k0 = 0; k0 < K; k0 += 32) {
    GLD16(gA + k0, lAw);
    GLD16(gA + (size_t)16 * K + k0, lAw + 512);
    GLD16(gB + k0, lBw);
    GLD16(gB + (size_t)16 * K + k0, lBw + 512);
    __syncthreads();
    s16x8 af[4], bf[4];
#pragma unroll
    for (int m = 0; m < 4; ++m)
      af[m] = *(const s16x8*)&lA[(wr * 64 + m * 16 + lo) * 32 + hi * 8];
#pragma unroll
    for (int n = 0; n < 4; ++n)
      bf[n] = *(const s16x8*)&lB[(wc * 64 + n * 16 + lo) * 32 + hi * 8];
#pragma unroll
    for (int m = 0; m < 4; ++m)
#pragma unroll
      for (int n = 0; n < 4; ++n)
        mfma16(acc[m][n], af[m], bf[n]);
    __syncthreads();
  }
#pragma unroll
  for (int n = 0; n < 4; ++n) {
    int c = bcol + wc * 64 + n * 16 + lo;
    float bs = bias[c];
#pragma unroll
    for (int m = 0; m < 4; ++m) {
      int r0 = brow + wr * 64 + m * 16 + 4 * hi;
#pragma unroll
      for (int r = 0; r < 4; ++r) {
        int rr = r0 + r;
        if (rr < Mvalid) C[(size_t)rr * N + c] = acc[m][n][r] + bs;
      }
    }
  }
}

// ---------------- bias'd QKV row post: rmsnorm+rope for q,k; v passthrough --
// Q rows are pre-scaled by ATT_SCALE (f32) so attention skips the score scale.

__global__ __launch_bounds__(256) void k_post(const float* __restrict__ qkv,
                                              const float* __restrict__ fc,
                                              const float* __restrict__ fs,
                                              const float* __restrict__ gq,
                                              const float* __restrict__ gk,
                                              short* __restrict__ Qb,
                                              short* __restrict__ Kb,
                                              short* __restrict__ Vr) {
  const int t = blockIdx.x, tid = threadIdx.x;
  __shared__ float buf[DIMM];
  __shared__ float red[4];
  const float* row = qkv + (size_t)t * NQKV;
  for (int sec = 0; sec < 2; ++sec) {
    const float* src = row + sec * DIMM;
    const float* g = sec ? gk : gq;
    float ssq = 0.f;
#pragma unroll
    for (int i = 0; i < 6; ++i) {
      float v = src[tid + i * 256];
      buf[tid + i * 256] = v;
      ssq += v * v;
    }
#pragma unroll
    for (int off = 32; off > 0; off >>= 1) ssq += __shfl_xor(ssq, off);
    if ((tid & 63) == 0) red[tid >> 6] = ssq;
    __syncthreads();
    float rms = rsqrtf((red[0] + red[1] + red[2] + red[3]) * (1.f / 1536.f) + 1e-6f);
    short* dst = sec ? (Kb + (size_t)(NEWB + t) * DIMM) : (Qb + (size_t)t * DIMM);
#pragma unroll
    for (int i = 0; i < 6; ++i) {
      int e = tid + i * 256;
      int d = e & 127;
      float vn = buf[e] * rms * g[e];
      float o;
      if (d < 64) {
        float v2 = buf[e + 64] * rms * g[e + 64];
        o = vn * fc[t * 64 + d] - v2 * fs[t * 64 + d];
      } else {
        float v1 = buf[e - 64] * rms * g[e - 64];
        o = v1 * fs[t * 64 + d - 64] + vn * fc[t * 64 + d - 64];
      }
      dst[e] = f2bf(sec ? o : o * ATT_SCALE);
    }
    __syncthreads();
  }
#pragma unroll
  for (int i = 0; i < 6; ++i) {
    int e = tid + i * 256;
    Vr[(size_t)(NEWB + t) * DIMM + e] = f2bf(row[3072 + e]);
  }
}

// ---------------- V transpose: Vr[l][h*128+d] -> Vt[h][d][l] ----------------

__global__ __launch_bounds__(256) void k_transv(const short* __restrict__ Vr,
                                                short* __restrict__ Vt) {
  const int h = blockIdx.y;
  const int l0 = blockIdx.x * 32;
  const int tid = threadIdx.x;
  __shared__ short lt[128 * 34];
#pragma unroll
  for (int i = 0; i < 16; ++i) {
    int idx = i * 256 + tid;
    int li = idx >> 7;
    int d = idx & 127;
    lt[d * 34 + li] = Vr[(size_t)(l0 + li) * DIMM + h * HD + d];
  }
  __syncthreads();
#pragma unroll
  for (int i = 0; i < 16; ++i) {
    int idx = i * 256 + tid;
    int d = idx >> 5;
    int li = idx & 31;
    Vt[((size_t)h * HD + d) * LPAD + l0 + li] = lt[d * 34 + li];
  }
}

// ---------------- flash attention: key-split + LDS dbuf + lean softmax -----
// r15 PASS base + SINGLE CHANGE: V slot-swizzle (both-sides involution
// sigma(dim)=(dim>>1)&3) to kill the 8-way bank conflict on V reads.
// LDS pipe was ~100% saturated; V-read conflict ~30% of LDS time.
// block: 256 thr (4 waves), 16 q/wave = 64 q/block; grid (25, 12, NSPLIT).

__global__ __launch_bounds__(256, 4) void k_attn(const short* __restrict__ Qb,
                                                 const short* __restrict__ Kb,
                                                 const short* __restrict__ Vt,
                                                 float* __restrict__ pO0,
                                                 float* __restrict__ pO3,
                                                 float2* __restrict__ pML) {
  const int h = blockIdx.y;
  const int s = blockIdx.z;
  const int w = threadIdx.x >> 6;
  const int l = threadIdx.x & 63;
  const int lo = l & 15, hi = l >> 4;
  const int q0 = blockIdx.x * 64 + w * 16;
  __shared__ __align__(16) char lK[2][8192];   // 32 keys x 256B, swizzled
  __shared__ __align__(16) char lV[2][8192];   // 128 dims x 4 slots, swizzled
  __shared__ short lP[4][640];
  short* P = lP[w];

  s16x8 aq[4];
  const short* qp = Qb + (size_t)(q0 + lo) * DIMM + h * HD + hi * 8;
#pragma unroll
  for (int kk = 0; kk < 4; ++kk) aq[kk] = *(const s16x8*)(qp + kk * 32);

  f32x4 oacc[8];
#pragma unroll
  for (int n = 0; n < 8; ++n) oacc[n] = 0;
  float m_w = -1e30f;
  float l_r[4];
#pragma unroll
  for (int r = 0; r < 4; ++r) l_r[r] = 0.f;

  const short* Kh = Kb + h * HD;
  const short* Vh = Vt + (size_t)h * HD * LPAD;

  // stage one 8KB K tile + 8KB V tile (block-cooperative, 2 chunks/wave each)
  auto stage = [&](int cur, int tile) {
#pragma unroll
    for (int j = 0; j < 2; ++j) {
      int chunk = j * 4 + w;
      int r = chunk * 4 + (l >> 4);
      int cb = ((l & 15) * 16) ^ ((r & 7) << 4);   // pre-swizzled source col
      GLD16(Kh + (size_t)(tile * 32 + r) * DIMM + (cb >> 1),
            &lK[cur][chunk * 1024]);
    }
#pragma unroll
    for (int j = 0; j < 2; ++j) {
      int chunk = j * 4 + w;
      int dim = chunk * 16 + (l >> 2);
      // V slot-swizzle: lane writes slot (l&3) of dim; source slot is
      // (l&3)^sigma(dim), sigma(dim)=(dim>>1)&3=(l>>3)&3
      GLD16(Vh + (size_t)dim * LPAD + tile * 32 + ((l & 3) ^ ((l >> 3) & 3)) * 8,
            &lV[cur][chunk * 1024]);
    }
  };

  auto body = [&](int kbv, int cur) {
    const int swz = (lo & 7) << 4;
    f32x4 s0 = 0, s1 = 0;
    __builtin_amdgcn_s_setprio(1);
#pragma unroll
    for (int kk = 0; kk < 4; ++kk) {
      s16x8 b0 = *(const s16x8*)(lK[cur] + lo * 256 + ((kk * 64 + hi * 16) ^ swz));
      s16x8 b1 = *(const s16x8*)(lK[cur] + (16 + lo) * 256 + ((kk * 64 + hi * 16) ^ swz));
      mfma16(s0, aq[kk], b0);
      mfma16(s1, aq[kk], b1);
    }
    __builtin_amdgcn_s_setprio(0);
    if (kbv + 32 > LKV) {            // boundary tile only (block-uniform)
      const int key1 = kbv + 16 + lo;
#pragma unroll
      for (int r = 0; r < 4; ++r)
        if (key1 >= LKV) s1[r] = -1e30f;
    }
    // wave-uniform tile max
    float tmx = fmaxf(fmaxf(fmaxf(s0[0], s0[1]), fmaxf(s0[2], s0[3])),
                      fmaxf(fmaxf(s1[0], s1[1]), fmaxf(s1[2], s1[3])));
#pragma unroll
    for (int off = 1; off < 64; off <<= 1)
      tmx = fmaxf(tmx, __shfl_xor(tmx, off));
    // defer-max: rescale only when max grows by > 8
    if (tmx > m_w + 8.0f) {
      float alpha = __expf(m_w - tmx);
      m_w = tmx;
#pragma unroll
      for (int r = 0; r < 4; ++r) l_r[r] *= alpha;
#pragma unroll
      for (int n = 0; n < 8; ++n)
#pragma unroll
        for (int r = 0; r < 4; ++r) oacc[n][r] *= alpha;
    }
#pragma unroll
    for (int r = 0; r < 4; ++r) {
      float p0 = __expf(s0[r] - m_w);
      float p1 = __expf(s1[r] - m_w);
      l_r[r] += p0 + p1;
      unsigned pk;
      asm("v_cvt_pk_bf16_f32 %0, %1, %2" : "=v"(pk) : "v"(p0), "v"(p1));
      int row = 4 * hi + r;
      P[row * 40 + lo] = (short)(pk & 0xffffu);
      P[row * 40 + 16 + lo] = (short)(pk >> 16);
    }
    s16x8 ap = *(const s16x8*)&P[lo * 40 + hi * 8];
    __builtin_amdgcn_s_setprio(1);
#pragma unroll
    for (int n = 0; n < 8; ++n) {
      int rv = n * 16 + lo;
      // read logical slot hi at physical slot hi^sigma(rv), sigma=(lo>>1)&3
      s16x8 bv = *(const s16x8*)(lV[cur] + rv * 64 +
                                 ((hi * 16) ^ (((lo >> 1) & 3) << 4)));
      mfma16(oacc[n], ap, bv);
    }
    __builtin_amdgcn_s_setprio(0);
  };

  int t = s, cur = 0;
  stage(0, t);
  __syncthreads();              // implicit vmcnt(0) drain before barrier
  while (true) {
    int tn = t + NSPLIT;
    if (tn < NTILE) stage(cur ^ 1, tn);
    body(t * 32, cur);
    __syncthreads();            // drains stage vmcnt + all waves done reading
    if (tn >= NTILE) break;
    t = tn;
    cur ^= 1;
  }

  // final cross-lane l reduction (within each hi group's 16 lanes)
#pragma unroll
  for (int off = 1; off < 16; off <<= 1)
#pragma unroll
    for (int r = 0; r < 4; ++r) l_r[r] += __shfl_xor(l_r[r], off);

  // write partials: O (unnormalized, f32), per-row (m, l)
  float* pOb = (s < 3) ? (pO0 + (size_t)(s * 12 + h) * 1560 * 128)
                       : (pO3 + (size_t)h * 1560 * 128);
#pragma unroll
  for (int n = 0; n < 8; ++n)
#pragma unroll
    for (int r = 0; r < 4; ++r) {
      int rr = q0 + 4 * hi + r;
      if (rr < 1560) pOb[(size_t)rr * 128 + n * 16 + lo] = oacc[n][r];
    }
  if (lo == 0) {
    float2* mlb = pML + (size_t)(s * 12 + h) * 1560;
#pragma unroll
    for (int r = 0; r < 4; ++r) {
      int rr = q0 + 4 * hi + r;
      if (rr < 1560) mlb[rr] = make_float2(m_w, l_r[r]);
    }
  }
}

// ---------------- combine partials -> Ob (bf16) ----------------------------
// grid (780, 12), 256 thr: each half-block handles one (t, h); d = tid&127.

__global__ __launch_bounds__(256) void k_comb(const float* __restrict__ pO0,
                                              const float* __restrict__ pO3,
                                              const float2* __restrict__ pML,
                                              short* __restrict__ Ob) {
  const int t = blockIdx.x * 2 + (threadIdx.x >> 7);
  const int h = blockIdx.y;
  const int d = threadIdx.x & 127;
  float2 ml[NSPLIT];
  float M = -1e30f;
#pragma unroll
  for (int s = 0; s < NSPLIT; ++s) {
    ml[s] = pML[((size_t)(s * 12 + h) * 1560) + t];
    M = fmaxf(M, ml[s].x);
  }
  float L = 0.f, o = 0.f;
#pragma unroll
  for (int s = 0; s < NSPLIT; ++s) {
    const float* pOb = (s < 3) ? (pO0 + (size_t)(s * 12 + h) * 1560 * 128)
                               : (pO3 + (size_t)h * 1560 * 128);
    float wgt = __expf(ml[s].x - M);
    L += ml[s].y * wgt;
    o += pOb[(size_t)t * 128 + d] * wgt;
  }
  Ob[(size_t)t * DIMM + h * HD + d] = f2bf(o / L);
}

// ---------------- launch ----------------

extern "C" void kernel_launch(void* const* d_in, const int* in_sizes, int n_in,
                              void* d_out, int out_size, void* d_ws, size_t ws_size,
                              hipStream_t stream) {
  (void)in_sizes; (void)n_in; (void)out_size;
  const float* x  = (const float*)d_in[0];
  const float* fc = (const float*)d_in[1];
  const float* fs = (const float*)d_in[2];
  const float* ck = (const float*)d_in[3];
  const float* cv = (const float*)d_in[4];
  const float* wq = (const float*)d_in[5];
  const float* p_bq = (const float*)d_in[6];
  const float* wk = (const float*)d_in[7];
  const float* p_bk = (const float*)d_in[8];
  const float* wv = (const float*)d_in[9];
  const float* p_bv = (const float*)d_in[10];
  const float* wo = (const float*)d_in[11];
  const float* p_bo = (const float*)d_in[12];
  const float* gq = (const float*)d_in[13];
  const float* gk = (const float*)d_in[14];
  float* out = (float*)d_out;

  char* ws = (char*)d_ws;
  if (ws_size < 117393408ull) return;
  short* xb   = (short*)(ws + 0);                 // 1664x1536 bf16 (alias Ob)
  short* ob   = xb;
  short* wqkv = (short*)(ws + 5111808);           // 4608x1536 bf16; partials s3+ML after QKV GEMM
  short* wob  = (short*)(ws + 19267584);          // 1536x1536 bf16
  float* bqkv = (float*)(ws + 23986176);          // 4608 f32
  float* qkvf = (float*)(ws + 24004608);          // 1664x4608 f32 (alias Vt)
  short* vt   = (short*)(ws + 24004608);          // 12x128x9376 bf16
  short* qb   = (short*)(ws + 54675456);          // 1664x1536 bf16
  short* kb   = (short*)(ws + 59787264);          // 9376x1536 bf16
  short* vr   = (short*)(ws + 88590336);          // 9376x1536 bf16; partials s0-2 after transv
  float*  pO0 = (float*)(ws + 88590336);          // 3 x 12x1560x128 f32 (28.75 MB)
  float*  pO3 = (float*)(ws + 5111808);           // 1 x 12x1560x128 f32 (9.58 MB)
  float2* pML = (float2*)(ws + 5111808 + 9584640);// 4 x 12x1560 float2 (600 KB)

  k_cvt_x<<<1248, 256, 0, stream>>>(x, xb);
  k_cvtw<<<dim3(1152, 4), 256, 0, stream>>>(wq, wk, wv, wo, wqkv, wob);
  k_bias3<<<18, 256, 0, stream>>>(p_bq, p_bk, p_bv, bqkv);
  k_gather2<<<dim3(5862, 2), 256, 0, stream>>>(ck, cv, kb, vr);
  hipMemsetAsync(qb + (size_t)1560 * 1536, 0, 104 * 1536 * 2, stream);

  k_gemm<<<dim3(36, 13), 256, 0, stream>>>(xb, wqkv, bqkv, qkvf, 4608, 1536, 1664);
  // zero ob pad rows (combine writes rows < 1560; final GEMM stages 1664)
  hipMemsetAsync(ob + (size_t)1560 * 1536, 0, 104 * 1536 * 2, stream);
  k_post<<<1560, 256, 0, stream>>>(qkvf, fc, fs, gq, gk, qb, kb, vr);
  k_transv<<<dim3(293, 12), 256, 0, stream>>>(vr, vt);
  k_attn<<<dim3(25, 12, NSPLIT), 256, 0, stream>>>(qb, kb, vt, pO0, pO3, pML);
  k_comb<<<dim3(780, 12), 256, 0, stream>>>(pO0, pO3, pML, ob);
  k_gemm<<<dim3(12, 13), 256, 0, stream>>>(ob, wob, p_bo, out, 1536, 1536, 1560);
}

// Round 17
// 370.811 us; speedup vs baseline: 64.6813x; 1.0153x over previous
//
#include <hip/hip_runtime.h>

typedef short s16x8 __attribute__((ext_vector_type(8)));
typedef __bf16 bf16x8 __attribute__((ext_vector_type(8)));
typedef float f32x4 __attribute__((ext_vector_type(4)));

#define T_NEW 1560
#define MPAD  1664
#define DIMM  1536
#define NQKV  4608
#define LKV   9360
#define LPAD  9376
#define NEWB  7800
#define HD    128
#define NSPLIT 4
#define NTILE  293          /* ceil(9360/32) */
#define ATT_SCALE 0.08838834764831845f

static __device__ __forceinline__ short f2bf(float f) {
  unsigned u = __builtin_bit_cast(unsigned, f);
  u = (u + 0x7fffu + ((u >> 16) & 1u)) >> 16;
  return (short)u;
}

static __device__ __forceinline__ float bf2f(short s) {
  unsigned u = ((unsigned)(unsigned short)s) << 16;
  return __builtin_bit_cast(float, u);
}

// builtin MFMA: compiler models latency + inserts MFMA->VALU wait states
// (raw inline-asm MFMA lacks hazard handling -> stale VALU reads; r2-r5 bug)
static __device__ __forceinline__ void mfma16(f32x4& d, s16x8 a, s16x8 b) {
  d = __builtin_amdgcn_mfma_f32_16x16x32_bf16(
      __builtin_bit_cast(bf16x8, a), __builtin_bit_cast(bf16x8, b), d, 0, 0, 0);
}

#define GLD16(gp, lp) __builtin_amdgcn_global_load_lds(                  \
    (const __attribute__((address_space(1))) void*)(gp),                 \
    (__attribute__((address_space(3))) void*)(lp), 16, 0, 0)

// ---------------- conversion kernels ----------------

// all four weight matrices in one launch; blockIdx.y selects (uniform branch)
__global__ __launch_bounds__(256) void k_cvtw(const float* __restrict__ wq,
                                              const float* __restrict__ wk,
                                              const float* __restrict__ wv,
                                              const float* __restrict__ wo,
                                              short* __restrict__ dqkv,
                                              short* __restrict__ dob) {
  const int m = blockIdx.y;
  const float* s = (m == 0) ? wq : (m == 1) ? wk : (m == 2) ? wv : wo;
  short* d = (m < 3) ? (dqkv + (size_t)m * DIMM * DIMM) : dob;
  int i = blockIdx.x * 256 + threadIdx.x;   // < 294912
  const f32x4* p = (const f32x4*)s + (size_t)i * 2;
  f32x4 a = p[0], b = p[1];
  s16x8 o;
  o[0]=f2bf(a[0]); o[1]=f2bf(a[1]); o[2]=f2bf(a[2]); o[3]=f2bf(a[3]);
  o[4]=f2bf(b[0]); o[5]=f2bf(b[1]); o[6]=f2bf(b[2]); o[7]=f2bf(b[3]);
  *((s16x8*)d + i) = o;
}

// x (1560x1536) -> bf16 padded to 1664 rows (pad rows = 0)
__global__ __launch_bounds__(256) void k_cvt_x(const float* __restrict__ s,
                                               short* __restrict__ d) {
  int i = blockIdx.x * 256 + threadIdx.x;   // over MPAD*192
  s16x8 o;
  if (i < T_NEW * (DIMM / 8)) {
    const f32x4* p = (const f32x4*)s + (size_t)i * 2;
    f32x4 a = p[0], b = p[1];
    o[0]=f2bf(a[0]); o[1]=f2bf(a[1]); o[2]=f2bf(a[2]); o[3]=f2bf(a[3]);
    o[4]=f2bf(b[0]); o[5]=f2bf(b[1]); o[6]=f2bf(b[2]); o[7]=f2bf(b[3]);
  } else {
    o = 0;
  }
  *((s16x8*)d + i) = o;
}

// three bias vectors -> contiguous bqkv (one launch).
// NOTE: 1536 is NOT a power of two -> must subtract, not mask (r14 bug:
// i & 1535 scrambled bk/bv -> absmax 1.84e-2).
__global__ __launch_bounds__(256) void k_bias3(const float* __restrict__ bq,
                                               const float* __restrict__ bk,
                                               const float* __restrict__ bv,
                                               float* __restrict__ dst) {
  int i = blockIdx.x * 256 + threadIdx.x;   // < 4608
  const float* s;
  int j;
  if (i < 1536)      { s = bq; j = i; }
  else if (i < 3072) { s = bk; j = i - 1536; }
  else               { s = bv; j = i - 3072; }
  dst[i] = s[j];
}

// both caches (K and V) in one launch; blockIdx.y selects (uniform branch).
// cache (9360x1536 f32) -> dst rows [0,7800) with roll, rows [9360,9376) zero
__global__ __launch_bounds__(256) void k_gather2(const float* __restrict__ ck,
                                                 const float* __restrict__ cv,
                                                 short* __restrict__ kb,
                                                 short* __restrict__ vr) {
  const float* src = blockIdx.y ? cv : ck;
  short* dst = blockIdx.y ? vr : kb;
  int i = blockIdx.x * 256 + threadIdx.x;   // over 7816*192
  int vrow = i / 192;
  int c8 = i - vrow * 192;
  s16x8 o;
  int drow;
  if (vrow < NEWB) {
    drow = vrow;
    int srow = (vrow < 1560) ? vrow : vrow + 1560;
    const f32x4* p = (const f32x4*)(src + (size_t)srow * DIMM + c8 * 8);
    f32x4 a = p[0], b = p[1];
    o[0]=f2bf(a[0]); o[1]=f2bf(a[1]); o[2]=f2bf(a[2]); o[3]=f2bf(a[3]);
    o[4]=f2bf(b[0]); o[5]=f2bf(b[1]); o[6]=f2bf(b[2]); o[7]=f2bf(b[3]);
  } else {
    drow = LKV + (vrow - NEWB);
    o = 0;
  }
  *(s16x8*)(dst + (size_t)drow * DIMM + c8 * 8) = o;
}

// ---------------- GEMM: C[M,N] = A[M,K] * Bt[N,K]^T + bias ----------------

__global__ __launch_bounds__(256) void k_gemm(const short* __restrict__ A,
                                              const short* __restrict__ Bt,
                                              const float* __restrict__ bias,
                                              float* __restrict__ C,
                                              int N, int K, int Mvalid) {
  __shared__ short lA[4096];
  __shared__ short lB[4096];
  const int tid = threadIdx.x;
  const int w = tid >> 6, l = tid & 63;
  const int lo = l & 15, hi = l >> 4;
  const int wr = w >> 1, wc = w & 1;
  const int brow = blockIdx.y * 128, bcol = blockIdx.x * 128;
  f32x4 acc[4][4] = {};
  const short* gA = A + (size_t)(brow + w * 32 + (l >> 2)) * K + ((l & 3) * 8);
  const short* gB = Bt + (size_t)(bcol + w * 32 + (l >> 2)) * K + ((l & 3) * 8);
  short* lAw = &lA[w * 1024];
  short* lBw = &lB[w * 1024];
  for (int k0 = 0; k0 < K; k0 += 32) {
    GLD16(gA + k0, lAw);
    GLD16(gA + (size_t)16 * K + k0, lAw + 512);
    GLD16(gB + k0, lBw);
    GLD16(gB + (size_t)16 * K + k0, lBw + 512);
    __syncthreads();
    s16x8 af[4], bf[4];
#pragma unroll
    for (int m = 0; m < 4; ++m)
      af[m] = *(const s16x8*)&lA[(wr * 64 + m * 16 + lo) * 32 + hi * 8];
#pragma unroll
    for (int n = 0; n < 4; ++n)
      bf[n] = *(const s16x8*)&lB[(wc * 64 + n * 16 + lo) * 32 + hi * 8];
#pragma unroll
    for (int m = 0; m < 4; ++m)
#pragma unroll
      for (int n = 0; n < 4; ++n)
        mfma16(acc[m][n], af[m], bf[n]);
    __syncthreads();
  }
#pragma unroll
  for (int n = 0; n < 4; ++n) {
    int c = bcol + wc * 64 + n * 16 + lo;
    float bs = bias[c];
#pragma unroll
    for (int m = 0; m < 4; ++m) {
      int r0 = brow + wr * 64 + m * 16 + 4 * hi;
#pragma unroll
      for (int r = 0; r < 4; ++r) {
        int rr = r0 + r;
        if (rr < Mvalid) C[(size_t)rr * N + c] = acc[m][n][r] + bs;
      }
    }
  }
}

// ---------------- bias'd QKV row post: rmsnorm+rope for q,k; v passthrough --
// Q rows are pre-scaled by ATT_SCALE (f32) so attention skips the score scale.

__global__ __launch_bounds__(256) void k_post(const float* __restrict__ qkv,
                                              const float* __restrict__ fc,
                                              const float* __restrict__ fs,
                                              const float* __restrict__ gq,
                                              const float* __restrict__ gk,
                                              short* __restrict__ Qb,
                                              short* __restrict__ Kb,
                                              short* __restrict__ Vr) {
  const int t = blockIdx.x, tid = threadIdx.x;
  __shared__ float buf[DIMM];
  __shared__ float red[4];
  const float* row = qkv + (size_t)t * NQKV;
  for (int sec = 0; sec < 2; ++sec) {
    const float* src = row + sec * DIMM;
    const float* g = sec ? gk : gq;
    float ssq = 0.f;
#pragma unroll
    for (int i = 0; i < 6; ++i) {
      float v = src[tid + i * 256];
      buf[tid + i * 256] = v;
      ssq += v * v;
    }
#pragma unroll
    for (int off = 32; off > 0; off >>= 1) ssq += __shfl_xor(ssq, off);
    if ((tid & 63) == 0) red[tid >> 6] = ssq;
    __syncthreads();
    float rms = rsqrtf((red[0] + red[1] + red[2] + red[3]) * (1.f / 1536.f) + 1e-6f);
    short* dst = sec ? (Kb + (size_t)(NEWB + t) * DIMM) : (Qb + (size_t)t * DIMM);
#pragma unroll
    for (int i = 0; i < 6; ++i) {
      int e = tid + i * 256;
      int d = e & 127;
      float vn = buf[e] * rms * g[e];
      float o;
      if (d < 64) {
        float v2 = buf[e + 64] * rms * g[e + 64];
        o = vn * fc[t * 64 + d] - v2 * fs[t * 64 + d];
      } else {
        float v1 = buf[e - 64] * rms * g[e - 64];
        o = v1 * fs[t * 64 + d - 64] + vn * fc[t * 64 + d - 64];
      }
      dst[e] = f2bf(sec ? o : o * ATT_SCALE);
    }
    __syncthreads();
  }
#pragma unroll
  for (int i = 0; i < 6; ++i) {
    int e = tid + i * 256;
    Vr[(size_t)(NEWB + t) * DIMM + e] = f2bf(row[3072 + e]);
  }
}

// ---------------- V transpose: Vr[l][h*128+d] -> Vt[h][d][l] ----------------

__global__ __launch_bounds__(256) void k_transv(const short* __restrict__ Vr,
                                                short* __restrict__ Vt) {
  const int h = blockIdx.y;
  const int l0 = blockIdx.x * 32;
  const int tid = threadIdx.x;
  __shared__ short lt[128 * 34];
#pragma unroll
  for (int i = 0; i < 16; ++i) {
    int idx = i * 256 + tid;
    int li = idx >> 7;
    int d = idx & 127;
    lt[d * 34 + li] = Vr[(size_t)(l0 + li) * DIMM + h * HD + d];
  }
  __syncthreads();
#pragma unroll
  for (int i = 0; i < 16; ++i) {
    int idx = i * 256 + tid;
    int d = idx >> 5;
    int li = idx & 31;
    Vt[((size_t)h * HD + d) * LPAD + l0 + li] = lt[d * 34 + li];
  }
}

// ---------------- flash attention: key-split + LDS dbuf + lean softmax -----
// r16 PASS base + SINGLE CHANGE: XCD panel-affinity swizzle. All 25 q-blocks
// of one (h,s) K/V panel land on ONE XCD (same id mod 8 under round-robin
// dispatch) -> panel (1.17MB) becomes L2-resident, cutting the 5x HBM
// re-fetch (285MB/dispatch) that made per-tile barrier drains ~900cy.
// block: 256 thr (4 waves), 16 q/wave = 64 q/block; flat grid 1200.

__global__ __launch_bounds__(256, 4) void k_attn(const short* __restrict__ Qb,
                                                 const short* __restrict__ Kb,
                                                 const short* __restrict__ Vt,
                                                 float* __restrict__ pO0,
                                                 float* __restrict__ pO3,
                                                 float2* __restrict__ pML) {
  // decode: f = xcd + 8*(bx + 25*pp); panel p = pp*8 + xcd; s = p/12, h = p%12
  const int f = blockIdx.x;
  const int xcd = f & 7;
  const int rdec = f >> 3;
  const int bx = rdec % 25;
  const int pp = rdec / 25;
  const int p = pp * 8 + xcd;
  const int s = p / 12;
  const int h = p % 12;
  const int w = threadIdx.x >> 6;
  const int l = threadIdx.x & 63;
  const int lo = l & 15, hi = l >> 4;
  const int q0 = bx * 64 + w * 16;
  __shared__ __align__(16) char lK[2][8192];   // 32 keys x 256B, swizzled
  __shared__ __align__(16) char lV[2][8192];   // 128 dims x 4 slots, swizzled
  __shared__ short lP[4][640];
  short* P = lP[w];

  s16x8 aq[4];
  const short* qp = Qb + (size_t)(q0 + lo) * DIMM + h * HD + hi * 8;
#pragma unroll
  for (int kk = 0; kk < 4; ++kk) aq[kk] = *(const s16x8*)(qp + kk * 32);

  f32x4 oacc[8];
#pragma unroll
  for (int n = 0; n < 8; ++n) oacc[n] = 0;
  float m_w = -1e30f;
  float l_r[4];
#pragma unroll
  for (int r = 0; r < 4; ++r) l_r[r] = 0.f;

  const short* Kh = Kb + h * HD;
  const short* Vh = Vt + (size_t)h * HD * LPAD;

  // stage one 8KB K tile + 8KB V tile (block-cooperative, 2 chunks/wave each)
  auto stage = [&](int cur, int tile) {
#pragma unroll
    for (int j = 0; j < 2; ++j) {
      int chunk = j * 4 + w;
      int r = chunk * 4 + (l >> 4);
      int cb = ((l & 15) * 16) ^ ((r & 7) << 4);   // pre-swizzled source col
      GLD16(Kh + (size_t)(tile * 32 + r) * DIMM + (cb >> 1),
            &lK[cur][chunk * 1024]);
    }
#pragma unroll
    for (int j = 0; j < 2; ++j) {
      int chunk = j * 4 + w;
      int dim = chunk * 16 + (l >> 2);
      // V slot-swizzle: lane writes slot (l&3) of dim; source slot is
      // (l&3)^sigma(dim), sigma(dim)=(dim>>1)&3=(l>>3)&3
      GLD16(Vh + (size_t)dim * LPAD + tile * 32 + ((l & 3) ^ ((l >> 3) & 3)) * 8,
            &lV[cur][chunk * 1024]);
    }
  };

  auto body = [&](int kbv, int cur) {
    const int swz = (lo & 7) << 4;
    f32x4 s0 = 0, s1 = 0;
    __builtin_amdgcn_s_setprio(1);
#pragma unroll
    for (int kk = 0; kk < 4; ++kk) {
      s16x8 b0 = *(const s16x8*)(lK[cur] + lo * 256 + ((kk * 64 + hi * 16) ^ swz));
      s16x8 b1 = *(const s16x8*)(lK[cur] + (16 + lo) * 256 + ((kk * 64 + hi * 16) ^ swz));
      mfma16(s0, aq[kk], b0);
      mfma16(s1, aq[kk], b1);
    }
    __builtin_amdgcn_s_setprio(0);
    if (kbv + 32 > LKV) {            // boundary tile only (block-uniform)
      const int key1 = kbv + 16 + lo;
#pragma unroll
      for (int r = 0; r < 4; ++r)
        if (key1 >= LKV) s1[r] = -1e30f;
    }
    // wave-uniform tile max
    float tmx = fmaxf(fmaxf(fmaxf(s0[0], s0[1]), fmaxf(s0[2], s0[3])),
                      fmaxf(fmaxf(s1[0], s1[1]), fmaxf(s1[2], s1[3])));
#pragma unroll
    for (int off = 1; off < 64; off <<= 1)
      tmx = fmaxf(tmx, __shfl_xor(tmx, off));
    // defer-max: rescale only when max grows by > 8
    if (tmx > m_w + 8.0f) {
      float alpha = __expf(m_w - tmx);
      m_w = tmx;
#pragma unroll
      for (int r = 0; r < 4; ++r) l_r[r] *= alpha;
#pragma unroll
      for (int n = 0; n < 8; ++n)
#pragma unroll
        for (int r = 0; r < 4; ++r) oacc[n][r] *= alpha;
    }
#pragma unroll
    for (int r = 0; r < 4; ++r) {
      float p0 = __expf(s0[r] - m_w);
      float p1 = __expf(s1[r] - m_w);
      l_r[r] += p0 + p1;
      unsigned pk;
      asm("v_cvt_pk_bf16_f32 %0, %1, %2" : "=v"(pk) : "v"(p0), "v"(p1));
      int row = 4 * hi + r;
      P[row * 40 + lo] = (short)(pk & 0xffffu);
      P[row * 40 + 16 + lo] = (short)(pk >> 16);
    }
    s16x8 ap = *(const s16x8*)&P[lo * 40 + hi * 8];
    __builtin_amdgcn_s_setprio(1);
#pragma unroll
    for (int n = 0; n < 8; ++n) {
      int rv = n * 16 + lo;
      // read logical slot hi at physical slot hi^sigma(rv), sigma=(lo>>1)&3
      s16x8 bv = *(const s16x8*)(lV[cur] + rv * 64 +
                                 ((hi * 16) ^ (((lo >> 1) & 3) << 4)));
      mfma16(oacc[n], ap, bv);
    }
    __builtin_amdgcn_s_setprio(0);
  };

  int t = s, cur = 0;
  stage(0, t);
  __syncthreads();              // implicit vmcnt(0) drain before barrier
  while (true) {
    int tn = t + NSPLIT;
    if (tn < NTILE) stage(cur ^ 1, tn);
    body(t * 32, cur);
    __syncthreads();            // drains stage vmcnt + all waves done reading
    if (tn >= NTILE) break;
    t = tn;
    cur ^= 1;
  }

  // final cross-lane l reduction (within each hi group's 16 lanes)
#pragma unroll
  for (int off = 1; off < 16; off <<= 1)
#pragma unroll
    for (int r = 0; r < 4; ++r) l_r[r] += __shfl_xor(l_r[r], off);

  // write partials: O (unnormalized, f32), per-row (m, l)
  float* pOb = (s < 3) ? (pO0 + (size_t)(s * 12 + h) * 1560 * 128)
                       : (pO3 + (size_t)h * 1560 * 128);
#pragma unroll
  for (int n = 0; n < 8; ++n)
#pragma unroll
    for (int r = 0; r < 4; ++r) {
      int rr = q0 + 4 * hi + r;
      if (rr < 1560) pOb[(size_t)rr * 128 + n * 16 + lo] = oacc[n][r];
    }
  if (lo == 0) {
    float2* mlb = pML + (size_t)(s * 12 + h) * 1560;
#pragma unroll
    for (int r = 0; r < 4; ++r) {
      int rr = q0 + 4 * hi + r;
      if (rr < 1560) mlb[rr] = make_float2(m_w, l_r[r]);
    }
  }
}

// ---------------- combine partials -> Ob (bf16) ----------------------------
// grid (780, 12), 256 thr: each half-block handles one (t, h); d = tid&127.

__global__ __launch_bounds__(256) void k_comb(const float* __restrict__ pO0,
                                              const float* __restrict__ pO3,
                                              const float2* __restrict__ pML,
                                              short* __restrict__ Ob) {
  const int t = blockIdx.x * 2 + (threadIdx.x >> 7);
  const int h = blockIdx.y;
  const int d = threadIdx.x & 127;
  float2 ml[NSPLIT];
  float M = -1e30f;
#pragma unroll
  for (int s = 0; s < NSPLIT; ++s) {
    ml[s] = pML[((size_t)(s * 12 + h) * 1560) + t];
    M = fmaxf(M, ml[s].x);
  }
  float L = 0.f, o = 0.f;
#pragma unroll
  for (int s = 0; s < NSPLIT; ++s) {
    const float* pOb = (s < 3) ? (pO0 + (size_t)(s * 12 + h) * 1560 * 128)
                               : (pO3 + (size_t)h * 1560 * 128);
    float wgt = __expf(ml[s].x - M);
    L += ml[s].y * wgt;
    o += pOb[(size_t)t * 128 + d] * wgt;
  }
  Ob[(size_t)t * DIMM + h * HD + d] = f2bf(o / L);
}

// ---------------- launch ----------------

extern "C" void kernel_launch(void* const* d_in, const int* in_sizes, int n_in,
                              void* d_out, int out_size, void* d_ws, size_t ws_size,
                              hipStream_t stream) {
  (void)in_sizes; (void)n_in; (void)out_size;
  const float* x  = (const float*)d_in[0];
  const float* fc = (const float*)d_in[1];
  const float* fs = (const float*)d_in[2];
  const float* ck = (const float*)d_in[3];
  const float* cv = (const float*)d_in[4];
  const float* wq = (const float*)d_in[5];
  const float* p_bq = (const float*)d_in[6];
  const float* wk = (const float*)d_in[7];
  const float* p_bk = (const float*)d_in[8];
  const float* wv = (const float*)d_in[9];
  const float* p_bv = (const float*)d_in[10];
  const float* wo = (const float*)d_in[11];
  const float* p_bo = (const float*)d_in[12];
  const float* gq = (const float*)d_in[13];
  const float* gk = (const float*)d_in[14];
  float* out = (float*)d_out;

  char* ws = (char*)d_ws;
  if (ws_size < 117393408ull) return;
  short* xb   = (short*)(ws + 0);                 // 1664x1536 bf16 (alias Ob)
  short* ob   = xb;
  short* wqkv = (short*)(ws + 5111808);           // 4608x1536 bf16; partials s3+ML after QKV GEMM
  short* wob  = (short*)(ws + 19267584);          // 1536x1536 bf16
  float* bqkv = (float*)(ws + 23986176);          // 4608 f32
  float* qkvf = (float*)(ws + 24004608);          // 1664x4608 f32 (alias Vt)
  short* vt   = (short*)(ws + 24004608);          // 12x128x9376 bf16
  short* qb   = (short*)(ws + 54675456);          // 1664x1536 bf16
  short* kb   = (short*)(ws + 59787264);          // 9376x1536 bf16
  short* vr   = (short*)(ws + 88590336);          // 9376x1536 bf16; partials s0-2 after transv
  float*  pO0 = (float*)(ws + 88590336);          // 3 x 12x1560x128 f32 (28.75 MB)
  float*  pO3 = (float*)(ws + 5111808);           // 1 x 12x1560x128 f32 (9.58 MB)
  float2* pML = (float2*)(ws + 5111808 + 9584640);// 4 x 12x1560 float2 (600 KB)

  k_cvt_x<<<1248, 256, 0, stream>>>(x, xb);
  k_cvtw<<<dim3(1152, 4), 256, 0, stream>>>(wq, wk, wv, wo, wqkv, wob);
  k_bias3<<<18, 256, 0, stream>>>(p_bq, p_bk, p_bv, bqkv);
  k_gather2<<<dim3(5862, 2), 256, 0, stream>>>(ck, cv, kb, vr);
  hipMemsetAsync(qb + (size_t)1560 * 1536, 0, 104 * 1536 * 2, stream);

  k_gemm<<<dim3(36, 13), 256, 0, stream>>>(xb, wqkv, bqkv, qkvf, 4608, 1536, 1664);
  // zero ob pad rows (combine writes rows < 1560; final GEMM stages 1664)
  hipMemsetAsync(ob + (size_t)1560 * 1536, 0, 104 * 1536 * 2, stream);
  k_post<<<1560, 256, 0, stream>>>(qkvf, fc, fs, gq, gk, qb, kb, vr);
  k_transv<<<dim3(293, 12), 256, 0, stream>>>(vr, vt);
  k_attn<<<1200, 256, 0, stream>>>(qb, kb, vt, pO0, pO3, pML);
  k_comb<<<dim3(780, 12), 256, 0, stream>>>(pO0, pO3, pML, ob);
  k_gemm<<<dim3(12, 13), 256, 0, stream>>>(ob, wob, p_bo, out, 1536, 1536, 1560);
}

// Round 18
// 341.188 us; speedup vs baseline: 70.2972x; 1.0868x over previous
//
#include <hip/hip_runtime.h>

typedef short s16x8 __attribute__((ext_vector_type(8)));
typedef __bf16 bf16x8 __attribute__((ext_vector_type(8)));
typedef float f32x4 __attribute__((ext_vector_type(4)));

#define T_NEW 1560
#define MPAD  1664
#define DIMM  1536
#define NQKV  4608
#define LKV   9360
#define LPAD  9376
#define NEWB  7800
#define HD    128
#define NSPLIT 3
#define NTILE  293          /* ceil(9360/32) */
#define ATT_SCALE 0.08838834764831845f

static __device__ __forceinline__ short f2bf(float f) {
  unsigned u = __builtin_bit_cast(unsigned, f);
  u = (u + 0x7fffu + ((u >> 16) & 1u)) >> 16;
  return (short)u;
}

static __device__ __forceinline__ float bf2f(short s) {
  unsigned u = ((unsigned)(unsigned short)s) << 16;
  return __builtin_bit_cast(float, u);
}

// builtin MFMA: compiler models latency + inserts MFMA->VALU wait states
// (raw inline-asm MFMA lacks hazard handling -> stale VALU reads; r2-r5 bug)
static __device__ __forceinline__ void mfma16(f32x4& d, s16x8 a, s16x8 b) {
  d = __builtin_amdgcn_mfma_f32_16x16x32_bf16(
      __builtin_bit_cast(bf16x8, a), __builtin_bit_cast(bf16x8, b), d, 0, 0, 0);
}

#define GLD16(gp, lp) __builtin_amdgcn_global_load_lds(                  \
    (const __attribute__((address_space(1))) void*)(gp),                 \
    (__attribute__((address_space(3))) void*)(lp), 16, 0, 0)

// ---------------- conversion kernels ----------------

// all four weight matrices in one launch; blockIdx.y selects (uniform branch)
__global__ __launch_bounds__(256) void k_cvtw(const float* __restrict__ wq,
                                              const float* __restrict__ wk,
                                              const float* __restrict__ wv,
                                              const float* __restrict__ wo,
                                              short* __restrict__ dqkv,
                                              short* __restrict__ dob) {
  const int m = blockIdx.y;
  const float* s = (m == 0) ? wq : (m == 1) ? wk : (m == 2) ? wv : wo;
  short* d = (m < 3) ? (dqkv + (size_t)m * DIMM * DIMM) : dob;
  int i = blockIdx.x * 256 + threadIdx.x;   // < 294912
  const f32x4* p = (const f32x4*)s + (size_t)i * 2;
  f32x4 a = p[0], b = p[1];
  s16x8 o;
  o[0]=f2bf(a[0]); o[1]=f2bf(a[1]); o[2]=f2bf(a[2]); o[3]=f2bf(a[3]);
  o[4]=f2bf(b[0]); o[5]=f2bf(b[1]); o[6]=f2bf(b[2]); o[7]=f2bf(b[3]);
  *((s16x8*)d + i) = o;
}

// x (1560x1536) -> bf16 padded to 1664 rows (pad rows = 0)
__global__ __launch_bounds__(256) void k_cvt_x(const float* __restrict__ s,
                                               short* __restrict__ d) {
  int i = blockIdx.x * 256 + threadIdx.x;   // over MPAD*192
  s16x8 o;
  if (i < T_NEW * (DIMM / 8)) {
    const f32x4* p = (const f32x4*)s + (size_t)i * 2;
    f32x4 a = p[0], b = p[1];
    o[0]=f2bf(a[0]); o[1]=f2bf(a[1]); o[2]=f2bf(a[2]); o[3]=f2bf(a[3]);
    o[4]=f2bf(b[0]); o[5]=f2bf(b[1]); o[6]=f2bf(b[2]); o[7]=f2bf(b[3]);
  } else {
    o = 0;
  }
  *((s16x8*)d + i) = o;
}

// three bias vectors -> contiguous bqkv (one launch).
// NOTE: 1536 is NOT a power of two -> must subtract, not mask (r14 bug:
// i & 1535 scrambled bk/bv -> absmax 1.84e-2).
__global__ __launch_bounds__(256) void k_bias3(const float* __restrict__ bq,
                                               const float* __restrict__ bk,
                                               const float* __restrict__ bv,
                                               float* __restrict__ dst) {
  int i = blockIdx.x * 256 + threadIdx.x;   // < 4608
  const float* s;
  int j;
  if (i < 1536)      { s = bq; j = i; }
  else if (i < 3072) { s = bk; j = i - 1536; }
  else               { s = bv; j = i - 3072; }
  dst[i] = s[j];
}

// both caches (K and V) in one launch; blockIdx.y selects (uniform branch).
// cache (9360x1536 f32) -> dst rows [0,7800) with roll, rows [9360,9376) zero
__global__ __launch_bounds__(256) void k_gather2(const float* __restrict__ ck,
                                                 const float* __restrict__ cv,
                                                 short* __restrict__ kb,
                                                 short* __restrict__ vr) {
  const float* src = blockIdx.y ? cv : ck;
  short* dst = blockIdx.y ? vr : kb;
  int i = blockIdx.x * 256 + threadIdx.x;   // over 7816*192
  int vrow = i / 192;
  int c8 = i - vrow * 192;
  s16x8 o;
  int drow;
  if (vrow < NEWB) {
    drow = vrow;
    int srow = (vrow < 1560) ? vrow : vrow + 1560;
    const f32x4* p = (const f32x4*)(src + (size_t)srow * DIMM + c8 * 8);
    f32x4 a = p[0], b = p[1];
    o[0]=f2bf(a[0]); o[1]=f2bf(a[1]); o[2]=f2bf(a[2]); o[3]=f2bf(a[3]);
    o[4]=f2bf(b[0]); o[5]=f2bf(b[1]); o[6]=f2bf(b[2]); o[7]=f2bf(b[3]);
  } else {
    drow = LKV + (vrow - NEWB);
    o = 0;
  }
  *(s16x8*)(dst + (size_t)drow * DIMM + c8 * 8) = o;
}

// ---------------- GEMM: C[M,N] = A[M,K] * Bt[N,K]^T + bias ----------------

__global__ __launch_bounds__(256) void k_gemm(const short* __restrict__ A,
                                              const short* __restrict__ Bt,
                                              const float* __restrict__ bias,
                                              float* __restrict__ C,
                                              int N, int K, int Mvalid) {
  __shared__ short lA[4096];
  __shared__ short lB[4096];
  const int tid = threadIdx.x;
  const int w = tid >> 6, l = tid & 63;
  const int lo = l & 15, hi = l >> 4;
  const int wr = w >> 1, wc = w & 1;
  const int brow = blockIdx.y * 128, bcol = blockIdx.x * 128;
  f32x4 acc[4][4] = {};
  const short* gA = A + (size_t)(brow + w * 32 + (l >> 2)) * K + ((l & 3) * 8);
  const short* gB = Bt + (size_t)(bcol + w * 32 + (l >> 2)) * K + ((l & 3) * 8);
  short* lAw = &lA[w * 1024];
  short* lBw = &lB[w * 1024];
  for (int k0 = 0; k0 < K; k0 += 32) {
    GLD16(gA + k0, lAw);
    GLD16(gA + (size_t)16 * K + k0, lAw + 512);
    GLD16(gB + k0, lBw);
    GLD16(gB + (size_t)16 * K + k0, lBw + 512);
    __syncthreads();
    s16x8 af[4], bf[4];
#pragma unroll
    for (int m = 0; m < 4; ++m)
      af[m] = *(const s16x8*)&lA[(wr * 64 + m * 16 + lo) * 32 + hi * 8];
#pragma unroll
    for (int n = 0; n < 4; ++n)
      bf[n] = *(const s16x8*)&lB[(wc * 64 + n * 16 + lo) * 32 + hi * 8];
#pragma unroll
    for (int m = 0; m < 4; ++m)
#pragma unroll
      for (int n = 0; n < 4; ++n)
        mfma16(acc[m][n], af[m], bf[n]);
    __syncthreads();
  }
#pragma unroll
  for (int n = 0; n < 4; ++n) {
    int c = bcol + wc * 64 + n * 16 + lo;
    float bs = bias[c];
#pragma unroll
    for (int m = 0; m < 4; ++m) {
      int r0 = brow + wr * 64 + m * 16 + 4 * hi;
#pragma unroll
      for (int r = 0; r < 4; ++r) {
        int rr = r0 + r;
        if (rr < Mvalid) C[(size_t)rr * N + c] = acc[m][n][r] + bs;
      }
    }
  }
}

// ---------------- bias'd QKV row post: rmsnorm+rope for q,k; v passthrough --
// Q rows are pre-scaled by ATT_SCALE (f32) so attention skips the score scale.

__global__ __launch_bounds__(256) void k_post(const float* __restrict__ qkv,
                                              const float* __restrict__ fc,
                                              const float* __restrict__ fs,
                                              const float* __restrict__ gq,
                                              const float* __restrict__ gk,
                                              short* __restrict__ Qb,
                                              short* __restrict__ Kb,
                                              short* __restrict__ Vr) {
  const int t = blockIdx.x, tid = threadIdx.x;
  __shared__ float buf[DIMM];
  __shared__ float red[4];
  const float* row = qkv + (size_t)t * NQKV;
  for (int sec = 0; sec < 2; ++sec) {
    const float* src = row + sec * DIMM;
    const float* g = sec ? gk : gq;
    float ssq = 0.f;
#pragma unroll
    for (int i = 0; i < 6; ++i) {
      float v = src[tid + i * 256];
      buf[tid + i * 256] = v;
      ssq += v * v;
    }
#pragma unroll
    for (int off = 32; off > 0; off >>= 1) ssq += __shfl_xor(ssq, off);
    if ((tid & 63) == 0) red[tid >> 6] = ssq;
    __syncthreads();
    float rms = rsqrtf((red[0] + red[1] + red[2] + red[3]) * (1.f / 1536.f) + 1e-6f);
    short* dst = sec ? (Kb + (size_t)(NEWB + t) * DIMM) : (Qb + (size_t)t * DIMM);
#pragma unroll
    for (int i = 0; i < 6; ++i) {
      int e = tid + i * 256;
      int d = e & 127;
      float vn = buf[e] * rms * g[e];
      float o;
      if (d < 64) {
        float v2 = buf[e + 64] * rms * g[e + 64];
        o = vn * fc[t * 64 + d] - v2 * fs[t * 64 + d];
      } else {
        float v1 = buf[e - 64] * rms * g[e - 64];
        o = v1 * fs[t * 64 + d - 64] + vn * fc[t * 64 + d - 64];
      }
      dst[e] = f2bf(sec ? o : o * ATT_SCALE);
    }
    __syncthreads();
  }
#pragma unroll
  for (int i = 0; i < 6; ++i) {
    int e = tid + i * 256;
    Vr[(size_t)(NEWB + t) * DIMM + e] = f2bf(row[3072 + e]);
  }
}

// ---------------- V transpose: Vr[l][h*128+d] -> Vt[h][d][l] ----------------

__global__ __launch_bounds__(256) void k_transv(const short* __restrict__ Vr,
                                                short* __restrict__ Vt) {
  const int h = blockIdx.y;
  const int l0 = blockIdx.x * 32;
  const int tid = threadIdx.x;
  __shared__ short lt[128 * 34];
#pragma unroll
  for (int i = 0; i < 16; ++i) {
    int idx = i * 256 + tid;
    int li = idx >> 7;
    int d = idx & 127;
    lt[d * 34 + li] = Vr[(size_t)(l0 + li) * DIMM + h * HD + d];
  }
  __syncthreads();
#pragma unroll
  for (int i = 0; i < 16; ++i) {
    int idx = i * 256 + tid;
    int d = idx >> 5;
    int li = idx & 31;
    Vt[((size_t)h * HD + d) * LPAD + l0 + li] = lt[d * 34 + li];
  }
}

// ---------------- flash attention: key-split + LDS dbuf + lean softmax -----
// r17 PASS base + SINGLE CHANGE: NSPLIT 4->3 so grid (900) <= resident
// capacity (4 blocks/CU x 256 = 1024): one full round, no 176-block tail
// (the tail made measured occupancy 30% and wasted ~40% of wall time).
// XCD panel affinity kept: 36 panels; first 800 blocks XCD-aligned, last
// 100 cover panels 32..35. block: 256 thr (4 waves), 64 q/block.

__global__ __launch_bounds__(256, 4) void k_attn(const short* __restrict__ Qb,
                                                 const short* __restrict__ Kb,
                                                 const short* __restrict__ Vt,
                                                 float* __restrict__ pO,
                                                 float2* __restrict__ pML) {
  // bijective decode of flat grid 900 -> (bx in [0,25), panel p in [0,36))
  const int f = blockIdx.x;
  int bx, p;
  if (f < 800) {
    const int xcd = f & 7;
    const int rdec = f >> 3;
    bx = rdec % 25;
    p = (rdec / 25) * 8 + xcd;     // panels 0..31, XCD-affine
  } else {
    const int g = f - 800;
    p = 32 + (g & 3);              // panels 32..35
    bx = g >> 2;
  }
  const int s = p / 12;
  const int h = p % 12;
  const int w = threadIdx.x >> 6;
  const int l = threadIdx.x & 63;
  const int lo = l & 15, hi = l >> 4;
  const int q0 = bx * 64 + w * 16;
  __shared__ __align__(16) char lK[2][8192];   // 32 keys x 256B, swizzled
  __shared__ __align__(16) char lV[2][8192];   // 128 dims x 4 slots, swizzled
  __shared__ short lP[4][640];
  short* P = lP[w];

  s16x8 aq[4];
  const short* qp = Qb + (size_t)(q0 + lo) * DIMM + h * HD + hi * 8;
#pragma unroll
  for (int kk = 0; kk < 4; ++kk) aq[kk] = *(const s16x8*)(qp + kk * 32);

  f32x4 oacc[8];
#pragma unroll
  for (int n = 0; n < 8; ++n) oacc[n] = 0;
  float m_w = -1e30f;
  float l_r[4];
#pragma unroll
  for (int r = 0; r < 4; ++r) l_r[r] = 0.f;

  const short* Kh = Kb + h * HD;
  const short* Vh = Vt + (size_t)h * HD * LPAD;

  // stage one 8KB K tile + 8KB V tile (block-cooperative, 2 chunks/wave each)
  auto stage = [&](int cur, int tile) {
#pragma unroll
    for (int j = 0; j < 2; ++j) {
      int chunk = j * 4 + w;
      int r = chunk * 4 + (l >> 4);
      int cb = ((l & 15) * 16) ^ ((r & 7) << 4);   // pre-swizzled source col
      GLD16(Kh + (size_t)(tile * 32 + r) * DIMM + (cb >> 1),
            &lK[cur][chunk * 1024]);
    }
#pragma unroll
    for (int j = 0; j < 2; ++j) {
      int chunk = j * 4 + w;
      int dim = chunk * 16 + (l >> 2);
      // V slot-swizzle: lane writes slot (l&3) of dim; source slot is
      // (l&3)^sigma(dim), sigma(dim)=(dim>>1)&3=(l>>3)&3
      GLD16(Vh + (size_t)dim * LPAD + tile * 32 + ((l & 3) ^ ((l >> 3) & 3)) * 8,
            &lV[cur][chunk * 1024]);
    }
  };

  auto body = [&](int kbv, int cur) {
    const int swz = (lo & 7) << 4;
    f32x4 s0 = 0, s1 = 0;
    __builtin_amdgcn_s_setprio(1);
#pragma unroll
    for (int kk = 0; kk < 4; ++kk) {
      s16x8 b0 = *(const s16x8*)(lK[cur] + lo * 256 + ((kk * 64 + hi * 16) ^ swz));
      s16x8 b1 = *(const s16x8*)(lK[cur] + (16 + lo) * 256 + ((kk * 64 + hi * 16) ^ swz));
      mfma16(s0, aq[kk], b0);
      mfma16(s1, aq[kk], b1);
    }
    __builtin_amdgcn_s_setprio(0);
    if (kbv + 32 > LKV) {            // boundary tile only (block-uniform)
      const int key1 = kbv + 16 + lo;
#pragma unroll
      for (int r = 0; r < 4; ++r)
        if (key1 >= LKV) s1[r] = -1e30f;
    }
    // wave-uniform tile max
    float tmx = fmaxf(fmaxf(fmaxf(s0[0], s0[1]), fmaxf(s0[2], s0[3])),
                      fmaxf(fmaxf(s1[0], s1[1]), fmaxf(s1[2], s1[3])));
#pragma unroll
    for (int off = 1; off < 64; off <<= 1)
      tmx = fmaxf(tmx, __shfl_xor(tmx, off));
    // defer-max: rescale only when max grows by > 8
    if (tmx > m_w + 8.0f) {
      float alpha = __expf(m_w - tmx);
      m_w = tmx;
#pragma unroll
      for (int r = 0; r < 4; ++r) l_r[r] *= alpha;
#pragma unroll
      for (int n = 0; n < 8; ++n)
#pragma unroll
        for (int r = 0; r < 4; ++r) oacc[n][r] *= alpha;
    }
#pragma unroll
    for (int r = 0; r < 4; ++r) {
      float p0 = __expf(s0[r] - m_w);
      float p1 = __expf(s1[r] - m_w);
      l_r[r] += p0 + p1;
      unsigned pk;
      asm("v_cvt_pk_bf16_f32 %0, %1, %2" : "=v"(pk) : "v"(p0), "v"(p1));
      int row = 4 * hi + r;
      P[row * 40 + lo] = (short)(pk & 0xffffu);
      P[row * 40 + 16 + lo] = (short)(pk >> 16);
    }
    s16x8 ap = *(const s16x8*)&P[lo * 40 + hi * 8];
    __builtin_amdgcn_s_setprio(1);
#pragma unroll
    for (int n = 0; n < 8; ++n) {
      int rv = n * 16 + lo;
      // read logical slot hi at physical slot hi^sigma(rv), sigma=(lo>>1)&3
      s16x8 bv = *(const s16x8*)(lV[cur] + rv * 64 +
                                 ((hi * 16) ^ (((lo >> 1) & 3) << 4)));
      mfma16(oacc[n], ap, bv);
    }
    __builtin_amdgcn_s_setprio(0);
  };

  int t = s, cur = 0;
  stage(0, t);
  __syncthreads();              // implicit vmcnt(0) drain before barrier
  while (true) {
    int tn = t + NSPLIT;
    if (tn < NTILE) stage(cur ^ 1, tn);
    body(t * 32, cur);
    __syncthreads();            // drains stage vmcnt + all waves done reading
    if (tn >= NTILE) break;
    t = tn;
    cur ^= 1;
  }

  // final cross-lane l reduction (within each hi group's 16 lanes)
#pragma unroll
  for (int off = 1; off < 16; off <<= 1)
#pragma unroll
    for (int r = 0; r < 4; ++r) l_r[r] += __shfl_xor(l_r[r], off);

  // write partials: O (unnormalized, f32), per-row (m, l)
  float* pOb = pO + (size_t)p * 1560 * 128;
#pragma unroll
  for (int n = 0; n < 8; ++n)
#pragma unroll
    for (int r = 0; r < 4; ++r) {
      int rr = q0 + 4 * hi + r;
      if (rr < 1560) pOb[(size_t)rr * 128 + n * 16 + lo] = oacc[n][r];
    }
  if (lo == 0) {
    float2* mlb = pML + (size_t)p * 1560;
#pragma unroll
    for (int r = 0; r < 4; ++r) {
      int rr = q0 + 4 * hi + r;
      if (rr < 1560) mlb[rr] = make_float2(m_w, l_r[r]);
    }
  }
}

// ---------------- combine partials -> Ob (bf16) ----------------------------
// grid (780, 12), 256 thr: each half-block handles one (t, h); d = tid&127.

__global__ __launch_bounds__(256) void k_comb(const float* __restrict__ pO,
                                              const float2* __restrict__ pML,
                                              short* __restrict__ Ob) {
  const int t = blockIdx.x * 2 + (threadIdx.x >> 7);
  const int h = blockIdx.y;
  const int d = threadIdx.x & 127;
  float2 ml[NSPLIT];
  float M = -1e30f;
#pragma unroll
  for (int s = 0; s < NSPLIT; ++s) {
    ml[s] = pML[((size_t)(s * 12 + h) * 1560) + t];
    M = fmaxf(M, ml[s].x);
  }
  float L = 0.f, o = 0.f;
#pragma unroll
  for (int s = 0; s < NSPLIT; ++s) {
    const float* pOb = pO + (size_t)(s * 12 + h) * 1560 * 128;
    float wgt = __expf(ml[s].x - M);
    L += ml[s].y * wgt;
    o += pOb[(size_t)t * 128 + d] * wgt;
  }
  Ob[(size_t)t * DIMM + h * HD + d] = f2bf(o / L);
}

// ---------------- launch ----------------

extern "C" void kernel_launch(void* const* d_in, const int* in_sizes, int n_in,
                              void* d_out, int out_size, void* d_ws, size_t ws_size,
                              hipStream_t stream) {
  (void)in_sizes; (void)n_in; (void)out_size;
  const float* x  = (const float*)d_in[0];
  const float* fc = (const float*)d_in[1];
  const float* fs = (const float*)d_in[2];
  const float* ck = (const float*)d_in[3];
  const float* cv = (const float*)d_in[4];
  const float* wq = (const float*)d_in[5];
  const float* p_bq = (const float*)d_in[6];
  const float* wk = (const float*)d_in[7];
  const float* p_bk = (const float*)d_in[8];
  const float* wv = (const float*)d_in[9];
  const float* p_bv = (const float*)d_in[10];
  const float* wo = (const float*)d_in[11];
  const float* p_bo = (const float*)d_in[12];
  const float* gq = (const float*)d_in[13];
  const float* gk = (const float*)d_in[14];
  float* out = (float*)d_out;

  char* ws = (char*)d_ws;
  if (ws_size < 117393408ull) return;
  short* xb   = (short*)(ws + 0);                 // 1664x1536 bf16 (alias Ob)
  short* ob   = xb;
  short* wqkv = (short*)(ws + 5111808);           // 4608x1536 bf16; pML after QKV GEMM
  short* wob  = (short*)(ws + 19267584);          // 1536x1536 bf16 (live to end)
  float* bqkv = (float*)(ws + 23986176);          // 4608 f32
  float* qkvf = (float*)(ws + 24004608);          // 1664x4608 f32 (alias Vt)
  short* vt   = (short*)(ws + 24004608);          // 12x128x9376 bf16
  short* qb   = (short*)(ws + 54675456);          // 1664x1536 bf16
  short* kb   = (short*)(ws + 59787264);          // 9376x1536 bf16
  short* vr   = (short*)(ws + 88590336);          // 9376x1536 bf16; pO after transv
  float*  pO  = (float*)(ws + 88590336);          // 3 x 12x1560x128 f32 (28.75 MB)
  float2* pML = (float2*)(ws + 5111808);          // 3 x 12x1560 float2 (449 KB)

  k_cvt_x<<<1248, 256, 0, stream>>>(x, xb);
  k_cvtw<<<dim3(1152, 4), 256, 0, stream>>>(wq, wk, wv, wo, wqkv, wob);
  k_bias3<<<18, 256, 0, stream>>>(p_bq, p_bk, p_bv, bqkv);
  k_gather2<<<dim3(5862, 2), 256, 0, stream>>>(ck, cv, kb, vr);
  hipMemsetAsync(qb + (size_t)1560 * 1536, 0, 104 * 1536 * 2, stream);

  k_gemm<<<dim3(36, 13), 256, 0, stream>>>(xb, wqkv, bqkv, qkvf, 4608, 1536, 1664);
  // zero ob pad rows (combine writes rows < 1560; final GEMM stages 1664)
  hipMemsetAsync(ob + (size_t)1560 * 1536, 0, 104 * 1536 * 2, stream);
  k_post<<<1560, 256, 0, stream>>>(qkvf, fc, fs, gq, gk, qb, kb, vr);
  k_transv<<<dim3(293, 12), 256, 0, stream>>>(vr, vt);
  k_attn<<<900, 256, 0, stream>>>(qb, kb, vt, pO, pML);
  k_comb<<<dim3(780, 12), 256, 0, stream>>>(pO, pML, ob);
  k_gemm<<<dim3(12, 13), 256, 0, stream>>>(ob, wob, p_bo, out, 1536, 1536, 1560);
}

// Round 20
// 338.948 us; speedup vs baseline: 70.7619x; 1.0066x over previous
//
#include <hip/hip_runtime.h>

typedef short s16x8 __attribute__((ext_vector_type(8)));
typedef __bf16 bf16x8 __attribute__((ext_vector_type(8)));
typedef float f32x4 __attribute__((ext_vector_type(4)));

#define T_NEW 1560
#define MPAD  1664
#define DIMM  1536
#define NQKV  4608
#define LKV   9360
#define LPAD  9376
#define NEWB  7800
#define HD    128
#define NSPLIT 3
#define NTILE  293          /* ceil(9360/32) */
#define VSPLIT 7776         /* 243*32; V rows below here go cv->vt directly */
#define ATT_SCALE 0.08838834764831845f

static __device__ __forceinline__ short f2bf(float f) {
  unsigned u = __builtin_bit_cast(unsigned, f);
  u = (u + 0x7fffu + ((u >> 16) & 1u)) >> 16;
  return (short)u;
}

static __device__ __forceinline__ float bf2f(short s) {
  unsigned u = ((unsigned)(unsigned short)s) << 16;
  return __builtin_bit_cast(float, u);
}

// builtin MFMA: compiler models latency + inserts MFMA->VALU wait states
// (raw inline-asm MFMA lacks hazard handling -> stale VALU reads; r2-r5 bug)
static __device__ __forceinline__ void mfma16(f32x4& d, s16x8 a, s16x8 b) {
  d = __builtin_amdgcn_mfma_f32_16x16x32_bf16(
      __builtin_bit_cast(bf16x8, a), __builtin_bit_cast(bf16x8, b), d, 0, 0, 0);
}

#define GLD16(gp, lp) __builtin_amdgcn_global_load_lds(                  \
    (const __attribute__((address_space(1))) void*)(gp),                 \
    (__attribute__((address_space(3))) void*)(lp), 16, 0, 0)

// ---------------- conversion kernels ----------------

// all four weight matrices in one launch; blockIdx.y selects (uniform branch)
__global__ __launch_bounds__(256) void k_cvtw(const float* __restrict__ wq,
                                              const float* __restrict__ wk,
                                              const float* __restrict__ wv,
                                              const float* __restrict__ wo,
                                              short* __restrict__ dqkv,
                                              short* __restrict__ dob) {
  const int m = blockIdx.y;
  const float* s = (m == 0) ? wq : (m == 1) ? wk : (m == 2) ? wv : wo;
  short* d = (m < 3) ? (dqkv + (size_t)m * DIMM * DIMM) : dob;
  int i = blockIdx.x * 256 + threadIdx.x;   // < 294912
  const f32x4* p = (const f32x4*)s + (size_t)i * 2;
  f32x4 a = p[0], b = p[1];
  s16x8 o;
  o[0]=f2bf(a[0]); o[1]=f2bf(a[1]); o[2]=f2bf(a[2]); o[3]=f2bf(a[3]);
  o[4]=f2bf(b[0]); o[5]=f2bf(b[1]); o[6]=f2bf(b[2]); o[7]=f2bf(b[3]);
  *((s16x8*)d + i) = o;
}

// x (1560x1536) -> bf16 padded to 1664 rows (pad rows = 0)
__global__ __launch_bounds__(256) void k_cvt_x(const float* __restrict__ s,
                                               short* __restrict__ d) {
  int i = blockIdx.x * 256 + threadIdx.x;   // over MPAD*192
  s16x8 o;
  if (i < T_NEW * (DIMM / 8)) {
    const f32x4* p = (const f32x4*)s + (size_t)i * 2;
    f32x4 a = p[0], b = p[1];
    o[0]=f2bf(a[0]); o[1]=f2bf(a[1]); o[2]=f2bf(a[2]); o[3]=f2bf(a[3]);
    o[4]=f2bf(b[0]); o[5]=f2bf(b[1]); o[6]=f2bf(b[2]); o[7]=f2bf(b[3]);
  } else {
    o = 0;
  }
  *((s16x8*)d + i) = o;
}

// three bias vectors -> contiguous bqkv (one launch).
// NOTE: 1536 is NOT a power of two -> must subtract, not mask (r14 bug:
// i & 1535 scrambled bk/bv -> absmax 1.84e-2).
__global__ __launch_bounds__(256) void k_bias3(const float* __restrict__ bq,
                                               const float* __restrict__ bk,
                                               const float* __restrict__ bv,
                                               float* __restrict__ dst) {
  int i = blockIdx.x * 256 + threadIdx.x;   // < 4608
  const float* s;
  int j;
  if (i < 1536)      { s = bq; j = i; }
  else if (i < 3072) { s = bk; j = i - 1536; }
  else               { s = bv; j = i - 3072; }
  dst[i] = s[j];
}

// both caches (K and V) in one launch; blockIdx.y selects (uniform branch).
// cache (9360x1536 f32) -> dst rows [0,7800) with roll, rows [9360,9376) zero.
// V branch skips rows < VSPLIT (k_gathervt writes those into vt directly).
__global__ __launch_bounds__(256) void k_gather2(const float* __restrict__ ck,
                                                 const float* __restrict__ cv,
                                                 short* __restrict__ kb,
                                                 short* __restrict__ vr) {
  const float* src = blockIdx.y ? cv : ck;
  short* dst = blockIdx.y ? vr : kb;
  int i = blockIdx.x * 256 + threadIdx.x;   // over 7816*192
  int vrow = i / 192;
  int c8 = i - vrow * 192;
  if (blockIdx.y && vrow < VSPLIT) return;  // no barrier in kernel: safe
  s16x8 o;
  int drow;
  if (vrow < NEWB) {
    drow = vrow;
    int srow = (vrow < 1560) ? vrow : vrow + 1560;
    const f32x4* p = (const f32x4*)(src + (size_t)srow * DIMM + c8 * 8);
    f32x4 a = p[0], b = p[1];
    o[0]=f2bf(a[0]); o[1]=f2bf(a[1]); o[2]=f2bf(a[2]); o[3]=f2bf(a[3]);
    o[4]=f2bf(b[0]); o[5]=f2bf(b[1]); o[6]=f2bf(b[2]); o[7]=f2bf(b[3]);
  } else {
    drow = LKV + (vrow - NEWB);
    o = 0;
  }
  *(s16x8*)(dst + (size_t)drow * DIMM + c8 * 8) = o;
}

// fused V cache gather + transpose: cv rows [0,VSPLIT) -> vt[h][d][vrow]
// (roll line verbatim from k_gather2; transpose pattern verbatim k_transv)
__global__ __launch_bounds__(256) void k_gathervt(const float* __restrict__ cv,
                                                  short* __restrict__ Vt) {
  const int h = blockIdx.y;
  const int l0 = blockIdx.x * 32;            // < VSPLIT, 243 blocks
  const int tid = threadIdx.x;
  __shared__ short lt[128 * 34];
#pragma unroll
  for (int i = 0; i < 16; ++i) {
    int idx = i * 256 + tid;
    int li = idx >> 7;
    int d = idx & 127;
    int vrow = l0 + li;
    int srow = (vrow < 1560) ? vrow : vrow + 1560;
    lt[d * 34 + li] = f2bf(cv[(size_t)srow * DIMM + h * HD + d]);
  }
  __syncthreads();
#pragma unroll
  for (int i = 0; i < 16; ++i) {
    int idx = i * 256 + tid;
    int d = idx >> 5;
    int li = idx & 31;
    Vt[((size_t)h * HD + d) * LPAD + l0 + li] = lt[d * 34 + li];
  }
}

// ---------------- GEMM: C[M,N] = A[M,K] * Bt[N,K]^T + bias ----------------

__global__ __launch_bounds__(256) void k_gemm(const short* __restrict__ A,
                                              const short* __restrict__ Bt,
                                              const float* __restrict__ bias,
                                              float* __restrict__ C,
                                              int N, int K, int Mvalid) {
  __shared__ short lA[4096];
  __shared__ short lB[4096];
  const int tid = threadIdx.x;
  const int w = tid >> 6, l = tid & 63;
  const int lo = l & 15, hi = l >> 4;
  const int wr = w >> 1, wc = w & 1;
  const int brow = blockIdx.y * 128, bcol = blockIdx.x * 128;
  f32x4 acc[4][4] = {};
  const short* gA = A + (size_t)(brow + w * 32 + (l >> 2)) * K + ((l & 3) * 8);
  const short* gB = Bt + (size_t)(bcol + w * 32 + (l >> 2)) * K + ((l & 3) * 8);
  short* lAw = &lA[w * 1024];
  short* lBw = &lB[w * 1024];
  for (int k0 = 0; k0 < K; k0 += 32) {
    GLD16(gA + k0, lAw);
    GLD16(gA + (size_t)16 * K + k0, lAw + 512);
    GLD16(gB + k0, lBw);
    GLD16(gB + (size_t)16 * K + k0, lBw + 512);
    __syncthreads();
    s16x8 af[4], bf[4];
#pragma unroll
    for (int m = 0; m < 4; ++m)
      af[m] = *(const s16x8*)&lA[(wr * 64 + m * 16 + lo) * 32 + hi * 8];
#pragma unroll
    for (int n = 0; n < 4; ++n)
      bf[n] = *(const s16x8*)&lB[(wc * 64 + n * 16 + lo) * 32 + hi * 8];
#pragma unroll
    for (int m = 0; m < 4; ++m)
#pragma unroll
      for (int n = 0; n < 4; ++n)
        mfma16(acc[m][n], af[m], bf[n]);
    __syncthreads();
  }
#pragma unroll
  for (int n = 0; n < 4; ++n) {
    int c = bcol + wc * 64 + n * 16 + lo;
    float bs = bias[c];
#pragma unroll
    for (int m = 0; m < 4; ++m) {
      int r0 = brow + wr * 64 + m * 16 + 4 * hi;
#pragma unroll
      for (int r = 0; r < 4; ++r) {
        int rr = r0 + r;
        if (rr < Mvalid) C[(size_t)rr * N + c] = acc[m][n][r] + bs;
      }
    }
  }
}

// ---------------- bias'd QKV row post: rmsnorm+rope for q,k; v passthrough --
// Q rows are pre-scaled by ATT_SCALE (f32) so attention skips the score scale.

__global__ __launch_bounds__(256) void k_post(const float* __restrict__ qkv,
                                              const float* __restrict__ fc,
                                              const float* __restrict__ fs,
                                              const float* __restrict__ gq,
                                              const float* __restrict__ gk,
                                              short* __restrict__ Qb,
                                              short* __restrict__ Kb,
                                              short* __restrict__ Vr) {
  const int t = blockIdx.x, tid = threadIdx.x;
  __shared__ float buf[DIMM];
  __shared__ float red[4];
  const float* row = qkv + (size_t)t * NQKV;
  for (int sec = 0; sec < 2; ++sec) {
    const float* src = row + sec * DIMM;
    const float* g = sec ? gk : gq;
    float ssq = 0.f;
#pragma unroll
    for (int i = 0; i < 6; ++i) {
      float v = src[tid + i * 256];
      buf[tid + i * 256] = v;
      ssq += v * v;
    }
#pragma unroll
    for (int off = 32; off > 0; off >>= 1) ssq += __shfl_xor(ssq, off);
    if ((tid & 63) == 0) red[tid >> 6] = ssq;
    __syncthreads();
    float rms = rsqrtf((red[0] + red[1] + red[2] + red[3]) * (1.f / 1536.f) + 1e-6f);
    short* dst = sec ? (Kb + (size_t)(NEWB + t) * DIMM) : (Qb + (size_t)t * DIMM);
#pragma unroll
    for (int i = 0; i < 6; ++i) {
      int e = tid + i * 256;
      int d = e & 127;
      float vn = buf[e] * rms * g[e];
      float o;
      if (d < 64) {
        float v2 = buf[e + 64] * rms * g[e + 64];
        o = vn * fc[t * 64 + d] - v2 * fs[t * 64 + d];
      } else {
        float v1 = buf[e - 64] * rms * g[e - 64];
        o = v1 * fs[t * 64 + d - 64] + vn * fc[t * 64 + d - 64];
      }
      dst[e] = f2bf(sec ? o : o * ATT_SCALE);
    }
    __syncthreads();
  }
#pragma unroll
  for (int i = 0; i < 6; ++i) {
    int e = tid + i * 256;
    Vr[(size_t)(NEWB + t) * DIMM + e] = f2bf(row[3072 + e]);
  }
}

// ---------------- V transpose (tail rows only): Vr[l][...] -> Vt[h][d][l] ---
// covers l0 in [VSPLIT, LPAD): 50 blocks x 32 rows (gather2 V-branch writes
// rows VSPLIT..NEWB-1 and zeros 9360..9375; k_post writes 7800..9359).

__global__ __launch_bounds__(256) void k_transv(const short* __restrict__ Vr,
                                                short* __restrict__ Vt) {
  const int h = blockIdx.y;
  const int l0 = VSPLIT + blockIdx.x * 32;
  const int tid = threadIdx.x;
  __shared__ short lt[128 * 34];
#pragma unroll
  for (int i = 0; i < 16; ++i) {
    int idx = i * 256 + tid;
    int li = idx >> 7;
    int d = idx & 127;
    lt[d * 34 + li] = Vr[(size_t)(l0 + li) * DIMM + h * HD + d];
  }
  __syncthreads();
#pragma unroll
  for (int i = 0; i < 16; ++i) {
    int idx = i * 256 + tid;
    int d = idx >> 5;
    int li = idx & 31;
    Vt[((size_t)h * HD + d) * LPAD + l0 + li] = lt[d * 34 + li];
  }
}

// ---------------- flash attention: key-split + LDS dbuf + lean softmax -----
// VERBATIM r18 (hardware-validated PASS, attn 199.6us). FOUR geometry
// restructures (r11,r12,r13,r19) all failed on HW with distinct errors;
// the 4-wave/64q geometry is FROZEN. grid 900, XCD panel-affine.

__global__ __launch_bounds__(256, 4) void k_attn(const short* __restrict__ Qb,
                                                 const short* __restrict__ Kb,
                                                 const short* __restrict__ Vt,
                                                 float* __restrict__ pO,
                                                 float2* __restrict__ pML) {
  // bijective decode of flat grid 900 -> (bx in [0,25), panel p in [0,36))
  const int f = blockIdx.x;
  int bx, p;
  if (f < 800) {
    const int xcd = f & 7;
    const int rdec = f >> 3;
    bx = rdec % 25;
    p = (rdec / 25) * 8 + xcd;     // panels 0..31, XCD-affine
  } else {
    const int g = f - 800;
    p = 32 + (g & 3);              // panels 32..35
    bx = g >> 2;
  }
  const int s = p / 12;
  const int h = p % 12;
  const int w = threadIdx.x >> 6;
  const int l = threadIdx.x & 63;
  const int lo = l & 15, hi = l >> 4;
  const int q0 = bx * 64 + w * 16;
  __shared__ __align__(16) char lK[2][8192];   // 32 keys x 256B, swizzled
  __shared__ __align__(16) char lV[2][8192];   // 128 dims x 4 slots, swizzled
  __shared__ short lP[4][640];
  short* P = lP[w];

  s16x8 aq[4];
  const short* qp = Qb + (size_t)(q0 + lo) * DIMM + h * HD + hi * 8;
#pragma unroll
  for (int kk = 0; kk < 4; ++kk) aq[kk] = *(const s16x8*)(qp + kk * 32);

  f32x4 oacc[8];
#pragma unroll
  for (int n = 0; n < 8; ++n) oacc[n] = 0;
  float m_w = -1e30f;
  float l_r[4];
#pragma unroll
  for (int r = 0; r < 4; ++r) l_r[r] = 0.f;

  const short* Kh = Kb + h * HD;
  const short* Vh = Vt + (size_t)h * HD * LPAD;

  // stage one 8KB K tile + 8KB V tile (block-cooperative, 2 chunks/wave each)
  auto stage = [&](int cur, int tile) {
#pragma unroll
    for (int j = 0; j < 2; ++j) {
      int chunk = j * 4 + w;
      int r = chunk * 4 + (l >> 4);
      int cb = ((l & 15) * 16) ^ ((r & 7) << 4);   // pre-swizzled source col
      GLD16(Kh + (size_t)(tile * 32 + r) * DIMM + (cb >> 1),
            &lK[cur][chunk * 1024]);
    }
#pragma unroll
    for (int j = 0; j < 2; ++j) {
      int chunk = j * 4 + w;
      int dim = chunk * 16 + (l >> 2);
      // V slot-swizzle: lane writes slot (l&3) of dim; source slot is
      // (l&3)^sigma(dim), sigma(dim)=(dim>>1)&3=(l>>3)&3
      GLD16(Vh + (size_t)dim * LPAD + tile * 32 + ((l & 3) ^ ((l >> 3) & 3)) * 8,
            &lV[cur][chunk * 1024]);
    }
  };

  auto body = [&](int kbv, int cur) {
    const int swz = (lo & 7) << 4;
    f32x4 s0 = 0, s1 = 0;
    __builtin_amdgcn_s_setprio(1);
#pragma unroll
    for (int kk = 0; kk < 4; ++kk) {
      s16x8 b0 = *(const s16x8*)(lK[cur] + lo * 256 + ((kk * 64 + hi * 16) ^ swz));
      s16x8 b1 = *(const s16x8*)(lK[cur] + (16 + lo) * 256 + ((kk * 64 + hi * 16) ^ swz));
      mfma16(s0, aq[kk], b0);
      mfma16(s1, aq[kk], b1);
    }
    __builtin_amdgcn_s_setprio(0);
    if (kbv + 32 > LKV) {            // boundary tile only (block-uniform)
      const int key1 = kbv + 16 + lo;
#pragma unroll
      for (int r = 0; r < 4; ++r)
        if (key1 >= LKV) s1[r] = -1e30f;
    }
    // wave-uniform tile max
    float tmx = fmaxf(fmaxf(fmaxf(s0[0], s0[1]), fmaxf(s0[2], s0[3])),
                      fmaxf(fmaxf(s1[0], s1[1]), fmaxf(s1[2], s1[3])));
#pragma unroll
    for (int off = 1; off < 64; off <<= 1)
      tmx = fmaxf(tmx, __shfl_xor(tmx, off));
    // defer-max: rescale only when max grows by > 8
    if (tmx > m_w + 8.0f) {
      float alpha = __expf(m_w - tmx);
      m_w = tmx;
#pragma unroll
      for (int r = 0; r < 4; ++r) l_r[r] *= alpha;
#pragma unroll
      for (int n = 0; n < 8; ++n)
#pragma unroll
        for (int r = 0; r < 4; ++r) oacc[n][r] *= alpha;
    }
#pragma unroll
    for (int r = 0; r < 4; ++r) {
      float p0 = __expf(s0[r] - m_w);
      float p1 = __expf(s1[r] - m_w);
      l_r[r] += p0 + p1;
      unsigned pk;
      asm("v_cvt_pk_bf16_f32 %0, %1, %2" : "=v"(pk) : "v"(p0), "v"(p1));
      int row = 4 * hi + r;
      P[row * 40 + lo] = (short)(pk & 0xffffu);
      P[row * 40 + 16 + lo] = (short)(pk >> 16);
    }
    s16x8 ap = *(const s16x8*)&P[lo * 40 + hi * 8];
    __builtin_amdgcn_s_setprio(1);
#pragma unroll
    for (int n = 0; n < 8; ++n) {
      int rv = n * 16 + lo;
      // read logical slot hi at physical slot hi^sigma(rv), sigma=(lo>>1)&3
      s16x8 bv = *(const s16x8*)(lV[cur] + rv * 64 +
                                 ((hi * 16) ^ (((lo >> 1) & 3) << 4)));
      mfma16(oacc[n], ap, bv);
    }
    __builtin_amdgcn_s_setprio(0);
  };

  int t = s, cur = 0;
  stage(0, t);
  __syncthreads();              // implicit vmcnt(0) drain before barrier
  while (true) {
    int tn = t + NSPLIT;
    if (tn < NTILE) stage(cur ^ 1, tn);
    body(t * 32, cur);
    __syncthreads();            // drains stage vmcnt + all waves done reading
    if (tn >= NTILE) break;
    t = tn;
    cur ^= 1;
  }

  // final cross-lane l reduction (within each hi group's 16 lanes)
#pragma unroll
  for (int off = 1; off < 16; off <<= 1)
#pragma unroll
    for (int r = 0; r < 4; ++r) l_r[r] += __shfl_xor(l_r[r], off);

  // write partials: O (unnormalized, f32), per-row (m, l)
  float* pOb = pO + (size_t)p * 1560 * 128;
#pragma unroll
  for (int n = 0; n < 8; ++n)
#pragma unroll
    for (int r = 0; r < 4; ++r) {
      int rr = q0 + 4 * hi + r;
      if (rr < 1560) pOb[(size_t)rr * 128 + n * 16 + lo] = oacc[n][r];
    }
  if (lo == 0) {
    float2* mlb = pML + (size_t)p * 1560;
#pragma unroll
    for (int r = 0; r < 4; ++r) {
      int rr = q0 + 4 * hi + r;
      if (rr < 1560) mlb[rr] = make_float2(m_w, l_r[r]);
    }
  }
}

// ---------------- combine partials -> Ob (bf16) ----------------------------
// grid (780, 12), 256 thr: each half-block handles one (t, h); d = tid&127.

__global__ __launch_bounds__(256) void k_comb(const float* __restrict__ pO,
                                              const float2* __restrict__ pML,
                                              short* __restrict__ Ob) {
  const int t = blockIdx.x * 2 + (threadIdx.x >> 7);
  const int h = blockIdx.y;
  const int d = threadIdx.x & 127;
  float2 ml[NSPLIT];
  float M = -1e30f;
#pragma unroll
  for (int s = 0; s < NSPLIT; ++s) {
    ml[s] = pML[((size_t)(s * 12 + h) * 1560) + t];
    M = fmaxf(M, ml[s].x);
  }
  float L = 0.f, o = 0.f;
#pragma unroll
  for (int s = 0; s < NSPLIT; ++s) {
    const float* pOb = pO + (size_t)(s * 12 + h) * 1560 * 128;
    float wgt = __expf(ml[s].x - M);
    L += ml[s].y * wgt;
    o += pOb[(size_t)t * 128 + d] * wgt;
  }
  Ob[(size_t)t * DIMM + h * HD + d] = f2bf(o / L);
}

// ---------------- launch ----------------

extern "C" void kernel_launch(void* const* d_in, const int* in_sizes, int n_in,
                              void* d_out, int out_size, void* d_ws, size_t ws_size,
                              hipStream_t stream) {
  (void)in_sizes; (void)n_in; (void)out_size;
  const float* x  = (const float*)d_in[0];
  const float* fc = (const float*)d_in[1];
  const float* fs = (const float*)d_in[2];
  const float* ck = (const float*)d_in[3];
  const float* cv = (const float*)d_in[4];
  const float* wq = (const float*)d_in[5];
  const float* p_bq = (const float*)d_in[6];
  const float* wk = (const float*)d_in[7];
  const float* p_bk = (const float*)d_in[8];
  const float* wv = (const float*)d_in[9];
  const float* p_bv = (const float*)d_in[10];
  const float* wo = (const float*)d_in[11];
  const float* p_bo = (const float*)d_in[12];
  const float* gq = (const float*)d_in[13];
  const float* gk = (const float*)d_in[14];
  float* out = (float*)d_out;

  char* ws = (char*)d_ws;
  if (ws_size < 117393408ull) return;
  short* xb   = (short*)(ws + 0);                 // 1664x1536 bf16 (alias Ob)
  short* ob   = xb;
  short* wqkv = (short*)(ws + 5111808);           // 4608x1536 bf16; pML after QKV GEMM
  short* wob  = (short*)(ws + 19267584);          // 1536x1536 bf16 (live to end)
  float* bqkv = (float*)(ws + 23986176);          // 4608 f32
  float* qkvf = (float*)(ws + 24004608);          // 1664x4608 f32 (alias Vt)
  short* vt   = (short*)(ws + 24004608);          // 12x128x9376 bf16
  short* qb   = (short*)(ws + 54675456);          // 1664x1536 bf16
  short* kb   = (short*)(ws + 59787264);          // 9376x1536 bf16
  short* vr   = (short*)(ws + 88590336);          // 9376x1536 bf16; pO after transv
  float*  pO  = (float*)(ws + 88590336);          // 3 x 12x1560x128 f32 (28.75 MB)
  float2* pML = (float2*)(ws + 5111808);          // 3 x 12x1560 float2 (449 KB)

  k_cvt_x<<<1248, 256, 0, stream>>>(x, xb);
  k_cvtw<<<dim3(1152, 4), 256, 0, stream>>>(wq, wk, wv, wo, wqkv, wob);
  k_bias3<<<18, 256, 0, stream>>>(p_bq, p_bk, p_bv, bqkv);
  k_gather2<<<dim3(5862, 2), 256, 0, stream>>>(ck, cv, kb, vr);
  hipMemsetAsync(qb + (size_t)1560 * 1536, 0, 104 * 1536 * 2, stream);

  k_gemm<<<dim3(36, 13), 256, 0, stream>>>(xb, wqkv, bqkv, qkvf, 4608, 1536, 1664);
  // zero ob pad rows (combine writes rows < 1560; final GEMM stages 1664)
  hipMemsetAsync(ob + (size_t)1560 * 1536, 0, 104 * 1536 * 2, stream);
  k_post<<<1560, 256, 0, stream>>>(qkvf, fc, fs, gq, gk, qb, kb, vr);
  k_gathervt<<<dim3(243, 12), 256, 0, stream>>>(cv, vt);
  k_transv<<<dim3(50, 12), 256, 0, stream>>>(vr, vt);
  k_attn<<<900, 256, 0, stream>>>(qb, kb, vt, pO, pML);
  k_comb<<<dim3(780, 12), 256, 0, stream>>>(pO, pML, ob);
  k_gemm<<<dim3(12, 13), 256, 0, stream>>>(ob, wob, p_bo, out, 1536, 1536, 1560);
}